// Round 1
// baseline (1420.249 us; speedup 1.0000x reference)
//
#include <hip/hip_runtime.h>
#include <hip/hip_bf16.h>
#include <math.h>

// Qwen3-Next GatedDeltaNet, B=1, S=1024, HIDDEN=2048
// H_K=8, H_V=16, DK=DV=128, KDIM=1024, VDIM=2048, CONV_DIM=4096, KS=4

#define SEQ 1024
#define HID 2048
#define NQKVZ 6144

// ---------------------------------------------------------------------------
// f32 tiled GEMM: C[M,N] = A[M,K] @ B[K,N].  BM=BN=128, BK=8, 256 threads,
// 8x8 micro-tile per thread. M,N multiples of 128, K multiple of 8.
// ---------------------------------------------------------------------------
__global__ __launch_bounds__(256) void gemm_f32(const float* __restrict__ A,
                                                const float* __restrict__ B,
                                                float* __restrict__ C,
                                                int M, int N, int K) {
  __shared__ float As[8][128];
  __shared__ float Bs[8][128];
  const int tid  = threadIdx.x;
  const int row0 = blockIdx.y * 128;
  const int col0 = blockIdx.x * 128;
  const int tx = tid & 15;         // N sub-tile 0..15
  const int ty = tid >> 4;         // M sub-tile 0..15
  const int arow = tid >> 1;       // 0..127
  const int acol = (tid & 1) * 4;  // 0 or 4
  const int brow = tid >> 5;       // 0..7
  const int bcol = (tid & 31) * 4; // 0..124

  float acc[8][8];
#pragma unroll
  for (int i = 0; i < 8; ++i)
#pragma unroll
    for (int j = 0; j < 8; ++j) acc[i][j] = 0.f;

  for (int k0 = 0; k0 < K; k0 += 8) {
    const float4 av = *(const float4*)&A[(size_t)(row0 + arow) * K + k0 + acol];
    const float4 bv = *(const float4*)&B[(size_t)(k0 + brow) * N + col0 + bcol];
    As[acol + 0][arow] = av.x;
    As[acol + 1][arow] = av.y;
    As[acol + 2][arow] = av.z;
    As[acol + 3][arow] = av.w;
    *(float4*)&Bs[brow][bcol] = bv;
    __syncthreads();
#pragma unroll
    for (int kk = 0; kk < 8; ++kk) {
      float a[8], b[8];
      *(float4*)&a[0] = *(const float4*)&As[kk][ty * 8];
      *(float4*)&a[4] = *(const float4*)&As[kk][ty * 8 + 4];
      *(float4*)&b[0] = *(const float4*)&Bs[kk][tx * 8];
      *(float4*)&b[4] = *(const float4*)&Bs[kk][tx * 8 + 4];
#pragma unroll
      for (int i = 0; i < 8; ++i)
#pragma unroll
        for (int j = 0; j < 8; ++j) acc[i][j] += a[i] * b[j];
    }
    __syncthreads();
  }
#pragma unroll
  for (int i = 0; i < 8; ++i) {
#pragma unroll
    for (int jv = 0; jv < 2; ++jv) {
      float4 o;
      o.x = acc[i][jv * 4 + 0];
      o.y = acc[i][jv * 4 + 1];
      o.z = acc[i][jv * 4 + 2];
      o.w = acc[i][jv * 4 + 3];
      *(float4*)&C[(size_t)(row0 + ty * 8 + i) * N + col0 + tx * 8 + jv * 4] = o;
    }
  }
}

// ---------------------------------------------------------------------------
// ba = X @ W_ba (1024x2048 @ 2048x32), fused into beta = sigmoid(b) and
// dec = exp(-exp(A_log)*softplus(a+dt_bias)).
// grid 128 blocks x 256 thr; block handles 8 seq rows x 32 cols.
// ---------------------------------------------------------------------------
__global__ __launch_bounds__(256) void ba_kernel(const float* __restrict__ X,
                                                 const float* __restrict__ W_ba,
                                                 const float* __restrict__ A_log,
                                                 const float* __restrict__ dt_bias,
                                                 float* __restrict__ dec,
                                                 float* __restrict__ bet) {
  const int t   = threadIdx.x;
  const int sl  = t >> 5;          // 0..7
  const int col = t & 31;          // 0..31
  const int s   = blockIdx.x * 8 + sl;
  const float* xr = X + (size_t)s * HID;
  const float* wb = W_ba + col;
  float acc = 0.f;
#pragma unroll 8
  for (int k = 0; k < HID; ++k) acc += xr[k] * wb[(size_t)k * 32];

  const int hk = col >> 2, j = col & 3;
  if (j < 2) {
    bet[s * 16 + hk * 2 + j] = 1.f / (1.f + expf(-acc));
  } else {
    const int vh = hk * 2 + (j - 2);
    const float x = acc + dt_bias[vh];
    const float sp = (x > 20.f) ? x : log1pf(expf(x));
    dec[s * 16 + vh] = expf(-expf(A_log[vh]) * sp);
  }
}

// ---------------------------------------------------------------------------
// depthwise causal conv (KS=4) + SiLU over q,k,v channels; l2norm on q,k
// (q also * DK^-0.5).  grid (32 slots, 1024 s), 128 thr (one per dim d).
// slots: 0-7 q-heads, 8-15 k-heads, 16-31 v-heads.
// ---------------------------------------------------------------------------
__global__ __launch_bounds__(128) void conv_kernel(const float* __restrict__ qkvz,
                                                   const float* __restrict__ conv_w,
                                                   float* __restrict__ qn,
                                                   float* __restrict__ kn,
                                                   float* __restrict__ vc) {
  const int slot = blockIdx.x;
  const int s    = blockIdx.y;
  const int d    = threadIdx.x;

  int col, ch;
  if (slot < 8) {                 // q head
    col = slot * 768 + d;
    ch  = slot * 128 + d;
  } else if (slot < 16) {         // k head
    const int hk = slot - 8;
    col = hk * 768 + 128 + d;
    ch  = 1024 + hk * 128 + d;
  } else {                        // v head
    const int vh = slot - 16;
    col = (vh >> 1) * 768 + 256 + (vh & 1) * 128 + d;
    ch  = 2048 + vh * 128 + d;
  }

  float acc = 0.f;
#pragma unroll
  for (int j = 0; j < 4; ++j) {
    const int sr = s - 3 + j;
    const float x = (sr >= 0) ? qkvz[(size_t)sr * NQKVZ + col] : 0.f;
    acc += conv_w[ch * 4 + j] * x;
  }
  float y = acc / (1.f + expf(-acc));  // silu

  if (slot < 16) {
    // l2 norm over the 128 dims of this head
    float ss = y * y;
#pragma unroll
    for (int m = 1; m < 64; m <<= 1) ss += __shfl_xor(ss, m);
    __shared__ float red[2];
    if ((threadIdx.x & 63) == 0) red[threadIdx.x >> 6] = ss;
    __syncthreads();
    const float tot = red[0] + red[1];
    float sc = rsqrtf(tot + 1e-6f);
    if (slot < 8) sc *= 0.08838834764831845f;  // DK^-0.5
    y *= sc;
    if (slot < 8) qn[((size_t)s * 8 + slot) * 128 + d] = y;
    else          kn[((size_t)s * 8 + (slot - 8)) * 128 + d] = y;
  } else {
    vc[((size_t)s * 16 + (slot - 16)) * 128 + d] = y;
  }
}

// ---------------------------------------------------------------------------
// Gated delta rule scan.  grid 128 blocks (16 heads x 8 dv-groups of 16),
// 256 thr: dkg = tid&15 owns 8 dk values, dvl = tid>>4 is the dv column.
// State S[dk][dv] lives in registers (8 floats / lane).  No __syncthreads:
// reductions over dk are intra-wave shfl_xor (16 consecutive lanes).
// ---------------------------------------------------------------------------
__global__ __launch_bounds__(256) void scan_kernel(const float* __restrict__ qn,
                                                   const float* __restrict__ kn,
                                                   const float* __restrict__ vc,
                                                   const float* __restrict__ dec,
                                                   const float* __restrict__ bet,
                                                   float* __restrict__ obuf) {
  const int h   = blockIdx.x >> 3;
  const int dvg = blockIdx.x & 7;
  const int tid = threadIdx.x;
  const int dkg = tid & 15;
  const int dvl = tid >> 4;
  const int dv  = dvg * 16 + dvl;
  const int hk  = h >> 1;
  const int dk0 = dkg * 8;

  const float* kbase = kn + hk * 128 + dk0;   // + t*1024
  const float* qbase = qn + hk * 128 + dk0;   // + t*1024
  const float* vbase = vc + h * 128 + dv;     // + t*2048

  float st[8];
#pragma unroll
  for (int i = 0; i < 8; ++i) st[i] = 0.f;

  // prefetch t = 0
  float4 ka = *(const float4*)(kbase);
  float4 kb = *(const float4*)(kbase + 4);
  float4 qa = *(const float4*)(qbase);
  float4 qb = *(const float4*)(qbase + 4);
  float vv = *vbase;
  float dc = dec[h];
  float bt = bet[h];

  for (int t = 0; t < SEQ; ++t) {
    const int tn = (t < SEQ - 1) ? t + 1 : t;
    const float* kp = kbase + (size_t)tn * 1024;
    const float* qp = qbase + (size_t)tn * 1024;
    const float4 nka = *(const float4*)(kp);
    const float4 nkb = *(const float4*)(kp + 4);
    const float4 nqa = *(const float4*)(qp);
    const float4 nqb = *(const float4*)(qp + 4);
    const float nvv = vbase[(size_t)tn * 2048];
    const float ndc = dec[tn * 16 + h];
    const float nbt = bet[tn * 16 + h];

    const float k_[8] = {ka.x, ka.y, ka.z, ka.w, kb.x, kb.y, kb.z, kb.w};
    const float q_[8] = {qa.x, qa.y, qa.z, qa.w, qb.x, qb.y, qb.z, qb.w};

    // decay + pred partial
    float p = 0.f;
#pragma unroll
    for (int i = 0; i < 8; ++i) {
      st[i] *= dc;
      p += k_[i] * st[i];
    }
    p += __shfl_xor(p, 1);
    p += __shfl_xor(p, 2);
    p += __shfl_xor(p, 4);
    p += __shfl_xor(p, 8);

    const float delta = (vv - p) * bt;

    float op = 0.f;
#pragma unroll
    for (int i = 0; i < 8; ++i) {
      st[i] += k_[i] * delta;
      op += q_[i] * st[i];
    }
    op += __shfl_xor(op, 1);
    op += __shfl_xor(op, 2);
    op += __shfl_xor(op, 4);
    op += __shfl_xor(op, 8);

    if (dkg == 0) obuf[((size_t)t * 16 + h) * 128 + dv] = op;

    ka = nka; kb = nkb; qa = nqa; qb = nqb; vv = nvv; dc = ndc; bt = nbt;
  }
}

// ---------------------------------------------------------------------------
// gated RMSNorm: on = o * rsqrt(mean(o^2)+eps) * w * silu(z)
// grid (16 vh, 1024 s), 128 thr.
// ---------------------------------------------------------------------------
__global__ __launch_bounds__(128) void rmsnorm_kernel(const float* __restrict__ obuf,
                                                      const float* __restrict__ qkvz,
                                                      const float* __restrict__ nw,
                                                      float* __restrict__ on) {
  const int vh = blockIdx.x;
  const int s  = blockIdx.y;
  const int d  = threadIdx.x;

  const float x = obuf[((size_t)s * 16 + vh) * 128 + d];
  float ss = x * x;
#pragma unroll
  for (int m = 1; m < 64; m <<= 1) ss += __shfl_xor(ss, m);
  __shared__ float red[2];
  if ((threadIdx.x & 63) == 0) red[threadIdx.x >> 6] = ss;
  __syncthreads();
  const float tot = red[0] + red[1];

  const float z = qkvz[(size_t)s * NQKVZ + (vh >> 1) * 768 + 512 + (vh & 1) * 128 + d];
  const float y = x * rsqrtf(tot * (1.f / 128.f) + 1e-6f) * nw[d] *
                  (z / (1.f + expf(-z)));
  on[(size_t)s * 2048 + vh * 128 + d] = y;
}

// ---------------------------------------------------------------------------
extern "C" void kernel_launch(void* const* d_in, const int* in_sizes, int n_in,
                              void* d_out, int out_size, void* d_ws, size_t ws_size,
                              hipStream_t stream) {
  const float* hid     = (const float*)d_in[0];
  const float* W_qkvz  = (const float*)d_in[1];
  const float* W_ba    = (const float*)d_in[2];
  const float* conv_w  = (const float*)d_in[3];
  const float* dt_bias = (const float*)d_in[4];
  const float* A_log   = (const float*)d_in[5];
  const float* norm_w  = (const float*)d_in[6];
  const float* W_out   = (const float*)d_in[7];
  float* out = (float*)d_out;

  char* ws = (char*)d_ws;
  float* qkvz = (float*)ws; ws += (size_t)SEQ * NQKVZ * 4;   // 24 MB
  float* qn   = (float*)ws; ws += (size_t)SEQ * 1024 * 4;    // 4 MB
  float* kn   = (float*)ws; ws += (size_t)SEQ * 1024 * 4;    // 4 MB
  float* vc   = (float*)ws; ws += (size_t)SEQ * 2048 * 4;    // 8 MB
  float* dec  = (float*)ws; ws += (size_t)SEQ * 16 * 4;
  float* bet  = (float*)ws; ws += (size_t)SEQ * 16 * 4;
  float* obuf = (float*)ws; ws += (size_t)SEQ * 2048 * 4;    // 8 MB
  float* on   = (float*)ws; ws += (size_t)SEQ * 2048 * 4;    // 8 MB

  // 1. qkvz = X @ W_qkvz
  gemm_f32<<<dim3(NQKVZ / 128, SEQ / 128), 256, 0, stream>>>(hid, W_qkvz, qkvz,
                                                             SEQ, NQKVZ, HID);
  // 2. beta / decay from X @ W_ba
  ba_kernel<<<dim3(SEQ / 8), 256, 0, stream>>>(hid, W_ba, A_log, dt_bias, dec, bet);
  // 3. causal conv + silu + l2norm
  conv_kernel<<<dim3(32, SEQ), 128, 0, stream>>>(qkvz, conv_w, qn, kn, vc);
  // 4. gated delta rule scan
  scan_kernel<<<dim3(128), 256, 0, stream>>>(qn, kn, vc, dec, bet, obuf);
  // 5. gated rmsnorm
  rmsnorm_kernel<<<dim3(16, SEQ), 128, 0, stream>>>(obuf, qkvz, norm_w, on);
  // 6. out = on @ W_out
  gemm_f32<<<dim3(HID / 128, SEQ / 128), 256, 0, stream>>>(on, W_out, out,
                                                           SEQ, HID, HID);
}

// Round 2
// 636.985 us; speedup vs baseline: 2.2296x; 2.2296x over previous
//
#include <hip/hip_runtime.h>
#include <hip/hip_bf16.h>
#include <math.h>

// Qwen3-Next GatedDeltaNet, B=1, S=1024, HIDDEN=2048
// H_K=8, H_V=16, DK=DV=128, KDIM=1024, VDIM=2048, CONV_DIM=4096, KS=4

#define SEQ 1024
#define HID 2048
#define NQKVZ 6144

typedef __attribute__((ext_vector_type(8))) short short8;
typedef __attribute__((ext_vector_type(4))) float f32x4;

__device__ __forceinline__ unsigned short f2bf(float f) {
  __hip_bfloat16 h = __float2bfloat16(f);
  return *reinterpret_cast<unsigned short*>(&h);
}

// ---------------------------------------------------------------------------
// elementwise f32 -> bf16 cast (4 per thread)
// ---------------------------------------------------------------------------
__global__ __launch_bounds__(256) void cast_bf16(const float* __restrict__ in,
                                                 unsigned short* __restrict__ out,
                                                 int n) {
  const int i = (blockIdx.x * 256 + threadIdx.x) * 4;
  if (i < n) {
    const float4 v = *(const float4*)&in[i];
    ushort4 o;
    o.x = f2bf(v.x); o.y = f2bf(v.y); o.z = f2bf(v.z); o.w = f2bf(v.w);
    *(ushort4*)&out[i] = o;
  }
}

// ---------------------------------------------------------------------------
// W[K][N] f32 -> Wt[N][K] bf16 (32x32 LDS tile transpose, coalesced both ways)
// ---------------------------------------------------------------------------
__global__ __launch_bounds__(256) void transpose_cast(const float* __restrict__ W,
                                                      unsigned short* __restrict__ Wt,
                                                      int K, int N) {
  __shared__ float tile[32][33];
  const int n0 = blockIdx.x * 32, k0 = blockIdx.y * 32;
  const int tx = threadIdx.x & 31, ty = threadIdx.x >> 5;  // ty 0..7
#pragma unroll
  for (int r = 0; r < 32; r += 8)
    tile[ty + r][tx] = W[(size_t)(k0 + ty + r) * N + n0 + tx];
  __syncthreads();
#pragma unroll
  for (int r = 0; r < 32; r += 8)
    Wt[(size_t)(n0 + ty + r) * K + k0 + tx] = f2bf(tile[tx][ty + r]);
}

// ---------------------------------------------------------------------------
// bf16 MFMA GEMM: C[M][N] f32 = A[M][K] @ Bt[N][K]^T, both operands bf16
// row-major with K contiguous. 128x128 tile, BK=32, 256 thr = 4 waves (2x2),
// each wave 64x64 via 4x4 frags of mfma_f32_16x16x32_bf16.
// LDS 16B-slot XOR swizzle (slot ^= row&3) applied on BOTH write and read.
// ---------------------------------------------------------------------------
__global__ __launch_bounds__(256) void gemm_bf16(const unsigned short* __restrict__ A,
                                                 const unsigned short* __restrict__ Bt,
                                                 float* __restrict__ C,
                                                 int M, int N, int K) {
  __shared__ unsigned short As[128 * 32];
  __shared__ unsigned short Bs[128 * 32];
  char* asb = (char*)As;
  char* bsb = (char*)Bs;

  const int tid  = threadIdx.x;
  const int lane = tid & 63;
  const int w    = tid >> 6;
  const int wm   = w >> 1, wn = w & 1;
  const int row0 = blockIdx.y * 128, col0 = blockIdx.x * 128;

  const int srow = tid >> 1;            // staging row 0..127
  const int skc  = (tid & 1) * 16;      // staging k elem offset (0 or 16)
  const int s0   = (tid & 1) * 2;       // 16B slot index (0 or 2)
  const int sw   = srow & 3;

  const int arow = lane & 15;
  const int ak   = (lane >> 4) * 8;     // k offset 0/8/16/24
  const int asl  = ak >> 3;             // 16B slot of the fragment

  f32x4 acc[4][4];
#pragma unroll
  for (int m = 0; m < 4; ++m)
#pragma unroll
    for (int n = 0; n < 4; ++n) acc[m][n] = (f32x4){0.f, 0.f, 0.f, 0.f};

  for (int k0 = 0; k0 < K; k0 += 32) {
    const unsigned short* ag = A  + (size_t)(row0 + srow) * K + k0 + skc;
    const unsigned short* bg = Bt + (size_t)(col0 + srow) * K + k0 + skc;
    const int4 a0 = *(const int4*)ag;
    const int4 a1 = *(const int4*)(ag + 8);
    const int4 b0 = *(const int4*)bg;
    const int4 b1 = *(const int4*)(bg + 8);
    __syncthreads();  // previous iteration's reads done before overwrite
    *(int4*)(asb + srow * 64 + ((s0    ) ^ sw) * 16) = a0;
    *(int4*)(asb + srow * 64 + ((s0 + 1) ^ sw) * 16) = a1;
    *(int4*)(bsb + srow * 64 + ((s0    ) ^ sw) * 16) = b0;
    *(int4*)(bsb + srow * 64 + ((s0 + 1) ^ sw) * 16) = b1;
    __syncthreads();

    short8 af[4], bf[4];
#pragma unroll
    for (int m = 0; m < 4; ++m) {
      const int row = wm * 64 + m * 16 + arow;
      af[m] = *(const short8*)(asb + row * 64 + (asl ^ (row & 3)) * 16);
    }
#pragma unroll
    for (int n = 0; n < 4; ++n) {
      const int row = wn * 64 + n * 16 + arow;
      bf[n] = *(const short8*)(bsb + row * 64 + (asl ^ (row & 3)) * 16);
    }
#pragma unroll
    for (int m = 0; m < 4; ++m)
#pragma unroll
      for (int n = 0; n < 4; ++n)
        acc[m][n] = __builtin_amdgcn_mfma_f32_16x16x32_bf16(af[m], bf[n], acc[m][n], 0, 0, 0);
  }

#pragma unroll
  for (int m = 0; m < 4; ++m)
#pragma unroll
    for (int n = 0; n < 4; ++n) {
      const int r0 = row0 + wm * 64 + m * 16 + (lane >> 4) * 4;
      const int c  = col0 + wn * 64 + n * 16 + (lane & 15);
#pragma unroll
      for (int r = 0; r < 4; ++r)
        C[(size_t)(r0 + r) * N + c] = acc[m][n][r];
    }
}

// ---------------------------------------------------------------------------
// ba = X @ W_ba, fused beta = sigmoid(b), dec = exp(-exp(A_log)*softplus(a+dt))
// ---------------------------------------------------------------------------
__global__ __launch_bounds__(256) void ba_kernel(const float* __restrict__ X,
                                                 const float* __restrict__ W_ba,
                                                 const float* __restrict__ A_log,
                                                 const float* __restrict__ dt_bias,
                                                 float* __restrict__ dec,
                                                 float* __restrict__ bet) {
  const int t   = threadIdx.x;
  const int sl  = t >> 5;
  const int col = t & 31;
  const int s   = blockIdx.x * 8 + sl;
  const float* xr = X + (size_t)s * HID;
  const float* wb = W_ba + col;
  float acc = 0.f;
#pragma unroll 8
  for (int k = 0; k < HID; ++k) acc += xr[k] * wb[(size_t)k * 32];

  const int hk = col >> 2, j = col & 3;
  if (j < 2) {
    bet[s * 16 + hk * 2 + j] = 1.f / (1.f + expf(-acc));
  } else {
    const int vh = hk * 2 + (j - 2);
    const float x = acc + dt_bias[vh];
    const float sp = (x > 20.f) ? x : log1pf(expf(x));
    dec[s * 16 + vh] = expf(-expf(A_log[vh]) * sp);
  }
}

// ---------------------------------------------------------------------------
// depthwise causal conv (KS=4) + SiLU; l2norm on q,k (q also * DK^-0.5)
// ---------------------------------------------------------------------------
__global__ __launch_bounds__(128) void conv_kernel(const float* __restrict__ qkvz,
                                                   const float* __restrict__ conv_w,
                                                   float* __restrict__ qn,
                                                   float* __restrict__ kn,
                                                   float* __restrict__ vc) {
  const int slot = blockIdx.x;
  const int s    = blockIdx.y;
  const int d    = threadIdx.x;

  int col, ch;
  if (slot < 8) {
    col = slot * 768 + d;
    ch  = slot * 128 + d;
  } else if (slot < 16) {
    const int hk = slot - 8;
    col = hk * 768 + 128 + d;
    ch  = 1024 + hk * 128 + d;
  } else {
    const int vh = slot - 16;
    col = (vh >> 1) * 768 + 256 + (vh & 1) * 128 + d;
    ch  = 2048 + vh * 128 + d;
  }

  float acc = 0.f;
#pragma unroll
  for (int j = 0; j < 4; ++j) {
    const int sr = s - 3 + j;
    const float x = (sr >= 0) ? qkvz[(size_t)sr * NQKVZ + col] : 0.f;
    acc += conv_w[ch * 4 + j] * x;
  }
  float y = acc / (1.f + expf(-acc));  // silu

  if (slot < 16) {
    float ss = y * y;
#pragma unroll
    for (int m = 1; m < 64; m <<= 1) ss += __shfl_xor(ss, m);
    __shared__ float red[2];
    if ((threadIdx.x & 63) == 0) red[threadIdx.x >> 6] = ss;
    __syncthreads();
    const float tot = red[0] + red[1];
    float sc = rsqrtf(tot + 1e-6f);
    if (slot < 8) sc *= 0.08838834764831845f;  // DK^-0.5
    y *= sc;
    if (slot < 8) qn[((size_t)s * 8 + slot) * 128 + d] = y;
    else          kn[((size_t)s * 8 + (slot - 8)) * 128 + d] = y;
  } else {
    vc[((size_t)s * 16 + (slot - 16)) * 128 + d] = y;
  }
}

// ---------------------------------------------------------------------------
// Gated delta rule scan.  128 blocks (16 heads x 8 dv-groups), 256 thr.
// lane layout: dkg = tid&15 owns 8 dk; dvl = tid>>4 is dv column.
// 16-lane reductions via DPP row_ror ring (VALU pipe, no LDS latency).
// 2-step-deep prefetch with statically named A/B buffers.
// ---------------------------------------------------------------------------
#define RORADD(x, ctrl)                                                     \
  x += __int_as_float(__builtin_amdgcn_update_dpp(                          \
      0, __float_as_int(x), ctrl, 0xf, 0xf, true))

__device__ __forceinline__ void scan_load(const float* kbase, const float* qbase,
                                          const float* vbase,
                                          const float* __restrict__ dec,
                                          const float* __restrict__ bet,
                                          int h, int tt,
                                          float k_[8], float q_[8],
                                          float& vv, float& dc, float& bt) {
  const int t_ = (tt < SEQ) ? tt : (SEQ - 1);
  const float4 a = *(const float4*)(kbase + (size_t)t_ * 1024);
  const float4 b = *(const float4*)(kbase + (size_t)t_ * 1024 + 4);
  const float4 c = *(const float4*)(qbase + (size_t)t_ * 1024);
  const float4 d = *(const float4*)(qbase + (size_t)t_ * 1024 + 4);
  k_[0] = a.x; k_[1] = a.y; k_[2] = a.z; k_[3] = a.w;
  k_[4] = b.x; k_[5] = b.y; k_[6] = b.z; k_[7] = b.w;
  q_[0] = c.x; q_[1] = c.y; q_[2] = c.z; q_[3] = c.w;
  q_[4] = d.x; q_[5] = d.y; q_[6] = d.z; q_[7] = d.w;
  vv = vbase[(size_t)t_ * 2048];
  dc = dec[t_ * 16 + h];
  bt = bet[t_ * 16 + h];
}

__device__ __forceinline__ float scan_step(float st[8], const float k_[8],
                                           const float q_[8], float vv,
                                           float dc, float bt) {
  float p0 = 0.f, p1 = 0.f;
#pragma unroll
  for (int i = 0; i < 4; ++i) { st[i] *= dc; p0 = fmaf(k_[i], st[i], p0); }
#pragma unroll
  for (int i = 4; i < 8; ++i) { st[i] *= dc; p1 = fmaf(k_[i], st[i], p1); }
  float p = p0 + p1;
  RORADD(p, 0x121); RORADD(p, 0x122); RORADD(p, 0x124); RORADD(p, 0x128);
  const float delta = (vv - p) * bt;
  float o0 = 0.f, o1 = 0.f;
#pragma unroll
  for (int i = 0; i < 4; ++i) { st[i] = fmaf(k_[i], delta, st[i]); o0 = fmaf(q_[i], st[i], o0); }
#pragma unroll
  for (int i = 4; i < 8; ++i) { st[i] = fmaf(k_[i], delta, st[i]); o1 = fmaf(q_[i], st[i], o1); }
  float o = o0 + o1;
  RORADD(o, 0x121); RORADD(o, 0x122); RORADD(o, 0x124); RORADD(o, 0x128);
  return o;
}

__global__ __launch_bounds__(256) void scan_kernel(const float* __restrict__ qn,
                                                   const float* __restrict__ kn,
                                                   const float* __restrict__ vc,
                                                   const float* __restrict__ dec,
                                                   const float* __restrict__ bet,
                                                   float* __restrict__ obuf) {
  const int h   = blockIdx.x >> 3;
  const int dvg = blockIdx.x & 7;
  const int tid = threadIdx.x;
  const int dkg = tid & 15;
  const int dvl = tid >> 4;
  const int dv  = dvg * 16 + dvl;
  const int hk  = h >> 1;
  const int dk0 = dkg * 8;

  const float* kbase = kn + hk * 128 + dk0;
  const float* qbase = qn + hk * 128 + dk0;
  const float* vbase = vc + h * 128 + dv;

  float st[8];
#pragma unroll
  for (int i = 0; i < 8; ++i) st[i] = 0.f;

  float kA[8], qA[8], vA, dA, bA;
  float kB[8], qB[8], vB, dB, bB;
  scan_load(kbase, qbase, vbase, dec, bet, h, 0, kA, qA, vA, dA, bA);
  scan_load(kbase, qbase, vbase, dec, bet, h, 1, kB, qB, vB, dB, bB);

  for (int t = 0; t < SEQ; t += 2) {
    float o = scan_step(st, kA, qA, vA, dA, bA);
    if (dkg == 0) obuf[((size_t)t * 16 + h) * 128 + dv] = o;
    scan_load(kbase, qbase, vbase, dec, bet, h, t + 2, kA, qA, vA, dA, bA);

    o = scan_step(st, kB, qB, vB, dB, bB);
    if (dkg == 0) obuf[((size_t)(t + 1) * 16 + h) * 128 + dv] = o;
    scan_load(kbase, qbase, vbase, dec, bet, h, t + 3, kB, qB, vB, dB, bB);
  }
}

// ---------------------------------------------------------------------------
// gated RMSNorm -> bf16 output (feeds GEMM2 directly)
// ---------------------------------------------------------------------------
__global__ __launch_bounds__(128) void rmsnorm_kernel(const float* __restrict__ obuf,
                                                      const float* __restrict__ qkvz,
                                                      const float* __restrict__ nw,
                                                      unsigned short* __restrict__ on) {
  const int vh = blockIdx.x;
  const int s  = blockIdx.y;
  const int d  = threadIdx.x;

  const float x = obuf[((size_t)s * 16 + vh) * 128 + d];
  float ss = x * x;
#pragma unroll
  for (int m = 1; m < 64; m <<= 1) ss += __shfl_xor(ss, m);
  __shared__ float red[2];
  if ((threadIdx.x & 63) == 0) red[threadIdx.x >> 6] = ss;
  __syncthreads();
  const float tot = red[0] + red[1];

  const float z = qkvz[(size_t)s * NQKVZ + (vh >> 1) * 768 + 512 + (vh & 1) * 128 + d];
  const float y = x * rsqrtf(tot * (1.f / 128.f) + 1e-6f) * nw[d] *
                  (z / (1.f + expf(-z)));
  on[(size_t)s * 2048 + vh * 128 + d] = f2bf(y);
}

// ---------------------------------------------------------------------------
extern "C" void kernel_launch(void* const* d_in, const int* in_sizes, int n_in,
                              void* d_out, int out_size, void* d_ws, size_t ws_size,
                              hipStream_t stream) {
  const float* hid     = (const float*)d_in[0];
  const float* W_qkvz  = (const float*)d_in[1];
  const float* W_ba    = (const float*)d_in[2];
  const float* conv_w  = (const float*)d_in[3];
  const float* dt_bias = (const float*)d_in[4];
  const float* A_log   = (const float*)d_in[5];
  const float* norm_w  = (const float*)d_in[6];
  const float* W_out   = (const float*)d_in[7];
  float* out = (float*)d_out;

  char* ws = (char*)d_ws;
  // region1: qkvz f32 (live: gemm1 .. rmsnorm)
  float* qkvz = (float*)ws;                 ws += (size_t)SEQ * NQKVZ * 4;   // 24 MB
  // region2: W_qkvz^T bf16 (live: transpose .. gemm1); then reused as
  //          qn(4MB) + kn(4MB) + vc(8MB) + obuf(8MB) = 24 MB exactly
  char* region2 = ws;                       ws += (size_t)HID * NQKVZ * 2;   // 24 MB
  unsigned short* W1t = (unsigned short*)region2;
  float* qn   = (float*)(region2);
  float* kn   = (float*)(region2 + 4194304);
  float* vc   = (float*)(region2 + 8388608);
  float* obuf = (float*)(region2 + 16777216);
  // region3: X bf16 (live through gemm1); reused as on_bf16 after
  unsigned short* Xb = (unsigned short*)ws; ws += (size_t)SEQ * HID * 2;     // 4 MB
  unsigned short* on_bf = Xb;
  // region4: W_out^T bf16
  unsigned short* W2t = (unsigned short*)ws; ws += (size_t)HID * HID * 2;    // 8 MB
  float* dec  = (float*)ws;                  ws += (size_t)SEQ * 16 * 4;
  float* bet  = (float*)ws;                  ws += (size_t)SEQ * 16 * 4;

  // casts / transposes
  cast_bf16<<<dim3(SEQ * HID / 1024), 256, 0, stream>>>(hid, Xb, SEQ * HID);
  transpose_cast<<<dim3(NQKVZ / 32, HID / 32), 256, 0, stream>>>(W_qkvz, W1t, HID, NQKVZ);
  transpose_cast<<<dim3(HID / 32, HID / 32), 256, 0, stream>>>(W_out, W2t, HID, HID);
  // beta / decay
  ba_kernel<<<dim3(SEQ / 8), 256, 0, stream>>>(hid, W_ba, A_log, dt_bias, dec, bet);
  // qkvz = X @ W_qkvz  (bf16 MFMA)
  gemm_bf16<<<dim3(NQKVZ / 128, SEQ / 128), 256, 0, stream>>>(Xb, W1t, qkvz,
                                                              SEQ, NQKVZ, HID);
  // conv + silu + l2norm (overwrites region2 after gemm1 is done with W1t)
  conv_kernel<<<dim3(32, SEQ), 128, 0, stream>>>(qkvz, conv_w, qn, kn, vc);
  // gated delta rule scan
  scan_kernel<<<dim3(128), 256, 0, stream>>>(qn, kn, vc, dec, bet, obuf);
  // gated rmsnorm -> bf16
  rmsnorm_kernel<<<dim3(16, SEQ), 128, 0, stream>>>(obuf, qkvz, norm_w, on_bf);
  // out = on @ W_out  (bf16 MFMA)
  gemm_bf16<<<dim3(HID / 128, SEQ / 128), 256, 0, stream>>>(on_bf, W2t, out,
                                                            SEQ, HID, HID);
}

// Round 3
// 345.825 us; speedup vs baseline: 4.1068x; 1.8419x over previous
//
#include <hip/hip_runtime.h>
#include <hip/hip_bf16.h>
#include <math.h>

// Qwen3-Next GatedDeltaNet, B=1, S=1024, HIDDEN=2048
// H_K=8, H_V=16, DK=DV=128, KDIM=1024, VDIM=2048, CONV_DIM=4096, KS=4
// Scan done via chunked delta rule: C=64, 16 chunks.

#define SEQ 1024
#define HID 2048
#define NQKVZ 6144

typedef __attribute__((ext_vector_type(8))) short short8;
typedef __attribute__((ext_vector_type(4))) float f32x4;

__device__ __forceinline__ unsigned short f2bf(float f) {
  __hip_bfloat16 h = __float2bfloat16(f);
  return *reinterpret_cast<unsigned short*>(&h);
}

// ---------------------------------------------------------------------------
// elementwise f32 -> bf16 cast
// ---------------------------------------------------------------------------
__global__ __launch_bounds__(256) void cast_bf16(const float* __restrict__ in,
                                                 unsigned short* __restrict__ out,
                                                 int n) {
  const int i = (blockIdx.x * 256 + threadIdx.x) * 4;
  if (i < n) {
    const float4 v = *(const float4*)&in[i];
    ushort4 o;
    o.x = f2bf(v.x); o.y = f2bf(v.y); o.z = f2bf(v.z); o.w = f2bf(v.w);
    *(ushort4*)&out[i] = o;
  }
}

// ---------------------------------------------------------------------------
// W[K][N] f32 -> Wt[N][K] bf16
// ---------------------------------------------------------------------------
__global__ __launch_bounds__(256) void transpose_cast(const float* __restrict__ W,
                                                      unsigned short* __restrict__ Wt,
                                                      int K, int N) {
  __shared__ float tile[32][33];
  const int n0 = blockIdx.x * 32, k0 = blockIdx.y * 32;
  const int tx = threadIdx.x & 31, ty = threadIdx.x >> 5;
#pragma unroll
  for (int r = 0; r < 32; r += 8)
    tile[ty + r][tx] = W[(size_t)(k0 + ty + r) * N + n0 + tx];
  __syncthreads();
#pragma unroll
  for (int r = 0; r < 32; r += 8)
    Wt[(size_t)(n0 + ty + r) * K + k0 + tx] = f2bf(tile[tx][ty + r]);
}

// ---------------------------------------------------------------------------
// bf16 MFMA GEMM: C[M][N] f32 = A[M][K] @ Bt[N][K]^T (unchanged from R2)
// ---------------------------------------------------------------------------
__global__ __launch_bounds__(256) void gemm_bf16(const unsigned short* __restrict__ A,
                                                 const unsigned short* __restrict__ Bt,
                                                 float* __restrict__ C,
                                                 int M, int N, int K) {
  __shared__ unsigned short As[128 * 32];
  __shared__ unsigned short Bs[128 * 32];
  char* asb = (char*)As;
  char* bsb = (char*)Bs;

  const int tid  = threadIdx.x;
  const int lane = tid & 63;
  const int w    = tid >> 6;
  const int wm   = w >> 1, wn = w & 1;
  const int row0 = blockIdx.y * 128, col0 = blockIdx.x * 128;

  const int srow = tid >> 1;
  const int skc  = (tid & 1) * 16;
  const int s0   = (tid & 1) * 2;
  const int sw   = srow & 3;

  const int arow = lane & 15;
  const int asl  = (lane >> 4);

  f32x4 acc[4][4];
#pragma unroll
  for (int m = 0; m < 4; ++m)
#pragma unroll
    for (int n = 0; n < 4; ++n) acc[m][n] = (f32x4){0.f, 0.f, 0.f, 0.f};

  for (int k0 = 0; k0 < K; k0 += 32) {
    const unsigned short* ag = A  + (size_t)(row0 + srow) * K + k0 + skc;
    const unsigned short* bg = Bt + (size_t)(col0 + srow) * K + k0 + skc;
    const int4 a0 = *(const int4*)ag;
    const int4 a1 = *(const int4*)(ag + 8);
    const int4 b0 = *(const int4*)bg;
    const int4 b1 = *(const int4*)(bg + 8);
    __syncthreads();
    *(int4*)(asb + srow * 64 + ((s0    ) ^ sw) * 16) = a0;
    *(int4*)(asb + srow * 64 + ((s0 + 1) ^ sw) * 16) = a1;
    *(int4*)(bsb + srow * 64 + ((s0    ) ^ sw) * 16) = b0;
    *(int4*)(bsb + srow * 64 + ((s0 + 1) ^ sw) * 16) = b1;
    __syncthreads();

    short8 af[4], bf[4];
#pragma unroll
    for (int m = 0; m < 4; ++m) {
      const int row = wm * 64 + m * 16 + arow;
      af[m] = *(const short8*)(asb + row * 64 + (asl ^ (row & 3)) * 16);
    }
#pragma unroll
    for (int n = 0; n < 4; ++n) {
      const int row = wn * 64 + n * 16 + arow;
      bf[n] = *(const short8*)(bsb + row * 64 + (asl ^ (row & 3)) * 16);
    }
#pragma unroll
    for (int m = 0; m < 4; ++m)
#pragma unroll
      for (int n = 0; n < 4; ++n)
        acc[m][n] = __builtin_amdgcn_mfma_f32_16x16x32_bf16(af[m], bf[n], acc[m][n], 0, 0, 0);
  }

#pragma unroll
  for (int m = 0; m < 4; ++m)
#pragma unroll
    for (int n = 0; n < 4; ++n) {
      const int r0 = row0 + wm * 64 + m * 16 + (lane >> 4) * 4;
      const int c  = col0 + wn * 64 + n * 16 + (lane & 15);
#pragma unroll
      for (int r = 0; r < 4; ++r)
        C[(size_t)(r0 + r) * N + c] = acc[m][n][r];
    }
}

// ---------------------------------------------------------------------------
// ba = X @ W_ba, fused: beta = sigmoid(b), g = -exp(A_log)*softplus(a+dt)
// ---------------------------------------------------------------------------
__global__ __launch_bounds__(256) void ba_kernel(const float* __restrict__ X,
                                                 const float* __restrict__ W_ba,
                                                 const float* __restrict__ A_log,
                                                 const float* __restrict__ dt_bias,
                                                 float* __restrict__ gbuf,
                                                 float* __restrict__ bet) {
  const int t   = threadIdx.x;
  const int sl  = t >> 5;
  const int col = t & 31;
  const int s   = blockIdx.x * 8 + sl;
  const float* xr = X + (size_t)s * HID;
  const float* wb = W_ba + col;
  float acc = 0.f;
#pragma unroll 8
  for (int k = 0; k < HID; ++k) acc += xr[k] * wb[(size_t)k * 32];

  const int hk = col >> 2, j = col & 3;
  if (j < 2) {
    bet[s * 16 + hk * 2 + j] = 1.f / (1.f + expf(-acc));
  } else {
    const int vh = hk * 2 + (j - 2);
    const float x = acc + dt_bias[vh];
    const float sp = (x > 20.f) ? x : log1pf(expf(x));
    gbuf[s * 16 + vh] = -expf(A_log[vh]) * sp;
  }
}

// ---------------------------------------------------------------------------
// depthwise causal conv (KS=4) + SiLU; l2norm on q,k (q also * DK^-0.5)
// ---------------------------------------------------------------------------
__global__ __launch_bounds__(128) void conv_kernel(const float* __restrict__ qkvz,
                                                   const float* __restrict__ conv_w,
                                                   float* __restrict__ qn,
                                                   float* __restrict__ kn,
                                                   float* __restrict__ vc) {
  const int slot = blockIdx.x;
  const int s    = blockIdx.y;
  const int d    = threadIdx.x;

  int col, ch;
  if (slot < 8) {
    col = slot * 768 + d;
    ch  = slot * 128 + d;
  } else if (slot < 16) {
    const int hk = slot - 8;
    col = hk * 768 + 128 + d;
    ch  = 1024 + hk * 128 + d;
  } else {
    const int vh = slot - 16;
    col = (vh >> 1) * 768 + 256 + (vh & 1) * 128 + d;
    ch  = 2048 + vh * 128 + d;
  }

  float acc = 0.f;
#pragma unroll
  for (int j = 0; j < 4; ++j) {
    const int sr = s - 3 + j;
    const float x = (sr >= 0) ? qkvz[(size_t)sr * NQKVZ + col] : 0.f;
    acc += conv_w[ch * 4 + j] * x;
  }
  float y = acc / (1.f + expf(-acc));  // silu

  if (slot < 16) {
    float ss = y * y;
#pragma unroll
    for (int m = 1; m < 64; m <<= 1) ss += __shfl_xor(ss, m);
    __shared__ float red[2];
    if ((threadIdx.x & 63) == 0) red[threadIdx.x >> 6] = ss;
    __syncthreads();
    const float tot = red[0] + red[1];
    float sc = rsqrtf(tot + 1e-6f);
    if (slot < 8) sc *= 0.08838834764831845f;  // DK^-0.5
    y *= sc;
    if (slot < 8) qn[((size_t)s * 8 + slot) * 128 + d] = y;
    else          kn[((size_t)s * 8 + (slot - 8)) * 128 + d] = y;
  } else {
    vc[((size_t)s * 16 + (slot - 16)) * 128 + d] = y;
  }
}

// ---------------------------------------------------------------------------
// chunk_prep: per (h, c) — cumulative decays, K K^T / Q K^T dots (f32),
// B matrix, T = (I+B)^-1 by forward substitution (f32), and the bf16
// chunk operand matrices for the recurrence.
// grid 256 = h*16+c, 256 threads.
// ---------------------------------------------------------------------------
__global__ __launch_bounds__(256) void chunk_prep(
    const float* __restrict__ qn, const float* __restrict__ kn,
    const float* __restrict__ vc, const float* __restrict__ gbuf,
    const float* __restrict__ bet,
    unsigned short* __restrict__ Tg, unsigned short* __restrict__ Gg,
    unsigned short* __restrict__ Wtg, unsigned short* __restrict__ Qtg,
    unsigned short* __restrict__ Khg, float* __restrict__ bvg,
    float* __restrict__ esg) {
  const int h  = blockIdx.x >> 4;
  const int c  = blockIdx.x & 15;
  const int hk = h >> 1;
  const int tid = threadIdx.x;

  __shared__ float Kf[64][132];
  __shared__ float Qf[64][132];
  __shared__ float Bm[64][65];
  __shared__ float Tm[64][65];
  __shared__ float cg[64];
  __shared__ float btl[64];

  // stage K,Q rows (f32), coalesced
  for (int n = 0; n < 32; ++n) {
    const int lin = tid + 256 * n;
    const int i = lin >> 7, dk = lin & 127;
    Kf[i][dk] = kn[((size_t)(c * 64 + i) * 8 + hk) * 128 + dk];
    Qf[i][dk] = qn[((size_t)(c * 64 + i) * 8 + hk) * 128 + dk];
  }
  if (tid < 64) {
    float g = gbuf[(c * 64 + tid) * 16 + h];
#pragma unroll
    for (int d = 1; d < 64; d <<= 1) {
      const float o = __shfl_up(g, d);
      if (tid >= d) g += o;
    }
    cg[tid] = g;                           // inclusive prefix
    btl[tid] = bet[(c * 64 + tid) * 16 + h];
  }
  __syncthreads();

  // dots: thread t -> row di = t>>2, columns j = (t&3) + 4*jj
  const int di = tid >> 2;
  const int js = tid & 3;
  float kkd[16], qkd[16];
#pragma unroll
  for (int jj = 0; jj < 16; ++jj) { kkd[jj] = 0.f; qkd[jj] = 0.f; }
  for (int kk = 0; kk < 128; kk += 4) {
    const float4 ka = *(const float4*)&Kf[di][kk];
    const float4 qa = *(const float4*)&Qf[di][kk];
#pragma unroll
    for (int jj = 0; jj < 16; ++jj) {
      const float4 kb = *(const float4*)&Kf[js + 4 * jj][kk];
      kkd[jj] += ka.x * kb.x + ka.y * kb.y + ka.z * kb.z + ka.w * kb.w;
      qkd[jj] += qa.x * kb.x + qa.y * kb.y + qa.z * kb.z + qa.w * kb.w;
    }
  }
  const float cgi = cg[di];
  const float bti = btl[di];
#pragma unroll
  for (int jj = 0; jj < 16; ++jj) {
    const int j = js + 4 * jj;
    const float e = __expf(cgi - cg[j]);
    Bm[di][j] = (j < di) ? bti * e * kkd[jj] : 0.f;
    const float gv = (j <= di) ? e * qkd[jj] : 0.f;
    Gg[(size_t)blockIdx.x * 4096 + di * 64 + j] = f2bf(gv);
  }
  __syncthreads();

  // T = (I + B)^-1, forward substitution; lanes = columns (wave 0)
  if (tid < 64) {
    const int l = tid;
    for (int i = 0; i < 64; ++i) {
      float v = (i == l) ? 1.f : 0.f;
      for (int j = 0; j < i; ++j) v -= Bm[i][j] * Tm[j][l];
      Tm[i][l] = v;
    }
  }
  __syncthreads();

  for (int n = 0; n < 16; ++n) {
    const int lin = tid + 256 * n;  // 4096
    Tg[(size_t)blockIdx.x * 4096 + lin] = f2bf(Tm[lin >> 6][lin & 63]);
  }

  const float cglast = cg[63];
  for (int n = 0; n < 32; ++n) {
    const int lin = tid + 256 * n;  // 8192
    const int i = lin >> 7, dk = lin & 127;
    const float ei = __expf(cg[i]);
    Wtg[(size_t)blockIdx.x * 8192 + lin] = f2bf(btl[i] * ei * Kf[i][dk]);
    Qtg[(size_t)blockIdx.x * 8192 + lin] = f2bf(ei * Qf[i][dk]);
    bvg[(size_t)blockIdx.x * 8192 + lin] =
        btl[i] * vc[((size_t)(c * 64 + i) * 16 + h) * 128 + dk];
  }
  for (int n = 0; n < 32; ++n) {
    const int lin = tid + 256 * n;  // 8192, layout [dk][i]
    const int dk = lin >> 6, i = lin & 63;
    Khg[(size_t)blockIdx.x * 8192 + lin] = f2bf(__expf(cglast - cg[i]) * Kf[i][dk]);
  }
  if (tid == 0) esg[blockIdx.x] = __expf(cglast);
}

// ---------------------------------------------------------------------------
// scan_rec: serial over 16 chunks, parallel over (h, dv-block of 16).
// grid 128 = h*8+dvb, 256 thr = 4 waves. Per chunk per wave: 16 MFMAs.
//   u = bv - W~ @ S0 ; d = T @ u ; o = q~ @ S0 + G @ d ; S = es*S0 + K^t @ d
// S lives in MFMA accumulators (f32), bf16 copy in LDS for the B-operand.
// ---------------------------------------------------------------------------
__global__ __launch_bounds__(256) void scan_rec(
    const unsigned short* __restrict__ Tg, const unsigned short* __restrict__ Gg,
    const unsigned short* __restrict__ Wtg, const unsigned short* __restrict__ Qtg,
    const unsigned short* __restrict__ Khg, const float* __restrict__ bvg,
    const float* __restrict__ esg, float* __restrict__ obuf) {
  const int h   = blockIdx.x >> 3;
  const int dvb = blockIdx.x & 7;
  const int dv0 = dvb * 16;
  const int tid = threadIdx.x;
  const int lane = tid & 63;
  const int w   = tid >> 6;
  const int lr  = lane & 15;   // frag row/col low index
  const int lk  = lane >> 4;   // frag k-group 0..3

  __shared__ unsigned short Sb[16][136];  // [dv_local][dk], bf16 copy of S
  __shared__ unsigned short Ub[16][72];   // [dv_local][i]
  __shared__ unsigned short Db[16][72];   // [dv_local][i]

  for (int n = tid; n < 16 * 136 / 2; n += 256) ((unsigned int*)Sb)[n] = 0u;

  f32x4 sacc0 = {0.f, 0.f, 0.f, 0.f};  // dk rows 32w    .. 32w+15
  f32x4 sacc1 = {0.f, 0.f, 0.f, 0.f};  // dk rows 32w+16 .. 32w+31
  __syncthreads();

  for (int c = 0; c < 16; ++c) {
    const size_t base = (size_t)h * 16 + c;
    const unsigned short* T_  = Tg  + base * 4096;
    const unsigned short* G_  = Gg  + base * 4096;
    const unsigned short* W_  = Wtg + base * 8192;
    const unsigned short* Q_  = Qtg + base * 8192;
    const unsigned short* Kh_ = Khg + base * 8192;
    const float* bv_ = bvg + base * 8192;
    const float es = esg[base];

    // ---- step 1: u = bv - W~ @ S0 (wave w owns rows 16w..16w+15)
    f32x4 au = {0.f, 0.f, 0.f, 0.f};
#pragma unroll
    for (int ks = 0; ks < 4; ++ks) {
      const short8 af = *(const short8*)(W_ + (16 * w + lr) * 128 + ks * 32 + lk * 8);
      const short8 bf = *(const short8*)(&Sb[lr][ks * 32 + lk * 8]);
      au = __builtin_amdgcn_mfma_f32_16x16x32_bf16(af, bf, au, 0, 0, 0);
    }
    {
      ushort4 pk;
#pragma unroll
      for (int r = 0; r < 4; ++r) {
        const int i = 16 * w + lk * 4 + r;
        const float bvv = bv_[i * 128 + dv0 + lr];
        ((unsigned short*)&pk)[r] = f2bf(bvv - au[r]);
      }
      *(ushort4*)&Ub[lr][16 * w + lk * 4] = pk;
    }
    __syncthreads();

    // ---- step 2: delta = T @ u
    f32x4 ad = {0.f, 0.f, 0.f, 0.f};
#pragma unroll
    for (int ks = 0; ks < 2; ++ks) {
      const short8 af = *(const short8*)(T_ + (16 * w + lr) * 64 + ks * 32 + lk * 8);
      const short8 bf = *(const short8*)(&Ub[lr][ks * 32 + lk * 8]);
      ad = __builtin_amdgcn_mfma_f32_16x16x32_bf16(af, bf, ad, 0, 0, 0);
    }
    {
      ushort4 pk;
#pragma unroll
      for (int r = 0; r < 4; ++r) ((unsigned short*)&pk)[r] = f2bf(ad[r]);
      *(ushort4*)&Db[lr][16 * w + lk * 4] = pk;
    }
    __syncthreads();

    // ---- step 3: o = q~ @ S0 + G @ delta
    f32x4 ao = {0.f, 0.f, 0.f, 0.f};
#pragma unroll
    for (int ks = 0; ks < 4; ++ks) {
      const short8 af = *(const short8*)(Q_ + (16 * w + lr) * 128 + ks * 32 + lk * 8);
      const short8 bf = *(const short8*)(&Sb[lr][ks * 32 + lk * 8]);
      ao = __builtin_amdgcn_mfma_f32_16x16x32_bf16(af, bf, ao, 0, 0, 0);
    }
#pragma unroll
    for (int ks = 0; ks < 2; ++ks) {
      const short8 af = *(const short8*)(G_ + (16 * w + lr) * 64 + ks * 32 + lk * 8);
      const short8 bf = *(const short8*)(&Db[lr][ks * 32 + lk * 8]);
      ao = __builtin_amdgcn_mfma_f32_16x16x32_bf16(af, bf, ao, 0, 0, 0);
    }
#pragma unroll
    for (int r = 0; r < 4; ++r) {
      const int i = 16 * w + lk * 4 + r;
      const int t = c * 64 + i;
      obuf[((size_t)t * 16 + h) * 128 + dv0 + lr] = ao[r];
    }

    // ---- step 4: S = es*S0 + K^t @ delta (wave w owns dk 32w..32w+31)
    sacc0 *= es;
    sacc1 *= es;
#pragma unroll
    for (int ks = 0; ks < 2; ++ks) {
      const short8 a0 = *(const short8*)(Kh_ + (32 * w + lr) * 64 + ks * 32 + lk * 8);
      const short8 a1 = *(const short8*)(Kh_ + (32 * w + 16 + lr) * 64 + ks * 32 + lk * 8);
      const short8 bf = *(const short8*)(&Db[lr][ks * 32 + lk * 8]);
      sacc0 = __builtin_amdgcn_mfma_f32_16x16x32_bf16(a0, bf, sacc0, 0, 0, 0);
      sacc1 = __builtin_amdgcn_mfma_f32_16x16x32_bf16(a1, bf, sacc1, 0, 0, 0);
    }
    __syncthreads();  // all waves done reading Sb (step 3) and Db

    {
      ushort4 p0, p1;
#pragma unroll
      for (int r = 0; r < 4; ++r) {
        ((unsigned short*)&p0)[r] = f2bf(sacc0[r]);
        ((unsigned short*)&p1)[r] = f2bf(sacc1[r]);
      }
      *(ushort4*)&Sb[lr][32 * w + lk * 4] = p0;
      *(ushort4*)&Sb[lr][32 * w + 16 + lk * 4] = p1;
    }
    __syncthreads();
  }
}

// ---------------------------------------------------------------------------
// gated RMSNorm -> bf16
// ---------------------------------------------------------------------------
__global__ __launch_bounds__(128) void rmsnorm_kernel(const float* __restrict__ obuf,
                                                      const float* __restrict__ qkvz,
                                                      const float* __restrict__ nw,
                                                      unsigned short* __restrict__ on) {
  const int vh = blockIdx.x;
  const int s  = blockIdx.y;
  const int d  = threadIdx.x;

  const float x = obuf[((size_t)s * 16 + vh) * 128 + d];
  float ss = x * x;
#pragma unroll
  for (int m = 1; m < 64; m <<= 1) ss += __shfl_xor(ss, m);
  __shared__ float red[2];
  if ((threadIdx.x & 63) == 0) red[threadIdx.x >> 6] = ss;
  __syncthreads();
  const float tot = red[0] + red[1];

  const float z = qkvz[(size_t)s * NQKVZ + (vh >> 1) * 768 + 512 + (vh & 1) * 128 + d];
  const float y = x * rsqrtf(tot * (1.f / 128.f) + 1e-6f) * nw[d] *
                  (z / (1.f + expf(-z)));
  on[(size_t)s * 2048 + vh * 128 + d] = f2bf(y);
}

// ---------------------------------------------------------------------------
extern "C" void kernel_launch(void* const* d_in, const int* in_sizes, int n_in,
                              void* d_out, int out_size, void* d_ws, size_t ws_size,
                              hipStream_t stream) {
  const float* hid     = (const float*)d_in[0];
  const float* W_qkvz  = (const float*)d_in[1];
  const float* W_ba    = (const float*)d_in[2];
  const float* conv_w  = (const float*)d_in[3];
  const float* dt_bias = (const float*)d_in[4];
  const float* A_log   = (const float*)d_in[5];
  const float* norm_w  = (const float*)d_in[6];
  const float* W_out   = (const float*)d_in[7];
  float* out = (float*)d_out;

  char* ws = (char*)d_ws;
  // region1: qkvz f32 (live gemm1..rmsnorm, z columns)
  float* qkvz = (float*)ws;                 ws += (size_t)SEQ * NQKVZ * 4;   // 24 MB
  // region2: W1t bf16 (until gemm1), then qn+kn+vc+obuf
  char* region2 = ws;                       ws += (size_t)HID * NQKVZ * 2;   // 24 MB
  unsigned short* W1t = (unsigned short*)region2;
  float* qn   = (float*)(region2);
  float* kn   = (float*)(region2 + 4194304);
  float* vc   = (float*)(region2 + 8388608);
  float* obuf = (float*)(region2 + 16777216);
  // region3: X bf16 (until gemm1); reused as on_bf16
  unsigned short* Xb = (unsigned short*)ws; ws += (size_t)SEQ * HID * 2;     // 4 MB
  unsigned short* on_bf = Xb;
  // region4: W_out^T bf16
  unsigned short* W2t = (unsigned short*)ws; ws += (size_t)HID * HID * 2;    // 8 MB
  float* gbuf = (float*)ws;                  ws += (size_t)SEQ * 16 * 4;
  float* bet  = (float*)ws;                  ws += (size_t)SEQ * 16 * 4;
  // chunked-scan operand matrices (256 = 16 heads x 16 chunks)
  unsigned short* Tg  = (unsigned short*)ws; ws += (size_t)256 * 4096 * 2;   // 2 MB
  unsigned short* Gg  = (unsigned short*)ws; ws += (size_t)256 * 4096 * 2;   // 2 MB
  unsigned short* Wtg = (unsigned short*)ws; ws += (size_t)256 * 8192 * 2;   // 4 MB
  unsigned short* Qtg = (unsigned short*)ws; ws += (size_t)256 * 8192 * 2;   // 4 MB
  unsigned short* Khg = (unsigned short*)ws; ws += (size_t)256 * 8192 * 2;   // 4 MB
  float* bvg          = (float*)ws;          ws += (size_t)256 * 8192 * 4;   // 8 MB
  float* esg          = (float*)ws;          ws += 256 * 4;

  cast_bf16<<<dim3(SEQ * HID / 1024), 256, 0, stream>>>(hid, Xb, SEQ * HID);
  transpose_cast<<<dim3(NQKVZ / 32, HID / 32), 256, 0, stream>>>(W_qkvz, W1t, HID, NQKVZ);
  transpose_cast<<<dim3(HID / 32, HID / 32), 256, 0, stream>>>(W_out, W2t, HID, HID);
  ba_kernel<<<dim3(SEQ / 8), 256, 0, stream>>>(hid, W_ba, A_log, dt_bias, gbuf, bet);
  gemm_bf16<<<dim3(NQKVZ / 128, SEQ / 128), 256, 0, stream>>>(Xb, W1t, qkvz,
                                                              SEQ, NQKVZ, HID);
  conv_kernel<<<dim3(32, SEQ), 128, 0, stream>>>(qkvz, conv_w, qn, kn, vc);
  chunk_prep<<<dim3(256), 256, 0, stream>>>(qn, kn, vc, gbuf, bet,
                                            Tg, Gg, Wtg, Qtg, Khg, bvg, esg);
  scan_rec<<<dim3(128), 256, 0, stream>>>(Tg, Gg, Wtg, Qtg, Khg, bvg, esg, obuf);
  rmsnorm_kernel<<<dim3(16, SEQ), 128, 0, stream>>>(obuf, qkvz, norm_w, on_bf);
  gemm_bf16<<<dim3(HID / 128, SEQ / 128), 256, 0, stream>>>(on_bf, W2t, out,
                                                            SEQ, HID, HID);
}

// Round 4
// 286.407 us; speedup vs baseline: 4.9588x; 1.2075x over previous
//
#include <hip/hip_runtime.h>
#include <hip/hip_bf16.h>
#include <math.h>

// Qwen3-Next GatedDeltaNet, B=1, S=1024, HIDDEN=2048
// H_K=8, H_V=16, DK=DV=128, KDIM=1024, VDIM=2048, CONV_DIM=4096, KS=4
// Scan via chunked delta rule: C=64, 16 chunks.

#define SEQ 1024
#define HID 2048
#define NQKVZ 6144

typedef __attribute__((ext_vector_type(8))) short short8;
typedef __attribute__((ext_vector_type(4))) float f32x4;

__device__ __forceinline__ unsigned short f2bf(float f) {
  __hip_bfloat16 h = __float2bfloat16(f);
  return *reinterpret_cast<unsigned short*>(&h);
}

// async global->LDS, 16B per lane (dest = wave-uniform base + lane*16)
typedef __attribute__((address_space(3))) void lds_void;
typedef const __attribute__((address_space(1))) void g_void;
__device__ __forceinline__ void gload16(const void* g, void* l) {
  __builtin_amdgcn_global_load_lds((g_void*)g, (lds_void*)l, 16, 0, 0);
}

// ---------------------------------------------------------------------------
// elementwise f32 -> bf16 cast
// ---------------------------------------------------------------------------
__global__ __launch_bounds__(256) void cast_bf16(const float* __restrict__ in,
                                                 unsigned short* __restrict__ out,
                                                 int n) {
  const int i = (blockIdx.x * 256 + threadIdx.x) * 4;
  if (i < n) {
    const float4 v = *(const float4*)&in[i];
    ushort4 o;
    o.x = f2bf(v.x); o.y = f2bf(v.y); o.z = f2bf(v.z); o.w = f2bf(v.w);
    *(ushort4*)&out[i] = o;
  }
}

// ---------------------------------------------------------------------------
// W[K][N] f32 -> Wt[N][K] bf16
// ---------------------------------------------------------------------------
__global__ __launch_bounds__(256) void transpose_cast(const float* __restrict__ W,
                                                      unsigned short* __restrict__ Wt,
                                                      int K, int N) {
  __shared__ float tile[32][33];
  const int n0 = blockIdx.x * 32, k0 = blockIdx.y * 32;
  const int tx = threadIdx.x & 31, ty = threadIdx.x >> 5;
#pragma unroll
  for (int r = 0; r < 32; r += 8)
    tile[ty + r][tx] = W[(size_t)(k0 + ty + r) * N + n0 + tx];
  __syncthreads();
#pragma unroll
  for (int r = 0; r < 32; r += 8)
    Wt[(size_t)(n0 + ty + r) * K + k0 + tx] = f2bf(tile[tx][ty + r]);
}

// ---------------------------------------------------------------------------
// W[K][N] f32 -> Wt[N][K] f32 (for W_ba)
// ---------------------------------------------------------------------------
__global__ __launch_bounds__(256) void transpose_f32(const float* __restrict__ W,
                                                     float* __restrict__ Wt,
                                                     int K, int N) {
  __shared__ float tile[32][33];
  const int n0 = blockIdx.x * 32, k0 = blockIdx.y * 32;
  const int tx = threadIdx.x & 31, ty = threadIdx.x >> 5;
#pragma unroll
  for (int r = 0; r < 32; r += 8)
    tile[ty + r][tx] = W[(size_t)(k0 + ty + r) * N + n0 + tx];
  __syncthreads();
#pragma unroll
  for (int r = 0; r < 32; r += 8)
    Wt[(size_t)(n0 + ty + r) * K + k0 + tx] = tile[tx][ty + r];
}

// ---------------------------------------------------------------------------
// bf16 MFMA GEMM: C[M][N] f32 = A[M][K] @ Bt[N][K]^T, both bf16 K-contiguous.
// 128x128 tile, BK=32, 4 waves. Staging via global_load_lds width-16 with
// PRE-SWIZZLED global source (LDS dest linear; read side uses the XOR):
//   LDS[row*64B + p*16B] = A[row][(p ^ (row&3))*8 ..]
// ---------------------------------------------------------------------------
__global__ __launch_bounds__(256) void gemm_bf16(const unsigned short* __restrict__ A,
                                                 const unsigned short* __restrict__ Bt,
                                                 float* __restrict__ C,
                                                 int M, int N, int K) {
  __shared__ unsigned short As[128 * 32];
  __shared__ unsigned short Bs[128 * 32];

  const int tid  = threadIdx.x;
  const int lane = tid & 63;
  const int w    = tid >> 6;
  const int wm   = w >> 1, wn = w & 1;
  const int row0 = blockIdx.y * 128, col0 = blockIdx.x * 128;

  // staging: lane covers row r0 = w*16 + (lane>>2), physical slot lane&3,
  // fetches global slot sg = (lane&3) ^ (r0&3)
  const int srow  = lane >> 2;
  const int sslot = lane & 3;
  const int sg    = sslot ^ (srow & 3);
  const int r0s   = w * 16 + srow;

  const unsigned short* agp0 = A  + (size_t)(row0 + r0s) * K + sg * 8;
  const unsigned short* agp1 = agp0 + (size_t)64 * K;
  const unsigned short* bgp0 = Bt + (size_t)(col0 + r0s) * K + sg * 8;
  const unsigned short* bgp1 = bgp0 + (size_t)64 * K;
  char* asw0 = (char*)As + w * 1024;
  char* asw1 = (char*)As + 4096 + w * 1024;
  char* bsw0 = (char*)Bs + w * 1024;
  char* bsw1 = (char*)Bs + 4096 + w * 1024;

  const int arow = lane & 15;
  const int asl  = lane >> 4;
  const char* asb = (const char*)As;
  const char* bsb = (const char*)Bs;

  f32x4 acc[4][4];
#pragma unroll
  for (int m = 0; m < 4; ++m)
#pragma unroll
    for (int n = 0; n < 4; ++n) acc[m][n] = (f32x4){0.f, 0.f, 0.f, 0.f};

  for (int k0 = 0; k0 < K; k0 += 32) {
    __syncthreads();  // previous iteration's LDS reads complete
    gload16(agp0 + k0, asw0);
    gload16(agp1 + k0, asw1);
    gload16(bgp0 + k0, bsw0);
    gload16(bgp1 + k0, bsw1);
    __syncthreads();  // drains vmcnt -> LDS visible

    short8 af[4], bf[4];
#pragma unroll
    for (int m = 0; m < 4; ++m) {
      const int row = wm * 64 + m * 16 + arow;
      af[m] = *(const short8*)(asb + row * 64 + (asl ^ (row & 3)) * 16);
    }
#pragma unroll
    for (int n = 0; n < 4; ++n) {
      const int row = wn * 64 + n * 16 + arow;
      bf[n] = *(const short8*)(bsb + row * 64 + (asl ^ (row & 3)) * 16);
    }
#pragma unroll
    for (int m = 0; m < 4; ++m)
#pragma unroll
      for (int n = 0; n < 4; ++n)
        acc[m][n] = __builtin_amdgcn_mfma_f32_16x16x32_bf16(af[m], bf[n], acc[m][n], 0, 0, 0);
  }

#pragma unroll
  for (int m = 0; m < 4; ++m)
#pragma unroll
    for (int n = 0; n < 4; ++n) {
      const int r0 = row0 + wm * 64 + m * 16 + (lane >> 4) * 4;
      const int c  = col0 + wn * 64 + n * 16 + (lane & 15);
#pragma unroll
      for (int r = 0; r < 4; ++r)
        C[(size_t)(r0 + r) * N + c] = acc[m][n][r];
    }
}

// ---------------------------------------------------------------------------
// ba: split-K GEMV vs W_ba^T[32][2048] f32, fused activations.
// 256 blocks x 256 thr; block = 4 seq rows; thread = (col 0..31, kg 0..7).
// ---------------------------------------------------------------------------
__global__ __launch_bounds__(256) void ba_kernel(const float* __restrict__ X,
                                                 const float* __restrict__ Wbt,
                                                 const float* __restrict__ A_log,
                                                 const float* __restrict__ dt_bias,
                                                 float* __restrict__ gbuf,
                                                 float* __restrict__ bet) {
  const int col = threadIdx.x & 31;
  const int kg  = threadIdx.x >> 5;
  const int s0  = blockIdx.x * 4;
  const float* wp = Wbt + (size_t)col * HID + kg * 256;
  const float* xp = X + (size_t)s0 * HID + kg * 256;

  float a0 = 0.f, a1 = 0.f, a2 = 0.f, a3 = 0.f;
  for (int kk = 0; kk < 256; kk += 4) {
    const float4 w4 = *(const float4*)&wp[kk];
    const float4 x0 = *(const float4*)&xp[kk];
    const float4 x1 = *(const float4*)&xp[kk + HID];
    const float4 x2 = *(const float4*)&xp[kk + 2 * HID];
    const float4 x3 = *(const float4*)&xp[kk + 3 * HID];
    a0 += x0.x * w4.x + x0.y * w4.y + x0.z * w4.z + x0.w * w4.w;
    a1 += x1.x * w4.x + x1.y * w4.y + x1.z * w4.z + x1.w * w4.w;
    a2 += x2.x * w4.x + x2.y * w4.y + x2.z * w4.z + x2.w * w4.w;
    a3 += x3.x * w4.x + x3.y * w4.y + x3.z * w4.z + x3.w * w4.w;
  }
  __shared__ float red[4][32][9];
  red[0][col][kg] = a0;
  red[1][col][kg] = a1;
  red[2][col][kg] = a2;
  red[3][col][kg] = a3;
  __syncthreads();
  if (threadIdx.x < 128) {
    const int r = threadIdx.x >> 5;
    const int c = threadIdx.x & 31;
    float acc = 0.f;
#pragma unroll
    for (int g = 0; g < 8; ++g) acc += red[r][c][g];
    const int s = s0 + r;
    const int hk = c >> 2, j = c & 3;
    if (j < 2) {
      bet[s * 16 + hk * 2 + j] = 1.f / (1.f + expf(-acc));
    } else {
      const int vh = hk * 2 + (j - 2);
      const float x = acc + dt_bias[vh];
      const float sp = (x > 20.f) ? x : log1pf(expf(x));
      gbuf[s * 16 + vh] = -expf(A_log[vh]) * sp;
    }
  }
}

// ---------------------------------------------------------------------------
// depthwise causal conv (KS=4) + SiLU; l2norm on q,k (q also * DK^-0.5)
// ---------------------------------------------------------------------------
__global__ __launch_bounds__(128) void conv_kernel(const float* __restrict__ qkvz,
                                                   const float* __restrict__ conv_w,
                                                   float* __restrict__ qn,
                                                   float* __restrict__ kn,
                                                   float* __restrict__ vc) {
  const int slot = blockIdx.x;
  const int s    = blockIdx.y;
  const int d    = threadIdx.x;

  int col, ch;
  if (slot < 8) {
    col = slot * 768 + d;
    ch  = slot * 128 + d;
  } else if (slot < 16) {
    const int hk = slot - 8;
    col = hk * 768 + 128 + d;
    ch  = 1024 + hk * 128 + d;
  } else {
    const int vh = slot - 16;
    col = (vh >> 1) * 768 + 256 + (vh & 1) * 128 + d;
    ch  = 2048 + vh * 128 + d;
  }

  float acc = 0.f;
#pragma unroll
  for (int j = 0; j < 4; ++j) {
    const int sr = s - 3 + j;
    const float x = (sr >= 0) ? qkvz[(size_t)sr * NQKVZ + col] : 0.f;
    acc += conv_w[ch * 4 + j] * x;
  }
  float y = acc / (1.f + expf(-acc));  // silu

  if (slot < 16) {
    float ss = y * y;
#pragma unroll
    for (int m = 1; m < 64; m <<= 1) ss += __shfl_xor(ss, m);
    __shared__ float red[2];
    if ((threadIdx.x & 63) == 0) red[threadIdx.x >> 6] = ss;
    __syncthreads();
    const float tot = red[0] + red[1];
    float sc = rsqrtf(tot + 1e-6f);
    if (slot < 8) sc *= 0.08838834764831845f;  // DK^-0.5
    y *= sc;
    if (slot < 8) qn[((size_t)s * 8 + slot) * 128 + d] = y;
    else          kn[((size_t)s * 8 + (slot - 8)) * 128 + d] = y;
  } else {
    vc[((size_t)s * 16 + (slot - 16)) * 128 + d] = y;
  }
}

// ---------------------------------------------------------------------------
// chunk_prep: per (h, c) — cumulative decays, K K^T / Q K^T dots (f32),
// B matrix, T = (I+B)^-1 forward substitution (f32), bf16 chunk operands.
// ---------------------------------------------------------------------------
__global__ __launch_bounds__(256) void chunk_prep(
    const float* __restrict__ qn, const float* __restrict__ kn,
    const float* __restrict__ vc, const float* __restrict__ gbuf,
    const float* __restrict__ bet,
    unsigned short* __restrict__ Tg, unsigned short* __restrict__ Gg,
    unsigned short* __restrict__ Wtg, unsigned short* __restrict__ Qtg,
    unsigned short* __restrict__ Khg, float* __restrict__ bvg,
    float* __restrict__ esg) {
  const int h  = blockIdx.x >> 4;
  const int c  = blockIdx.x & 15;
  const int hk = h >> 1;
  const int tid = threadIdx.x;

  __shared__ float Kf[64][132];
  __shared__ float Qf[64][132];
  __shared__ float Bm[64][65];
  __shared__ float Tm[64][65];
  __shared__ float cg[64];
  __shared__ float btl[64];

  for (int n = 0; n < 32; ++n) {
    const int lin = tid + 256 * n;
    const int i = lin >> 7, dk = lin & 127;
    Kf[i][dk] = kn[((size_t)(c * 64 + i) * 8 + hk) * 128 + dk];
    Qf[i][dk] = qn[((size_t)(c * 64 + i) * 8 + hk) * 128 + dk];
  }
  if (tid < 64) {
    float g = gbuf[(c * 64 + tid) * 16 + h];
#pragma unroll
    for (int d = 1; d < 64; d <<= 1) {
      const float o = __shfl_up(g, d);
      if (tid >= d) g += o;
    }
    cg[tid] = g;
    btl[tid] = bet[(c * 64 + tid) * 16 + h];
  }
  __syncthreads();

  const int di = tid >> 2;
  const int js = tid & 3;
  float kkd[16], qkd[16];
#pragma unroll
  for (int jj = 0; jj < 16; ++jj) { kkd[jj] = 0.f; qkd[jj] = 0.f; }
  for (int kk = 0; kk < 128; kk += 4) {
    const float4 ka = *(const float4*)&Kf[di][kk];
    const float4 qa = *(const float4*)&Qf[di][kk];
#pragma unroll
    for (int jj = 0; jj < 16; ++jj) {
      const float4 kb = *(const float4*)&Kf[js + 4 * jj][kk];
      kkd[jj] += ka.x * kb.x + ka.y * kb.y + ka.z * kb.z + ka.w * kb.w;
      qkd[jj] += qa.x * kb.x + qa.y * kb.y + qa.z * kb.z + qa.w * kb.w;
    }
  }
  const float cgi = cg[di];
  const float bti = btl[di];
#pragma unroll
  for (int jj = 0; jj < 16; ++jj) {
    const int j = js + 4 * jj;
    const float e = __expf(cgi - cg[j]);
    Bm[di][j] = (j < di) ? bti * e * kkd[jj] : 0.f;
    const float gv = (j <= di) ? e * qkd[jj] : 0.f;
    Gg[(size_t)blockIdx.x * 4096 + di * 64 + j] = f2bf(gv);
  }
  __syncthreads();

  if (tid < 64) {
    const int l = tid;
    for (int i = 0; i < 64; ++i) {
      float v = (i == l) ? 1.f : 0.f;
      for (int j = 0; j < i; ++j) v -= Bm[i][j] * Tm[j][l];
      Tm[i][l] = v;
    }
  }
  __syncthreads();

  for (int n = 0; n < 16; ++n) {
    const int lin = tid + 256 * n;
    Tg[(size_t)blockIdx.x * 4096 + lin] = f2bf(Tm[lin >> 6][lin & 63]);
  }

  const float cglast = cg[63];
  for (int n = 0; n < 32; ++n) {
    const int lin = tid + 256 * n;
    const int i = lin >> 7, dk = lin & 127;
    const float ei = __expf(cg[i]);
    Wtg[(size_t)blockIdx.x * 8192 + lin] = f2bf(btl[i] * ei * Kf[i][dk]);
    Qtg[(size_t)blockIdx.x * 8192 + lin] = f2bf(ei * Qf[i][dk]);
    bvg[(size_t)blockIdx.x * 8192 + lin] =
        btl[i] * vc[((size_t)(c * 64 + i) * 16 + h) * 128 + dk];
  }
  for (int n = 0; n < 32; ++n) {
    const int lin = tid + 256 * n;  // layout [dk][i]
    const int dk = lin >> 6, i = lin & 63;
    Khg[(size_t)blockIdx.x * 8192 + lin] = f2bf(__expf(cglast - cg[i]) * Kf[i][dk]);
  }
  if (tid == 0) esg[blockIdx.x] = __expf(cglast);
}

// ---------------------------------------------------------------------------
// scan_rec: serial over 16 chunks, parallel over (h, dv-block of 16).
// ---------------------------------------------------------------------------
__global__ __launch_bounds__(256) void scan_rec(
    const unsigned short* __restrict__ Tg, const unsigned short* __restrict__ Gg,
    const unsigned short* __restrict__ Wtg, const unsigned short* __restrict__ Qtg,
    const unsigned short* __restrict__ Khg, const float* __restrict__ bvg,
    const float* __restrict__ esg, float* __restrict__ obuf) {
  const int h   = blockIdx.x >> 3;
  const int dvb = blockIdx.x & 7;
  const int dv0 = dvb * 16;
  const int tid = threadIdx.x;
  const int lane = tid & 63;
  const int w   = tid >> 6;
  const int lr  = lane & 15;
  const int lk  = lane >> 4;

  __shared__ unsigned short Sb[16][136];
  __shared__ unsigned short Ub[16][72];
  __shared__ unsigned short Db[16][72];

  for (int n = tid; n < 16 * 136 / 2; n += 256) ((unsigned int*)Sb)[n] = 0u;

  f32x4 sacc0 = {0.f, 0.f, 0.f, 0.f};
  f32x4 sacc1 = {0.f, 0.f, 0.f, 0.f};
  __syncthreads();

  for (int c = 0; c < 16; ++c) {
    const size_t base = (size_t)h * 16 + c;
    const unsigned short* T_  = Tg  + base * 4096;
    const unsigned short* G_  = Gg  + base * 4096;
    const unsigned short* W_  = Wtg + base * 8192;
    const unsigned short* Q_  = Qtg + base * 8192;
    const unsigned short* Kh_ = Khg + base * 8192;
    const float* bv_ = bvg + base * 8192;
    const float es = esg[base];

    f32x4 au = {0.f, 0.f, 0.f, 0.f};
#pragma unroll
    for (int ks = 0; ks < 4; ++ks) {
      const short8 af = *(const short8*)(W_ + (16 * w + lr) * 128 + ks * 32 + lk * 8);
      const short8 bf = *(const short8*)(&Sb[lr][ks * 32 + lk * 8]);
      au = __builtin_amdgcn_mfma_f32_16x16x32_bf16(af, bf, au, 0, 0, 0);
    }
    {
      ushort4 pk;
#pragma unroll
      for (int r = 0; r < 4; ++r) {
        const int i = 16 * w + lk * 4 + r;
        const float bvv = bv_[i * 128 + dv0 + lr];
        ((unsigned short*)&pk)[r] = f2bf(bvv - au[r]);
      }
      *(ushort4*)&Ub[lr][16 * w + lk * 4] = pk;
    }
    __syncthreads();

    f32x4 ad = {0.f, 0.f, 0.f, 0.f};
#pragma unroll
    for (int ks = 0; ks < 2; ++ks) {
      const short8 af = *(const short8*)(T_ + (16 * w + lr) * 64 + ks * 32 + lk * 8);
      const short8 bf = *(const short8*)(&Ub[lr][ks * 32 + lk * 8]);
      ad = __builtin_amdgcn_mfma_f32_16x16x32_bf16(af, bf, ad, 0, 0, 0);
    }
    {
      ushort4 pk;
#pragma unroll
      for (int r = 0; r < 4; ++r) ((unsigned short*)&pk)[r] = f2bf(ad[r]);
      *(ushort4*)&Db[lr][16 * w + lk * 4] = pk;
    }
    __syncthreads();

    f32x4 ao = {0.f, 0.f, 0.f, 0.f};
#pragma unroll
    for (int ks = 0; ks < 4; ++ks) {
      const short8 af = *(const short8*)(Q_ + (16 * w + lr) * 128 + ks * 32 + lk * 8);
      const short8 bf = *(const short8*)(&Sb[lr][ks * 32 + lk * 8]);
      ao = __builtin_amdgcn_mfma_f32_16x16x32_bf16(af, bf, ao, 0, 0, 0);
    }
#pragma unroll
    for (int ks = 0; ks < 2; ++ks) {
      const short8 af = *(const short8*)(G_ + (16 * w + lr) * 64 + ks * 32 + lk * 8);
      const short8 bf = *(const short8*)(&Db[lr][ks * 32 + lk * 8]);
      ao = __builtin_amdgcn_mfma_f32_16x16x32_bf16(af, bf, ao, 0, 0, 0);
    }
#pragma unroll
    for (int r = 0; r < 4; ++r) {
      const int i = 16 * w + lk * 4 + r;
      const int t = c * 64 + i;
      obuf[((size_t)t * 16 + h) * 128 + dv0 + lr] = ao[r];
    }

    sacc0 *= es;
    sacc1 *= es;
#pragma unroll
    for (int ks = 0; ks < 2; ++ks) {
      const short8 a0 = *(const short8*)(Kh_ + (32 * w + lr) * 64 + ks * 32 + lk * 8);
      const short8 a1 = *(const short8*)(Kh_ + (32 * w + 16 + lr) * 64 + ks * 32 + lk * 8);
      const short8 bf = *(const short8*)(&Db[lr][ks * 32 + lk * 8]);
      sacc0 = __builtin_amdgcn_mfma_f32_16x16x32_bf16(a0, bf, sacc0, 0, 0, 0);
      sacc1 = __builtin_amdgcn_mfma_f32_16x16x32_bf16(a1, bf, sacc1, 0, 0, 0);
    }
    __syncthreads();

    {
      ushort4 p0, p1;
#pragma unroll
      for (int r = 0; r < 4; ++r) {
        ((unsigned short*)&p0)[r] = f2bf(sacc0[r]);
        ((unsigned short*)&p1)[r] = f2bf(sacc1[r]);
      }
      *(ushort4*)&Sb[lr][32 * w + lk * 4] = p0;
      *(ushort4*)&Sb[lr][32 * w + 16 + lk * 4] = p1;
    }
    __syncthreads();
  }
}

// ---------------------------------------------------------------------------
// gated RMSNorm -> bf16
// ---------------------------------------------------------------------------
__global__ __launch_bounds__(128) void rmsnorm_kernel(const float* __restrict__ obuf,
                                                      const float* __restrict__ qkvz,
                                                      const float* __restrict__ nw,
                                                      unsigned short* __restrict__ on) {
  const int vh = blockIdx.x;
  const int s  = blockIdx.y;
  const int d  = threadIdx.x;

  const float x = obuf[((size_t)s * 16 + vh) * 128 + d];
  float ss = x * x;
#pragma unroll
  for (int m = 1; m < 64; m <<= 1) ss += __shfl_xor(ss, m);
  __shared__ float red[2];
  if ((threadIdx.x & 63) == 0) red[threadIdx.x >> 6] = ss;
  __syncthreads();
  const float tot = red[0] + red[1];

  const float z = qkvz[(size_t)s * NQKVZ + (vh >> 1) * 768 + 512 + (vh & 1) * 128 + d];
  const float y = x * rsqrtf(tot * (1.f / 128.f) + 1e-6f) * nw[d] *
                  (z / (1.f + expf(-z)));
  on[(size_t)s * 2048 + vh * 128 + d] = f2bf(y);
}

// ---------------------------------------------------------------------------
extern "C" void kernel_launch(void* const* d_in, const int* in_sizes, int n_in,
                              void* d_out, int out_size, void* d_ws, size_t ws_size,
                              hipStream_t stream) {
  const float* hid     = (const float*)d_in[0];
  const float* W_qkvz  = (const float*)d_in[1];
  const float* W_ba    = (const float*)d_in[2];
  const float* conv_w  = (const float*)d_in[3];
  const float* dt_bias = (const float*)d_in[4];
  const float* A_log   = (const float*)d_in[5];
  const float* norm_w  = (const float*)d_in[6];
  const float* W_out   = (const float*)d_in[7];
  float* out = (float*)d_out;

  char* ws = (char*)d_ws;
  float* qkvz = (float*)ws;                 ws += (size_t)SEQ * NQKVZ * 4;   // 24 MB
  char* region2 = ws;                       ws += (size_t)HID * NQKVZ * 2;   // 24 MB
  unsigned short* W1t = (unsigned short*)region2;
  float* qn   = (float*)(region2);
  float* kn   = (float*)(region2 + 4194304);
  float* vc   = (float*)(region2 + 8388608);
  float* obuf = (float*)(region2 + 16777216);
  unsigned short* Xb = (unsigned short*)ws; ws += (size_t)SEQ * HID * 2;     // 4 MB
  unsigned short* on_bf = Xb;
  unsigned short* W2t = (unsigned short*)ws; ws += (size_t)HID * HID * 2;    // 8 MB
  float* gbuf = (float*)ws;                  ws += (size_t)SEQ * 16 * 4;
  float* bet  = (float*)ws;                  ws += (size_t)SEQ * 16 * 4;
  unsigned short* Tg  = (unsigned short*)ws; ws += (size_t)256 * 4096 * 2;
  unsigned short* Gg  = (unsigned short*)ws; ws += (size_t)256 * 4096 * 2;
  unsigned short* Wtg = (unsigned short*)ws; ws += (size_t)256 * 8192 * 2;
  unsigned short* Qtg = (unsigned short*)ws; ws += (size_t)256 * 8192 * 2;
  unsigned short* Khg = (unsigned short*)ws; ws += (size_t)256 * 8192 * 2;
  float* bvg          = (float*)ws;          ws += (size_t)256 * 8192 * 4;
  float* esg          = (float*)ws;          ws += 256 * 4;
  float* Wbt          = (float*)ws;          ws += (size_t)32 * HID * 4;     // 256 KB

  cast_bf16<<<dim3(SEQ * HID / 1024), 256, 0, stream>>>(hid, Xb, SEQ * HID);
  transpose_cast<<<dim3(NQKVZ / 32, HID / 32), 256, 0, stream>>>(W_qkvz, W1t, HID, NQKVZ);
  transpose_cast<<<dim3(HID / 32, HID / 32), 256, 0, stream>>>(W_out, W2t, HID, HID);
  transpose_f32<<<dim3(1, HID / 32), 256, 0, stream>>>(W_ba, Wbt, HID, 32);
  ba_kernel<<<dim3(SEQ / 4), 256, 0, stream>>>(hid, Wbt, A_log, dt_bias, gbuf, bet);
  gemm_bf16<<<dim3(NQKVZ / 128, SEQ / 128), 256, 0, stream>>>(Xb, W1t, qkvz,
                                                              SEQ, NQKVZ, HID);
  conv_kernel<<<dim3(32, SEQ), 128, 0, stream>>>(qkvz, conv_w, qn, kn, vc);
  chunk_prep<<<dim3(256), 256, 0, stream>>>(qn, kn, vc, gbuf, bet,
                                            Tg, Gg, Wtg, Qtg, Khg, bvg, esg);
  scan_rec<<<dim3(128), 256, 0, stream>>>(Tg, Gg, Wtg, Qtg, Khg, bvg, esg, obuf);
  rmsnorm_kernel<<<dim3(16, SEQ), 128, 0, stream>>>(obuf, qkvz, norm_w, on_bf);
  gemm_bf16<<<dim3(HID / 128, SEQ / 128), 256, 0, stream>>>(on_bf, W2t, out,
                                                            SEQ, HID, HID);
}

// Round 5
// 273.521 us; speedup vs baseline: 5.1925x; 1.0471x over previous
//
#include <hip/hip_runtime.h>
#include <hip/hip_bf16.h>
#include <math.h>

// Qwen3-Next GatedDeltaNet, B=1, S=1024, HIDDEN=2048
// H_K=8, H_V=16, DK=DV=128, KDIM=1024, VDIM=2048, CONV_DIM=4096, KS=4
// Scan via chunked delta rule: C=64, 16 chunks.

#define SEQ 1024
#define HID 2048
#define NQKVZ 6144

typedef __attribute__((ext_vector_type(8))) short short8;
typedef __attribute__((ext_vector_type(4))) float f32x4;

__device__ __forceinline__ unsigned short f2bf(float f) {
  __hip_bfloat16 h = __float2bfloat16(f);
  return *reinterpret_cast<unsigned short*>(&h);
}
__device__ __forceinline__ float bf2f(unsigned short u) {
  unsigned int x = ((unsigned int)u) << 16;
  return __int_as_float(x);
}

// async global->LDS, 16B per lane (dest = wave-uniform base + lane*16)
typedef __attribute__((address_space(3))) void lds_void;
typedef const __attribute__((address_space(1))) void g_void;
__device__ __forceinline__ void gload16(const void* g, void* l) {
  __builtin_amdgcn_global_load_lds((g_void*)g, (lds_void*)l, 16, 0, 0);
}

// ---------------------------------------------------------------------------
// elementwise f32 -> bf16 cast
// ---------------------------------------------------------------------------
__global__ __launch_bounds__(256) void cast_bf16(const float* __restrict__ in,
                                                 unsigned short* __restrict__ out,
                                                 int n) {
  const int i = (blockIdx.x * 256 + threadIdx.x) * 4;
  if (i < n) {
    const float4 v = *(const float4*)&in[i];
    ushort4 o;
    o.x = f2bf(v.x); o.y = f2bf(v.y); o.z = f2bf(v.z); o.w = f2bf(v.w);
    *(ushort4*)&out[i] = o;
  }
}

// ---------------------------------------------------------------------------
// W[K][N] f32 -> Wt[N][K] bf16
// ---------------------------------------------------------------------------
__global__ __launch_bounds__(256) void transpose_cast(const float* __restrict__ W,
                                                      unsigned short* __restrict__ Wt,
                                                      int K, int N) {
  __shared__ float tile[32][33];
  const int n0 = blockIdx.x * 32, k0 = blockIdx.y * 32;
  const int tx = threadIdx.x & 31, ty = threadIdx.x >> 5;
#pragma unroll
  for (int r = 0; r < 32; r += 8)
    tile[ty + r][tx] = W[(size_t)(k0 + ty + r) * N + n0 + tx];
  __syncthreads();
#pragma unroll
  for (int r = 0; r < 32; r += 8)
    Wt[(size_t)(n0 + ty + r) * K + k0 + tx] = f2bf(tile[tx][ty + r]);
}

// ---------------------------------------------------------------------------
// W[K][N] f32 -> Wt[N][K] f32 (for W_ba)
// ---------------------------------------------------------------------------
__global__ __launch_bounds__(256) void transpose_f32(const float* __restrict__ W,
                                                     float* __restrict__ Wt,
                                                     int K, int N) {
  __shared__ float tile[32][33];
  const int n0 = blockIdx.x * 32, k0 = blockIdx.y * 32;
  const int tx = threadIdx.x & 31, ty = threadIdx.x >> 5;
#pragma unroll
  for (int r = 0; r < 32; r += 8)
    tile[ty + r][tx] = W[(size_t)(k0 + ty + r) * N + n0 + tx];
  __syncthreads();
#pragma unroll
  for (int r = 0; r < 32; r += 8)
    Wt[(size_t)(n0 + ty + r) * K + k0 + tx] = tile[tx][ty + r];
}

// ---------------------------------------------------------------------------
// bf16 MFMA GEMM: C[M][N] f32 = A[M][K] @ Bt[N][K]^T, both bf16 K-contiguous.
// 128x128 tile, BK=32, 4 waves. Staging via global_load_lds width-16 with
// PRE-SWIZZLED global source (LDS dest linear; read side uses the XOR).
// ---------------------------------------------------------------------------
__global__ __launch_bounds__(256) void gemm_bf16(const unsigned short* __restrict__ A,
                                                 const unsigned short* __restrict__ Bt,
                                                 float* __restrict__ C,
                                                 int M, int N, int K) {
  __shared__ unsigned short As[128 * 32];
  __shared__ unsigned short Bs[128 * 32];

  const int tid  = threadIdx.x;
  const int lane = tid & 63;
  const int w    = tid >> 6;
  const int wm   = w >> 1, wn = w & 1;
  const int row0 = blockIdx.y * 128, col0 = blockIdx.x * 128;

  const int srow  = lane >> 2;
  const int sslot = lane & 3;
  const int sg    = sslot ^ (srow & 3);
  const int r0s   = w * 16 + srow;

  const unsigned short* agp0 = A  + (size_t)(row0 + r0s) * K + sg * 8;
  const unsigned short* agp1 = agp0 + (size_t)64 * K;
  const unsigned short* bgp0 = Bt + (size_t)(col0 + r0s) * K + sg * 8;
  const unsigned short* bgp1 = bgp0 + (size_t)64 * K;
  char* asw0 = (char*)As + w * 1024;
  char* asw1 = (char*)As + 4096 + w * 1024;
  char* bsw0 = (char*)Bs + w * 1024;
  char* bsw1 = (char*)Bs + 4096 + w * 1024;

  const int arow = lane & 15;
  const int asl  = lane >> 4;
  const char* asb = (const char*)As;
  const char* bsb = (const char*)Bs;

  f32x4 acc[4][4];
#pragma unroll
  for (int m = 0; m < 4; ++m)
#pragma unroll
    for (int n = 0; n < 4; ++n) acc[m][n] = (f32x4){0.f, 0.f, 0.f, 0.f};

  for (int k0 = 0; k0 < K; k0 += 32) {
    __syncthreads();
    gload16(agp0 + k0, asw0);
    gload16(agp1 + k0, asw1);
    gload16(bgp0 + k0, bsw0);
    gload16(bgp1 + k0, bsw1);
    __syncthreads();

    short8 af[4], bf[4];
#pragma unroll
    for (int m = 0; m < 4; ++m) {
      const int row = wm * 64 + m * 16 + arow;
      af[m] = *(const short8*)(asb + row * 64 + (asl ^ (row & 3)) * 16);
    }
#pragma unroll
    for (int n = 0; n < 4; ++n) {
      const int row = wn * 64 + n * 16 + arow;
      bf[n] = *(const short8*)(bsb + row * 64 + (asl ^ (row & 3)) * 16);
    }
#pragma unroll
    for (int m = 0; m < 4; ++m)
#pragma unroll
      for (int n = 0; n < 4; ++n)
        acc[m][n] = __builtin_amdgcn_mfma_f32_16x16x32_bf16(af[m], bf[n], acc[m][n], 0, 0, 0);
  }

#pragma unroll
  for (int m = 0; m < 4; ++m)
#pragma unroll
    for (int n = 0; n < 4; ++n) {
      const int r0 = row0 + wm * 64 + m * 16 + (lane >> 4) * 4;
      const int c  = col0 + wn * 64 + n * 16 + (lane & 15);
#pragma unroll
      for (int r = 0; r < 4; ++r)
        C[(size_t)(r0 + r) * N + c] = acc[m][n][r];
    }
}

// ---------------------------------------------------------------------------
// ba: split-K GEMV vs W_ba^T[32][2048] f32, fused activations.
// ---------------------------------------------------------------------------
__global__ __launch_bounds__(256) void ba_kernel(const float* __restrict__ X,
                                                 const float* __restrict__ Wbt,
                                                 const float* __restrict__ A_log,
                                                 const float* __restrict__ dt_bias,
                                                 float* __restrict__ gbuf,
                                                 float* __restrict__ bet) {
  const int col = threadIdx.x & 31;
  const int kg  = threadIdx.x >> 5;
  const int s0  = blockIdx.x * 4;
  const float* wp = Wbt + (size_t)col * HID + kg * 256;
  const float* xp = X + (size_t)s0 * HID + kg * 256;

  float a0 = 0.f, a1 = 0.f, a2 = 0.f, a3 = 0.f;
  for (int kk = 0; kk < 256; kk += 4) {
    const float4 w4 = *(const float4*)&wp[kk];
    const float4 x0 = *(const float4*)&xp[kk];
    const float4 x1 = *(const float4*)&xp[kk + HID];
    const float4 x2 = *(const float4*)&xp[kk + 2 * HID];
    const float4 x3 = *(const float4*)&xp[kk + 3 * HID];
    a0 += x0.x * w4.x + x0.y * w4.y + x0.z * w4.z + x0.w * w4.w;
    a1 += x1.x * w4.x + x1.y * w4.y + x1.z * w4.z + x1.w * w4.w;
    a2 += x2.x * w4.x + x2.y * w4.y + x2.z * w4.z + x2.w * w4.w;
    a3 += x3.x * w4.x + x3.y * w4.y + x3.z * w4.z + x3.w * w4.w;
  }
  __shared__ float red[4][32][9];
  red[0][col][kg] = a0;
  red[1][col][kg] = a1;
  red[2][col][kg] = a2;
  red[3][col][kg] = a3;
  __syncthreads();
  if (threadIdx.x < 128) {
    const int r = threadIdx.x >> 5;
    const int c = threadIdx.x & 31;
    float acc = 0.f;
#pragma unroll
    for (int g = 0; g < 8; ++g) acc += red[r][c][g];
    const int s = s0 + r;
    const int hk = c >> 2, j = c & 3;
    if (j < 2) {
      bet[s * 16 + hk * 2 + j] = 1.f / (1.f + expf(-acc));
    } else {
      const int vh = hk * 2 + (j - 2);
      const float x = acc + dt_bias[vh];
      const float sp = (x > 20.f) ? x : log1pf(expf(x));
      gbuf[s * 16 + vh] = -expf(A_log[vh]) * sp;
    }
  }
}

// ---------------------------------------------------------------------------
// depthwise causal conv (KS=4) + SiLU; l2norm on q,k (q also * DK^-0.5)
// ---------------------------------------------------------------------------
__global__ __launch_bounds__(128) void conv_kernel(const float* __restrict__ qkvz,
                                                   const float* __restrict__ conv_w,
                                                   float* __restrict__ qn,
                                                   float* __restrict__ kn,
                                                   float* __restrict__ vc) {
  const int slot = blockIdx.x;
  const int s    = blockIdx.y;
  const int d    = threadIdx.x;

  int col, ch;
  if (slot < 8) {
    col = slot * 768 + d;
    ch  = slot * 128 + d;
  } else if (slot < 16) {
    const int hk = slot - 8;
    col = hk * 768 + 128 + d;
    ch  = 1024 + hk * 128 + d;
  } else {
    const int vh = slot - 16;
    col = (vh >> 1) * 768 + 256 + (vh & 1) * 128 + d;
    ch  = 2048 + vh * 128 + d;
  }

  float acc = 0.f;
#pragma unroll
  for (int j = 0; j < 4; ++j) {
    const int sr = s - 3 + j;
    const float x = (sr >= 0) ? qkvz[(size_t)sr * NQKVZ + col] : 0.f;
    acc += conv_w[ch * 4 + j] * x;
  }
  float y = acc / (1.f + expf(-acc));  // silu

  if (slot < 16) {
    float ss = y * y;
#pragma unroll
    for (int m = 1; m < 64; m <<= 1) ss += __shfl_xor(ss, m);
    __shared__ float red[2];
    if ((threadIdx.x & 63) == 0) red[threadIdx.x >> 6] = ss;
    __syncthreads();
    const float tot = red[0] + red[1];
    float sc = rsqrtf(tot + 1e-6f);
    if (slot < 8) sc *= 0.08838834764831845f;  // DK^-0.5
    y *= sc;
    if (slot < 8) qn[((size_t)s * 8 + slot) * 128 + d] = y;
    else          kn[((size_t)s * 8 + (slot - 8)) * 128 + d] = y;
  } else {
    vc[((size_t)s * 16 + (slot - 16)) * 128 + d] = y;
  }
}

// ---------------------------------------------------------------------------
// chunk_prep v2: K,Q staged bf16 in XOR-swizzled LDS; KK^T/QK^T via MFMA;
// B bf16; T=(I+B)^-1 f32 forward substitution (wave 0); bf16 operand outputs.
// LDS ~57KB -> 2 blocks/CU.
// ---------------------------------------------------------------------------
__global__ __launch_bounds__(256) void chunk_prep(
    const float* __restrict__ qn, const float* __restrict__ kn,
    const float* __restrict__ vc, const float* __restrict__ gbuf,
    const float* __restrict__ bet,
    unsigned short* __restrict__ Tg, unsigned short* __restrict__ Gg,
    unsigned short* __restrict__ Wtg, unsigned short* __restrict__ Qtg,
    unsigned short* __restrict__ Khg, float* __restrict__ bvg,
    float* __restrict__ esg) {
  const int h  = blockIdx.x >> 4;
  const int c  = blockIdx.x & 15;
  const int hk = h >> 1;
  const int tid = threadIdx.x;
  const int lane = tid & 63;
  const int w    = tid >> 6;
  const int lr   = lane & 15;
  const int lk   = lane >> 4;

  __shared__ unsigned short Kb[64 * 128];   // 16 KB, swizzled rows of 256B
  __shared__ unsigned short Qb[64 * 128];   // 16 KB
  __shared__ unsigned short Bm[64][64];     // 8 KB  (bf16 B matrix)
  __shared__ float Tm[64][65];              // 16.6 KB
  __shared__ float cg[64];
  __shared__ float btl[64];

  // ---- stage K,Q as bf16, swizzled: byte = row*256 + ((col*2) ^ ((row&7)<<4))
#pragma unroll
  for (int n = 0; n < 8; ++n) {
    const int idx = tid + 256 * n;         // 2048 float4-groups
    const int row = idx >> 5;
    const int col = (idx & 31) * 4;
    const float4 kv = *(const float4*)&kn[((size_t)(c * 64 + row) * 8 + hk) * 128 + col];
    const float4 qv = *(const float4*)&qn[((size_t)(c * 64 + row) * 8 + hk) * 128 + col];
    const int boff = row * 256 + ((col * 2) ^ ((row & 7) << 4));
    ushort4 ko = {f2bf(kv.x), f2bf(kv.y), f2bf(kv.z), f2bf(kv.w)};
    ushort4 qo = {f2bf(qv.x), f2bf(qv.y), f2bf(qv.z), f2bf(qv.w)};
    *(ushort4*)((char*)Kb + boff) = ko;
    *(ushort4*)((char*)Qb + boff) = qo;
  }
  if (tid < 64) {
    float g = gbuf[(c * 64 + tid) * 16 + h];
#pragma unroll
    for (int d = 1; d < 64; d <<= 1) {
      const float o = __shfl_up(g, d);
      if (tid >= d) g += o;
    }
    cg[tid] = g;
    btl[tid] = bet[(c * 64 + tid) * 16 + h];
  }
  __syncthreads();

  // ---- KK^T and QK^T via MFMA: wave w owns rows 16w..16w+15
  f32x4 kkacc[4], qkacc[4];
#pragma unroll
  for (int ct = 0; ct < 4; ++ct) {
    kkacc[ct] = (f32x4){0.f, 0.f, 0.f, 0.f};
    qkacc[ct] = (f32x4){0.f, 0.f, 0.f, 0.f};
  }
  {
    const int rowA = 16 * w + lr;
    const int swA  = (rowA & 7) << 4;
#pragma unroll
    for (int ks = 0; ks < 4; ++ks) {
      const int kb = ks * 64 + lk * 16;
      const short8 aK = *(const short8*)((char*)Kb + rowA * 256 + (kb ^ swA));
      const short8 aQ = *(const short8*)((char*)Qb + rowA * 256 + (kb ^ swA));
#pragma unroll
      for (int ct = 0; ct < 4; ++ct) {
        const int rowB = ct * 16 + lr;
        const short8 bK = *(const short8*)((char*)Kb + rowB * 256 + (kb ^ ((rowB & 7) << 4)));
        kkacc[ct] = __builtin_amdgcn_mfma_f32_16x16x32_bf16(aK, bK, kkacc[ct], 0, 0, 0);
        qkacc[ct] = __builtin_amdgcn_mfma_f32_16x16x32_bf16(aQ, bK, qkacc[ct], 0, 0, 0);
      }
    }
  }
  // epilogue: B (bf16 LDS) and G (bf16 global)
#pragma unroll
  for (int ct = 0; ct < 4; ++ct) {
#pragma unroll
    for (int r = 0; r < 4; ++r) {
      const int i = 16 * w + lk * 4 + r;
      const int j = ct * 16 + lr;
      const float e = __expf(cg[i] - cg[j]);
      Bm[i][j] = f2bf((j < i) ? btl[i] * e * kkacc[ct][r] : 0.f);
      const float gv = (j <= i) ? e * qkacc[ct][r] : 0.f;
      Gg[(size_t)blockIdx.x * 4096 + i * 64 + j] = f2bf(gv);
    }
  }
  __syncthreads();

  // ---- T = (I + B)^-1, forward substitution; wave 0, lanes = columns
  if (tid < 64) {
    const int l = tid;
    for (int i = 0; i < 64; ++i) {
      float v = (i == l) ? 1.f : 0.f;
      for (int j = 0; j < i; ++j) v -= bf2f(Bm[i][j]) * Tm[j][l];
      Tm[i][l] = v;
    }
  }
  __syncthreads();

#pragma unroll
  for (int n = 0; n < 16; ++n) {
    const int lin = tid + 256 * n;
    Tg[(size_t)blockIdx.x * 4096 + lin] = f2bf(Tm[lin >> 6][lin & 63]);
  }

  // ---- chunk operand outputs
  const float cglast = cg[63];
#pragma unroll
  for (int n = 0; n < 8; ++n) {
    const int idx = tid + 256 * n;         // 2048 groups of 4
    const int i = idx >> 5;
    const int dk = (idx & 31) * 4;
    const int boff = i * 256 + ((dk * 2) ^ ((i & 7) << 4));
    const ushort4 kq = *(const ushort4*)((char*)Kb + boff);
    const ushort4 qq = *(const ushort4*)((char*)Qb + boff);
    const float ei = __expf(cg[i]);
    const float wi = btl[i] * ei;
    ushort4 wo = {f2bf(wi * bf2f(kq.x)), f2bf(wi * bf2f(kq.y)),
                  f2bf(wi * bf2f(kq.z)), f2bf(wi * bf2f(kq.w))};
    ushort4 qo = {f2bf(ei * bf2f(qq.x)), f2bf(ei * bf2f(qq.y)),
                  f2bf(ei * bf2f(qq.z)), f2bf(ei * bf2f(qq.w))};
    *(ushort4*)&Wtg[(size_t)blockIdx.x * 8192 + i * 128 + dk] = wo;
    *(ushort4*)&Qtg[(size_t)blockIdx.x * 8192 + i * 128 + dk] = qo;
    const float4 vv = *(const float4*)&vc[((size_t)(c * 64 + i) * 16 + h) * 128 + dk];
    float4 bv4 = {btl[i] * vv.x, btl[i] * vv.y, btl[i] * vv.z, btl[i] * vv.w};
    *(float4*)&bvg[(size_t)blockIdx.x * 8192 + i * 128 + dk] = bv4;
  }
#pragma unroll
  for (int n = 0; n < 32; ++n) {
    const int lin = tid + 256 * n;         // layout [dk][i]
    const int dk = lin >> 6, i = lin & 63;
    const unsigned short kraw =
        *(const unsigned short*)((char*)Kb + i * 256 + ((dk * 2) ^ ((i & 7) << 4)));
    Khg[(size_t)blockIdx.x * 8192 + lin] = f2bf(__expf(cglast - cg[i]) * bf2f(kraw));
  }
  if (tid == 0) esg[blockIdx.x] = __expf(cglast);
}

// ---------------------------------------------------------------------------
// scan_rec: serial over 16 chunks, parallel over (h, dv-block of 16).
// ---------------------------------------------------------------------------
__global__ __launch_bounds__(256) void scan_rec(
    const unsigned short* __restrict__ Tg, const unsigned short* __restrict__ Gg,
    const unsigned short* __restrict__ Wtg, const unsigned short* __restrict__ Qtg,
    const unsigned short* __restrict__ Khg, const float* __restrict__ bvg,
    const float* __restrict__ esg, float* __restrict__ obuf) {
  const int h   = blockIdx.x >> 3;
  const int dvb = blockIdx.x & 7;
  const int dv0 = dvb * 16;
  const int tid = threadIdx.x;
  const int lane = tid & 63;
  const int w   = tid >> 6;
  const int lr  = lane & 15;
  const int lk  = lane >> 4;

  __shared__ unsigned short Sb[16][136];
  __shared__ unsigned short Ub[16][72];
  __shared__ unsigned short Db[16][72];

  for (int n = tid; n < 16 * 136 / 2; n += 256) ((unsigned int*)Sb)[n] = 0u;

  f32x4 sacc0 = {0.f, 0.f, 0.f, 0.f};
  f32x4 sacc1 = {0.f, 0.f, 0.f, 0.f};
  __syncthreads();

  for (int c = 0; c < 16; ++c) {
    const size_t base = (size_t)h * 16 + c;
    const unsigned short* T_  = Tg  + base * 4096;
    const unsigned short* G_  = Gg  + base * 4096;
    const unsigned short* W_  = Wtg + base * 8192;
    const unsigned short* Q_  = Qtg + base * 8192;
    const unsigned short* Kh_ = Khg + base * 8192;
    const float* bv_ = bvg + base * 8192;
    const float es = esg[base];

    f32x4 au = {0.f, 0.f, 0.f, 0.f};
#pragma unroll
    for (int ks = 0; ks < 4; ++ks) {
      const short8 af = *(const short8*)(W_ + (16 * w + lr) * 128 + ks * 32 + lk * 8);
      const short8 bf = *(const short8*)(&Sb[lr][ks * 32 + lk * 8]);
      au = __builtin_amdgcn_mfma_f32_16x16x32_bf16(af, bf, au, 0, 0, 0);
    }
    {
      ushort4 pk;
#pragma unroll
      for (int r = 0; r < 4; ++r) {
        const int i = 16 * w + lk * 4 + r;
        const float bvv = bv_[i * 128 + dv0 + lr];
        ((unsigned short*)&pk)[r] = f2bf(bvv - au[r]);
      }
      *(ushort4*)&Ub[lr][16 * w + lk * 4] = pk;
    }
    __syncthreads();

    f32x4 ad = {0.f, 0.f, 0.f, 0.f};
#pragma unroll
    for (int ks = 0; ks < 2; ++ks) {
      const short8 af = *(const short8*)(T_ + (16 * w + lr) * 64 + ks * 32 + lk * 8);
      const short8 bf = *(const short8*)(&Ub[lr][ks * 32 + lk * 8]);
      ad = __builtin_amdgcn_mfma_f32_16x16x32_bf16(af, bf, ad, 0, 0, 0);
    }
    {
      ushort4 pk;
#pragma unroll
      for (int r = 0; r < 4; ++r) ((unsigned short*)&pk)[r] = f2bf(ad[r]);
      *(ushort4*)&Db[lr][16 * w + lk * 4] = pk;
    }
    __syncthreads();

    f32x4 ao = {0.f, 0.f, 0.f, 0.f};
#pragma unroll
    for (int ks = 0; ks < 4; ++ks) {
      const short8 af = *(const short8*)(Q_ + (16 * w + lr) * 128 + ks * 32 + lk * 8);
      const short8 bf = *(const short8*)(&Sb[lr][ks * 32 + lk * 8]);
      ao = __builtin_amdgcn_mfma_f32_16x16x32_bf16(af, bf, ao, 0, 0, 0);
    }
#pragma unroll
    for (int ks = 0; ks < 2; ++ks) {
      const short8 af = *(const short8*)(G_ + (16 * w + lr) * 64 + ks * 32 + lk * 8);
      const short8 bf = *(const short8*)(&Db[lr][ks * 32 + lk * 8]);
      ao = __builtin_amdgcn_mfma_f32_16x16x32_bf16(af, bf, ao, 0, 0, 0);
    }
#pragma unroll
    for (int r = 0; r < 4; ++r) {
      const int i = 16 * w + lk * 4 + r;
      const int t = c * 64 + i;
      obuf[((size_t)t * 16 + h) * 128 + dv0 + lr] = ao[r];
    }

    sacc0 *= es;
    sacc1 *= es;
#pragma unroll
    for (int ks = 0; ks < 2; ++ks) {
      const short8 a0 = *(const short8*)(Kh_ + (32 * w + lr) * 64 + ks * 32 + lk * 8);
      const short8 a1 = *(const short8*)(Kh_ + (32 * w + 16 + lr) * 64 + ks * 32 + lk * 8);
      const short8 bf = *(const short8*)(&Db[lr][ks * 32 + lk * 8]);
      sacc0 = __builtin_amdgcn_mfma_f32_16x16x32_bf16(a0, bf, sacc0, 0, 0, 0);
      sacc1 = __builtin_amdgcn_mfma_f32_16x16x32_bf16(a1, bf, sacc1, 0, 0, 0);
    }
    __syncthreads();

    {
      ushort4 p0, p1;
#pragma unroll
      for (int r = 0; r < 4; ++r) {
        ((unsigned short*)&p0)[r] = f2bf(sacc0[r]);
        ((unsigned short*)&p1)[r] = f2bf(sacc1[r]);
      }
      *(ushort4*)&Sb[lr][32 * w + lk * 4] = p0;
      *(ushort4*)&Sb[lr][32 * w + 16 + lk * 4] = p1;
    }
    __syncthreads();
  }
}

// ---------------------------------------------------------------------------
// gated RMSNorm -> bf16
// ---------------------------------------------------------------------------
__global__ __launch_bounds__(128) void rmsnorm_kernel(const float* __restrict__ obuf,
                                                      const float* __restrict__ qkvz,
                                                      const float* __restrict__ nw,
                                                      unsigned short* __restrict__ on) {
  const int vh = blockIdx.x;
  const int s  = blockIdx.y;
  const int d  = threadIdx.x;

  const float x = obuf[((size_t)s * 16 + vh) * 128 + d];
  float ss = x * x;
#pragma unroll
  for (int m = 1; m < 64; m <<= 1) ss += __shfl_xor(ss, m);
  __shared__ float red[2];
  if ((threadIdx.x & 63) == 0) red[threadIdx.x >> 6] = ss;
  __syncthreads();
  const float tot = red[0] + red[1];

  const float z = qkvz[(size_t)s * NQKVZ + (vh >> 1) * 768 + 512 + (vh & 1) * 128 + d];
  const float y = x * rsqrtf(tot * (1.f / 128.f) + 1e-6f) * nw[d] *
                  (z / (1.f + expf(-z)));
  on[(size_t)s * 2048 + vh * 128 + d] = f2bf(y);
}

// ---------------------------------------------------------------------------
extern "C" void kernel_launch(void* const* d_in, const int* in_sizes, int n_in,
                              void* d_out, int out_size, void* d_ws, size_t ws_size,
                              hipStream_t stream) {
  const float* hid     = (const float*)d_in[0];
  const float* W_qkvz  = (const float*)d_in[1];
  const float* W_ba    = (const float*)d_in[2];
  const float* conv_w  = (const float*)d_in[3];
  const float* dt_bias = (const float*)d_in[4];
  const float* A_log   = (const float*)d_in[5];
  const float* norm_w  = (const float*)d_in[6];
  const float* W_out   = (const float*)d_in[7];
  float* out = (float*)d_out;

  char* ws = (char*)d_ws;
  float* qkvz = (float*)ws;                 ws += (size_t)SEQ * NQKVZ * 4;   // 24 MB
  char* region2 = ws;                       ws += (size_t)HID * NQKVZ * 2;   // 24 MB
  unsigned short* W1t = (unsigned short*)region2;
  float* qn   = (float*)(region2);
  float* kn   = (float*)(region2 + 4194304);
  float* vc   = (float*)(region2 + 8388608);
  float* obuf = (float*)(region2 + 16777216);
  unsigned short* Xb = (unsigned short*)ws; ws += (size_t)SEQ * HID * 2;     // 4 MB
  unsigned short* on_bf = Xb;
  unsigned short* W2t = (unsigned short*)ws; ws += (size_t)HID * HID * 2;    // 8 MB
  float* gbuf = (float*)ws;                  ws += (size_t)SEQ * 16 * 4;
  float* bet  = (float*)ws;                  ws += (size_t)SEQ * 16 * 4;
  unsigned short* Tg  = (unsigned short*)ws; ws += (size_t)256 * 4096 * 2;
  unsigned short* Gg  = (unsigned short*)ws; ws += (size_t)256 * 4096 * 2;
  unsigned short* Wtg = (unsigned short*)ws; ws += (size_t)256 * 8192 * 2;
  unsigned short* Qtg = (unsigned short*)ws; ws += (size_t)256 * 8192 * 2;
  unsigned short* Khg = (unsigned short*)ws; ws += (size_t)256 * 8192 * 2;
  float* bvg          = (float*)ws;          ws += (size_t)256 * 8192 * 4;
  float* esg          = (float*)ws;          ws += 256 * 4;
  float* Wbt          = (float*)ws;          ws += (size_t)32 * HID * 4;     // 256 KB

  cast_bf16<<<dim3(SEQ * HID / 1024), 256, 0, stream>>>(hid, Xb, SEQ * HID);
  transpose_cast<<<dim3(NQKVZ / 32, HID / 32), 256, 0, stream>>>(W_qkvz, W1t, HID, NQKVZ);
  transpose_cast<<<dim3(HID / 32, HID / 32), 256, 0, stream>>>(W_out, W2t, HID, HID);
  transpose_f32<<<dim3(1, HID / 32), 256, 0, stream>>>(W_ba, Wbt, HID, 32);
  ba_kernel<<<dim3(SEQ / 4), 256, 0, stream>>>(hid, Wbt, A_log, dt_bias, gbuf, bet);
  gemm_bf16<<<dim3(NQKVZ / 128, SEQ / 128), 256, 0, stream>>>(Xb, W1t, qkvz,
                                                              SEQ, NQKVZ, HID);
  conv_kernel<<<dim3(32, SEQ), 128, 0, stream>>>(qkvz, conv_w, qn, kn, vc);
  chunk_prep<<<dim3(256), 256, 0, stream>>>(qn, kn, vc, gbuf, bet,
                                            Tg, Gg, Wtg, Qtg, Khg, bvg, esg);
  scan_rec<<<dim3(128), 256, 0, stream>>>(Tg, Gg, Wtg, Qtg, Khg, bvg, esg, obuf);
  rmsnorm_kernel<<<dim3(16, SEQ), 128, 0, stream>>>(obuf, qkvz, norm_w, on_bf);
  gemm_bf16<<<dim3(HID / 128, SEQ / 128), 256, 0, stream>>>(on_bf, W2t, out,
                                                            SEQ, HID, HID);
}

// Round 6
// 252.734 us; speedup vs baseline: 5.6195x; 1.0823x over previous
//
#include <hip/hip_runtime.h>
#include <hip/hip_bf16.h>
#include <math.h>

// Qwen3-Next GatedDeltaNet, B=1, S=1024, HIDDEN=2048
// H_K=8, H_V=16, DK=DV=128, KDIM=1024, VDIM=2048, CONV_DIM=4096, KS=4
// Scan via chunked delta rule: C=64, 16 chunks.

#define SEQ 1024
#define HID 2048
#define NQKVZ 6144

typedef __attribute__((ext_vector_type(8))) short short8;
typedef __attribute__((ext_vector_type(4))) float f32x4;

__device__ __forceinline__ unsigned short f2bf(float f) {
  __hip_bfloat16 h = __float2bfloat16(f);
  return *reinterpret_cast<unsigned short*>(&h);
}
__device__ __forceinline__ float bf2f(unsigned short u) {
  unsigned int x = ((unsigned int)u) << 16;
  return __int_as_float(x);
}

// async global->LDS, 16B per lane (dest = wave-uniform base + lane*16)
typedef __attribute__((address_space(3))) void lds_void;
typedef const __attribute__((address_space(1))) void g_void;
__device__ __forceinline__ void gload16(const void* g, void* l) {
  __builtin_amdgcn_global_load_lds((g_void*)g, (lds_void*)l, 16, 0, 0);
}

// ---------------------------------------------------------------------------
// elementwise f32 -> bf16 cast
// ---------------------------------------------------------------------------
__global__ __launch_bounds__(256) void cast_bf16(const float* __restrict__ in,
                                                 unsigned short* __restrict__ out,
                                                 int n) {
  const int i = (blockIdx.x * 256 + threadIdx.x) * 4;
  if (i < n) {
    const float4 v = *(const float4*)&in[i];
    ushort4 o;
    o.x = f2bf(v.x); o.y = f2bf(v.y); o.z = f2bf(v.z); o.w = f2bf(v.w);
    *(ushort4*)&out[i] = o;
  }
}

// ---------------------------------------------------------------------------
// W[K][N] f32 -> Wt[N][K] bf16
// ---------------------------------------------------------------------------
__global__ __launch_bounds__(256) void transpose_cast(const float* __restrict__ W,
                                                      unsigned short* __restrict__ Wt,
                                                      int K, int N) {
  __shared__ float tile[32][33];
  const int n0 = blockIdx.x * 32, k0 = blockIdx.y * 32;
  const int tx = threadIdx.x & 31, ty = threadIdx.x >> 5;
#pragma unroll
  for (int r = 0; r < 32; r += 8)
    tile[ty + r][tx] = W[(size_t)(k0 + ty + r) * N + n0 + tx];
  __syncthreads();
#pragma unroll
  for (int r = 0; r < 32; r += 8)
    Wt[(size_t)(n0 + ty + r) * K + k0 + tx] = f2bf(tile[tx][ty + r]);
}

// ---------------------------------------------------------------------------
// W[K][N] f32 -> Wt[N][K] f32 (for W_ba)
// ---------------------------------------------------------------------------
__global__ __launch_bounds__(256) void transpose_f32(const float* __restrict__ W,
                                                     float* __restrict__ Wt,
                                                     int K, int N) {
  __shared__ float tile[32][33];
  const int n0 = blockIdx.x * 32, k0 = blockIdx.y * 32;
  const int tx = threadIdx.x & 31, ty = threadIdx.x >> 5;
#pragma unroll
  for (int r = 0; r < 32; r += 8)
    tile[ty + r][tx] = W[(size_t)(k0 + ty + r) * N + n0 + tx];
  __syncthreads();
#pragma unroll
  for (int r = 0; r < 32; r += 8)
    Wt[(size_t)(n0 + ty + r) * K + k0 + tx] = tile[tx][ty + r];
}

// ---------------------------------------------------------------------------
// bf16 MFMA GEMM: C[M][N] f32 = A[M][K] @ Bt[N][K]^T, both bf16 K-contiguous.
// Block tile 128 x (32*NF), BK=32, 4 waves (2x2), wave tile 64 x (16*NF).
// Double-buffered LDS; staging via global_load_lds width-16 with PRE-SWIZZLED
// global source (LDS dest linear). Swizzle: slot ^= (row>>1)&3  -> 16
// consecutive rows cover all 8 16B-slots mod 128B => 2-way (free) on ds_read.
// ---------------------------------------------------------------------------
template <int NF>
__global__ __launch_bounds__(256) void gemm_bf16(const unsigned short* __restrict__ A,
                                                 const unsigned short* __restrict__ Bt,
                                                 float* __restrict__ C,
                                                 int M, int N, int K) {
  constexpr int BN = 32 * NF;
  __shared__ unsigned short As[2][128 * 32];
  __shared__ unsigned short Bs[2][BN * 32];

  const int tid  = threadIdx.x;
  const int lane = tid & 63;
  const int w    = tid >> 6;
  const int wm   = w >> 1, wn = w & 1;
  const int row0 = blockIdx.y * 128, col0 = blockIdx.x * BN;

  // staging: lane covers row r0s = w*16 + (lane>>2) (and +64 for group 1),
  // physical 16B slot lane&3, global slot sg = slot ^ ((row>>1)&3).
  // ((row+64)>>1)&3 == (row>>1)&3, so sg is valid for both groups.
  const int srow  = lane >> 2;
  const int sslot = lane & 3;
  const int r0s   = w * 16 + srow;
  const int sg    = sslot ^ ((r0s >> 1) & 3);

  const unsigned short* agp0 = A  + (size_t)(row0 + r0s) * K + sg * 8;
  const unsigned short* agp1 = agp0 + (size_t)64 * K;
  const unsigned short* bgp0 = Bt + (size_t)(col0 + r0s) * K + sg * 8;
  const unsigned short* bgp1 = bgp0 + (size_t)64 * K;

  const int arow = lane & 15;
  const int asl  = lane >> 4;

  f32x4 acc[4][NF];
#pragma unroll
  for (int m = 0; m < 4; ++m)
#pragma unroll
    for (int n = 0; n < NF; ++n) acc[m][n] = (f32x4){0.f, 0.f, 0.f, 0.f};

  const int nk = K >> 5;

#define STAGE(bi, kt)                                                        \
  {                                                                          \
    const int ko = (kt) * 32;                                                \
    gload16(agp0 + ko, (char*)As[bi] + w * 1024);                            \
    gload16(agp1 + ko, (char*)As[bi] + 4096 + w * 1024);                     \
    gload16(bgp0 + ko, (char*)Bs[bi] + w * 1024);                            \
    if (NF == 4) gload16(bgp1 + ko, (char*)Bs[bi] + 4096 + w * 1024);        \
  }

  STAGE(0, 0);
  __syncthreads();  // buf0 staged (vmcnt drained by syncthreads semantics)

  int cur = 0;
  for (int kt = 0; kt < nk; ++kt) {
    if (kt + 1 < nk) STAGE(cur ^ 1, kt + 1);  // issue next tile (async)

    const char* asb = (const char*)As[cur];
    const char* bsb = (const char*)Bs[cur];
    short8 af[4], bf[NF];
#pragma unroll
    for (int m = 0; m < 4; ++m) {
      const int row = wm * 64 + m * 16 + arow;
      af[m] = *(const short8*)(asb + row * 64 + ((asl ^ ((row >> 1) & 3)) * 16));
    }
#pragma unroll
    for (int n = 0; n < NF; ++n) {
      const int row = wn * (16 * NF) + n * 16 + arow;
      bf[n] = *(const short8*)(bsb + row * 64 + ((asl ^ ((row >> 1) & 3)) * 16));
    }
#pragma unroll
    for (int m = 0; m < 4; ++m)
#pragma unroll
      for (int n = 0; n < NF; ++n)
        acc[m][n] = __builtin_amdgcn_mfma_f32_16x16x32_bf16(af[m], bf[n], acc[m][n], 0, 0, 0);

    __syncthreads();  // drain next-tile stage + all waves done with buf[cur]
    cur ^= 1;
  }
#undef STAGE

#pragma unroll
  for (int m = 0; m < 4; ++m)
#pragma unroll
    for (int n = 0; n < NF; ++n) {
      const int r0 = row0 + wm * 64 + m * 16 + (lane >> 4) * 4;
      const int c  = col0 + wn * (16 * NF) + n * 16 + (lane & 15);
#pragma unroll
      for (int r = 0; r < 4; ++r)
        C[(size_t)(r0 + r) * N + c] = acc[m][n][r];
    }
}

// ---------------------------------------------------------------------------
// ba: split-K GEMV vs W_ba^T[32][2048] f32, fused activations.
// ---------------------------------------------------------------------------
__global__ __launch_bounds__(256) void ba_kernel(const float* __restrict__ X,
                                                 const float* __restrict__ Wbt,
                                                 const float* __restrict__ A_log,
                                                 const float* __restrict__ dt_bias,
                                                 float* __restrict__ gbuf,
                                                 float* __restrict__ bet) {
  const int col = threadIdx.x & 31;
  const int kg  = threadIdx.x >> 5;
  const int s0  = blockIdx.x * 4;
  const float* wp = Wbt + (size_t)col * HID + kg * 256;
  const float* xp = X + (size_t)s0 * HID + kg * 256;

  float a0 = 0.f, a1 = 0.f, a2 = 0.f, a3 = 0.f;
  for (int kk = 0; kk < 256; kk += 4) {
    const float4 w4 = *(const float4*)&wp[kk];
    const float4 x0 = *(const float4*)&xp[kk];
    const float4 x1 = *(const float4*)&xp[kk + HID];
    const float4 x2 = *(const float4*)&xp[kk + 2 * HID];
    const float4 x3 = *(const float4*)&xp[kk + 3 * HID];
    a0 += x0.x * w4.x + x0.y * w4.y + x0.z * w4.z + x0.w * w4.w;
    a1 += x1.x * w4.x + x1.y * w4.y + x1.z * w4.z + x1.w * w4.w;
    a2 += x2.x * w4.x + x2.y * w4.y + x2.z * w4.z + x2.w * w4.w;
    a3 += x3.x * w4.x + x3.y * w4.y + x3.z * w4.z + x3.w * w4.w;
  }
  __shared__ float red[4][32][9];
  red[0][col][kg] = a0;
  red[1][col][kg] = a1;
  red[2][col][kg] = a2;
  red[3][col][kg] = a3;
  __syncthreads();
  if (threadIdx.x < 128) {
    const int r = threadIdx.x >> 5;
    const int c = threadIdx.x & 31;
    float acc = 0.f;
#pragma unroll
    for (int g = 0; g < 8; ++g) acc += red[r][c][g];
    const int s = s0 + r;
    const int hk = c >> 2, j = c & 3;
    if (j < 2) {
      bet[s * 16 + hk * 2 + j] = 1.f / (1.f + expf(-acc));
    } else {
      const int vh = hk * 2 + (j - 2);
      const float x = acc + dt_bias[vh];
      const float sp = (x > 20.f) ? x : log1pf(expf(x));
      gbuf[s * 16 + vh] = -expf(A_log[vh]) * sp;
    }
  }
}

// ---------------------------------------------------------------------------
// depthwise causal conv (KS=4) + SiLU; l2norm on q,k (q also * DK^-0.5)
// ---------------------------------------------------------------------------
__global__ __launch_bounds__(128) void conv_kernel(const float* __restrict__ qkvz,
                                                   const float* __restrict__ conv_w,
                                                   float* __restrict__ qn,
                                                   float* __restrict__ kn,
                                                   float* __restrict__ vc) {
  const int slot = blockIdx.x;
  const int s    = blockIdx.y;
  const int d    = threadIdx.x;

  int col, ch;
  if (slot < 8) {
    col = slot * 768 + d;
    ch  = slot * 128 + d;
  } else if (slot < 16) {
    const int hk = slot - 8;
    col = hk * 768 + 128 + d;
    ch  = 1024 + hk * 128 + d;
  } else {
    const int vh = slot - 16;
    col = (vh >> 1) * 768 + 256 + (vh & 1) * 128 + d;
    ch  = 2048 + vh * 128 + d;
  }

  float acc = 0.f;
#pragma unroll
  for (int j = 0; j < 4; ++j) {
    const int sr = s - 3 + j;
    const float x = (sr >= 0) ? qkvz[(size_t)sr * NQKVZ + col] : 0.f;
    acc += conv_w[ch * 4 + j] * x;
  }
  float y = acc / (1.f + expf(-acc));  // silu

  if (slot < 16) {
    float ss = y * y;
#pragma unroll
    for (int m = 1; m < 64; m <<= 1) ss += __shfl_xor(ss, m);
    __shared__ float red[2];
    if ((threadIdx.x & 63) == 0) red[threadIdx.x >> 6] = ss;
    __syncthreads();
    const float tot = red[0] + red[1];
    float sc = rsqrtf(tot + 1e-6f);
    if (slot < 8) sc *= 0.08838834764831845f;  // DK^-0.5
    y *= sc;
    if (slot < 8) qn[((size_t)s * 8 + slot) * 128 + d] = y;
    else          kn[((size_t)s * 8 + (slot - 8)) * 128 + d] = y;
  } else {
    vc[((size_t)s * 16 + (slot - 16)) * 128 + d] = y;
  }
}

// ---------------------------------------------------------------------------
// chunk_prep v2: K,Q staged bf16 in XOR-swizzled LDS; KK^T/QK^T via MFMA;
// B bf16; T=(I+B)^-1 f32 forward substitution (wave 0); bf16 operand outputs.
// ---------------------------------------------------------------------------
__global__ __launch_bounds__(256) void chunk_prep(
    const float* __restrict__ qn, const float* __restrict__ kn,
    const float* __restrict__ vc, const float* __restrict__ gbuf,
    const float* __restrict__ bet,
    unsigned short* __restrict__ Tg, unsigned short* __restrict__ Gg,
    unsigned short* __restrict__ Wtg, unsigned short* __restrict__ Qtg,
    unsigned short* __restrict__ Khg, float* __restrict__ bvg,
    float* __restrict__ esg) {
  const int h  = blockIdx.x >> 4;
  const int c  = blockIdx.x & 15;
  const int hk = h >> 1;
  const int tid = threadIdx.x;
  const int lane = tid & 63;
  const int w    = tid >> 6;
  const int lr   = lane & 15;
  const int lk   = lane >> 4;

  __shared__ unsigned short Kb[64 * 128];   // 16 KB, swizzled rows of 256B
  __shared__ unsigned short Qb[64 * 128];   // 16 KB
  __shared__ unsigned short Bm[64][64];     // 8 KB  (bf16 B matrix)
  __shared__ float Tm[64][65];              // 16.6 KB
  __shared__ float cg[64];
  __shared__ float btl[64];

#pragma unroll
  for (int n = 0; n < 8; ++n) {
    const int idx = tid + 256 * n;
    const int row = idx >> 5;
    const int col = (idx & 31) * 4;
    const float4 kv = *(const float4*)&kn[((size_t)(c * 64 + row) * 8 + hk) * 128 + col];
    const float4 qv = *(const float4*)&qn[((size_t)(c * 64 + row) * 8 + hk) * 128 + col];
    const int boff = row * 256 + ((col * 2) ^ ((row & 7) << 4));
    ushort4 ko = {f2bf(kv.x), f2bf(kv.y), f2bf(kv.z), f2bf(kv.w)};
    ushort4 qo = {f2bf(qv.x), f2bf(qv.y), f2bf(qv.z), f2bf(qv.w)};
    *(ushort4*)((char*)Kb + boff) = ko;
    *(ushort4*)((char*)Qb + boff) = qo;
  }
  if (tid < 64) {
    float g = gbuf[(c * 64 + tid) * 16 + h];
#pragma unroll
    for (int d = 1; d < 64; d <<= 1) {
      const float o = __shfl_up(g, d);
      if (tid >= d) g += o;
    }
    cg[tid] = g;
    btl[tid] = bet[(c * 64 + tid) * 16 + h];
  }
  __syncthreads();

  f32x4 kkacc[4], qkacc[4];
#pragma unroll
  for (int ct = 0; ct < 4; ++ct) {
    kkacc[ct] = (f32x4){0.f, 0.f, 0.f, 0.f};
    qkacc[ct] = (f32x4){0.f, 0.f, 0.f, 0.f};
  }
  {
    const int rowA = 16 * w + lr;
    const int swA  = (rowA & 7) << 4;
#pragma unroll
    for (int ks = 0; ks < 4; ++ks) {
      const int kb = ks * 64 + lk * 16;
      const short8 aK = *(const short8*)((char*)Kb + rowA * 256 + (kb ^ swA));
      const short8 aQ = *(const short8*)((char*)Qb + rowA * 256 + (kb ^ swA));
#pragma unroll
      for (int ct = 0; ct < 4; ++ct) {
        const int rowB = ct * 16 + lr;
        const short8 bK = *(const short8*)((char*)Kb + rowB * 256 + (kb ^ ((rowB & 7) << 4)));
        kkacc[ct] = __builtin_amdgcn_mfma_f32_16x16x32_bf16(aK, bK, kkacc[ct], 0, 0, 0);
        qkacc[ct] = __builtin_amdgcn_mfma_f32_16x16x32_bf16(aQ, bK, qkacc[ct], 0, 0, 0);
      }
    }
  }
#pragma unroll
  for (int ct = 0; ct < 4; ++ct) {
#pragma unroll
    for (int r = 0; r < 4; ++r) {
      const int i = 16 * w + lk * 4 + r;
      const int j = ct * 16 + lr;
      const float e = __expf(cg[i] - cg[j]);
      Bm[i][j] = f2bf((j < i) ? btl[i] * e * kkacc[ct][r] : 0.f);
      const float gv = (j <= i) ? e * qkacc[ct][r] : 0.f;
      Gg[(size_t)blockIdx.x * 4096 + i * 64 + j] = f2bf(gv);
    }
  }
  __syncthreads();

  if (tid < 64) {
    const int l = tid;
    for (int i = 0; i < 64; ++i) {
      float v = (i == l) ? 1.f : 0.f;
      for (int j = 0; j < i; ++j) v -= bf2f(Bm[i][j]) * Tm[j][l];
      Tm[i][l] = v;
    }
  }
  __syncthreads();

#pragma unroll
  for (int n = 0; n < 16; ++n) {
    const int lin = tid + 256 * n;
    Tg[(size_t)blockIdx.x * 4096 + lin] = f2bf(Tm[lin >> 6][lin & 63]);
  }

  const float cglast = cg[63];
#pragma unroll
  for (int n = 0; n < 8; ++n) {
    const int idx = tid + 256 * n;
    const int i = idx >> 5;
    const int dk = (idx & 31) * 4;
    const int boff = i * 256 + ((dk * 2) ^ ((i & 7) << 4));
    const ushort4 kq = *(const ushort4*)((char*)Kb + boff);
    const ushort4 qq = *(const ushort4*)((char*)Qb + boff);
    const float ei = __expf(cg[i]);
    const float wi = btl[i] * ei;
    ushort4 wo = {f2bf(wi * bf2f(kq.x)), f2bf(wi * bf2f(kq.y)),
                  f2bf(wi * bf2f(kq.z)), f2bf(wi * bf2f(kq.w))};
    ushort4 qo = {f2bf(ei * bf2f(qq.x)), f2bf(ei * bf2f(qq.y)),
                  f2bf(ei * bf2f(qq.z)), f2bf(ei * bf2f(qq.w))};
    *(ushort4*)&Wtg[(size_t)blockIdx.x * 8192 + i * 128 + dk] = wo;
    *(ushort4*)&Qtg[(size_t)blockIdx.x * 8192 + i * 128 + dk] = qo;
    const float4 vv = *(const float4*)&vc[((size_t)(c * 64 + i) * 16 + h) * 128 + dk];
    float4 bv4 = {btl[i] * vv.x, btl[i] * vv.y, btl[i] * vv.z, btl[i] * vv.w};
    *(float4*)&bvg[(size_t)blockIdx.x * 8192 + i * 128 + dk] = bv4;
  }
#pragma unroll
  for (int n = 0; n < 32; ++n) {
    const int lin = tid + 256 * n;         // layout [dk][i]
    const int dk = lin >> 6, i = lin & 63;
    const unsigned short kraw =
        *(const unsigned short*)((char*)Kb + i * 256 + ((dk * 2) ^ ((i & 7) << 4)));
    Khg[(size_t)blockIdx.x * 8192 + lin] = f2bf(__expf(cglast - cg[i]) * bf2f(kraw));
  }
  if (tid == 0) esg[blockIdx.x] = __expf(cglast);
}

// ---------------------------------------------------------------------------
// scan_rec: serial over 16 chunks, parallel over (h, dv-block of 16).
// ---------------------------------------------------------------------------
__global__ __launch_bounds__(256) void scan_rec(
    const unsigned short* __restrict__ Tg, const unsigned short* __restrict__ Gg,
    const unsigned short* __restrict__ Wtg, const unsigned short* __restrict__ Qtg,
    const unsigned short* __restrict__ Khg, const float* __restrict__ bvg,
    const float* __restrict__ esg, float* __restrict__ obuf) {
  const int h   = blockIdx.x >> 3;
  const int dvb = blockIdx.x & 7;
  const int dv0 = dvb * 16;
  const int tid = threadIdx.x;
  const int lane = tid & 63;
  const int w   = tid >> 6;
  const int lr  = lane & 15;
  const int lk  = lane >> 4;

  __shared__ unsigned short Sb[16][136];
  __shared__ unsigned short Ub[16][72];
  __shared__ unsigned short Db[16][72];

  for (int n = tid; n < 16 * 136 / 2; n += 256) ((unsigned int*)Sb)[n] = 0u;

  f32x4 sacc0 = {0.f, 0.f, 0.f, 0.f};
  f32x4 sacc1 = {0.f, 0.f, 0.f, 0.f};
  __syncthreads();

  for (int c = 0; c < 16; ++c) {
    const size_t base = (size_t)h * 16 + c;
    const unsigned short* T_  = Tg  + base * 4096;
    const unsigned short* G_  = Gg  + base * 4096;
    const unsigned short* W_  = Wtg + base * 8192;
    const unsigned short* Q_  = Qtg + base * 8192;
    const unsigned short* Kh_ = Khg + base * 8192;
    const float* bv_ = bvg + base * 8192;
    const float es = esg[base];

    f32x4 au = {0.f, 0.f, 0.f, 0.f};
#pragma unroll
    for (int ks = 0; ks < 4; ++ks) {
      const short8 af = *(const short8*)(W_ + (16 * w + lr) * 128 + ks * 32 + lk * 8);
      const short8 bf = *(const short8*)(&Sb[lr][ks * 32 + lk * 8]);
      au = __builtin_amdgcn_mfma_f32_16x16x32_bf16(af, bf, au, 0, 0, 0);
    }
    {
      ushort4 pk;
#pragma unroll
      for (int r = 0; r < 4; ++r) {
        const int i = 16 * w + lk * 4 + r;
        const float bvv = bv_[i * 128 + dv0 + lr];
        ((unsigned short*)&pk)[r] = f2bf(bvv - au[r]);
      }
      *(ushort4*)&Ub[lr][16 * w + lk * 4] = pk;
    }
    __syncthreads();

    f32x4 ad = {0.f, 0.f, 0.f, 0.f};
#pragma unroll
    for (int ks = 0; ks < 2; ++ks) {
      const short8 af = *(const short8*)(T_ + (16 * w + lr) * 64 + ks * 32 + lk * 8);
      const short8 bf = *(const short8*)(&Ub[lr][ks * 32 + lk * 8]);
      ad = __builtin_amdgcn_mfma_f32_16x16x32_bf16(af, bf, ad, 0, 0, 0);
    }
    {
      ushort4 pk;
#pragma unroll
      for (int r = 0; r < 4; ++r) ((unsigned short*)&pk)[r] = f2bf(ad[r]);
      *(ushort4*)&Db[lr][16 * w + lk * 4] = pk;
    }
    __syncthreads();

    f32x4 ao = {0.f, 0.f, 0.f, 0.f};
#pragma unroll
    for (int ks = 0; ks < 4; ++ks) {
      const short8 af = *(const short8*)(Q_ + (16 * w + lr) * 128 + ks * 32 + lk * 8);
      const short8 bf = *(const short8*)(&Sb[lr][ks * 32 + lk * 8]);
      ao = __builtin_amdgcn_mfma_f32_16x16x32_bf16(af, bf, ao, 0, 0, 0);
    }
#pragma unroll
    for (int ks = 0; ks < 2; ++ks) {
      const short8 af = *(const short8*)(G_ + (16 * w + lr) * 64 + ks * 32 + lk * 8);
      const short8 bf = *(const short8*)(&Db[lr][ks * 32 + lk * 8]);
      ao = __builtin_amdgcn_mfma_f32_16x16x32_bf16(af, bf, ao, 0, 0, 0);
    }
#pragma unroll
    for (int r = 0; r < 4; ++r) {
      const int i = 16 * w + lk * 4 + r;
      const int t = c * 64 + i;
      obuf[((size_t)t * 16 + h) * 128 + dv0 + lr] = ao[r];
    }

    sacc0 *= es;
    sacc1 *= es;
#pragma unroll
    for (int ks = 0; ks < 2; ++ks) {
      const short8 a0 = *(const short8*)(Kh_ + (32 * w + lr) * 64 + ks * 32 + lk * 8);
      const short8 a1 = *(const short8*)(Kh_ + (32 * w + 16 + lr) * 64 + ks * 32 + lk * 8);
      const short8 bf = *(const short8*)(&Db[lr][ks * 32 + lk * 8]);
      sacc0 = __builtin_amdgcn_mfma_f32_16x16x32_bf16(a0, bf, sacc0, 0, 0, 0);
      sacc1 = __builtin_amdgcn_mfma_f32_16x16x32_bf16(a1, bf, sacc1, 0, 0, 0);
    }
    __syncthreads();

    {
      ushort4 p0, p1;
#pragma unroll
      for (int r = 0; r < 4; ++r) {
        ((unsigned short*)&p0)[r] = f2bf(sacc0[r]);
        ((unsigned short*)&p1)[r] = f2bf(sacc1[r]);
      }
      *(ushort4*)&Sb[lr][32 * w + lk * 4] = p0;
      *(ushort4*)&Sb[lr][32 * w + 16 + lk * 4] = p1;
    }
    __syncthreads();
  }
}

// ---------------------------------------------------------------------------
// gated RMSNorm -> bf16
// ---------------------------------------------------------------------------
__global__ __launch_bounds__(128) void rmsnorm_kernel(const float* __restrict__ obuf,
                                                      const float* __restrict__ qkvz,
                                                      const float* __restrict__ nw,
                                                      unsigned short* __restrict__ on) {
  const int vh = blockIdx.x;
  const int s  = blockIdx.y;
  const int d  = threadIdx.x;

  const float x = obuf[((size_t)s * 16 + vh) * 128 + d];
  float ss = x * x;
#pragma unroll
  for (int m = 1; m < 64; m <<= 1) ss += __shfl_xor(ss, m);
  __shared__ float red[2];
  if ((threadIdx.x & 63) == 0) red[threadIdx.x >> 6] = ss;
  __syncthreads();
  const float tot = red[0] + red[1];

  const float z = qkvz[(size_t)s * NQKVZ + (vh >> 1) * 768 + 512 + (vh & 1) * 128 + d];
  const float y = x * rsqrtf(tot * (1.f / 128.f) + 1e-6f) * nw[d] *
                  (z / (1.f + expf(-z)));
  on[(size_t)s * 2048 + vh * 128 + d] = f2bf(y);
}

// ---------------------------------------------------------------------------
extern "C" void kernel_launch(void* const* d_in, const int* in_sizes, int n_in,
                              void* d_out, int out_size, void* d_ws, size_t ws_size,
                              hipStream_t stream) {
  const float* hid     = (const float*)d_in[0];
  const float* W_qkvz  = (const float*)d_in[1];
  const float* W_ba    = (const float*)d_in[2];
  const float* conv_w  = (const float*)d_in[3];
  const float* dt_bias = (const float*)d_in[4];
  const float* A_log   = (const float*)d_in[5];
  const float* norm_w  = (const float*)d_in[6];
  const float* W_out   = (const float*)d_in[7];
  float* out = (float*)d_out;

  char* ws = (char*)d_ws;
  float* qkvz = (float*)ws;                 ws += (size_t)SEQ * NQKVZ * 4;   // 24 MB
  char* region2 = ws;                       ws += (size_t)HID * NQKVZ * 2;   // 24 MB
  unsigned short* W1t = (unsigned short*)region2;
  float* qn   = (float*)(region2);
  float* kn   = (float*)(region2 + 4194304);
  float* vc   = (float*)(region2 + 8388608);
  float* obuf = (float*)(region2 + 16777216);
  unsigned short* Xb = (unsigned short*)ws; ws += (size_t)SEQ * HID * 2;     // 4 MB
  unsigned short* on_bf = Xb;
  unsigned short* W2t = (unsigned short*)ws; ws += (size_t)HID * HID * 2;    // 8 MB
  float* gbuf = (float*)ws;                  ws += (size_t)SEQ * 16 * 4;
  float* bet  = (float*)ws;                  ws += (size_t)SEQ * 16 * 4;
  unsigned short* Tg  = (unsigned short*)ws; ws += (size_t)256 * 4096 * 2;
  unsigned short* Gg  = (unsigned short*)ws; ws += (size_t)256 * 4096 * 2;
  unsigned short* Wtg = (unsigned short*)ws; ws += (size_t)256 * 8192 * 2;
  unsigned short* Qtg = (unsigned short*)ws; ws += (size_t)256 * 8192 * 2;
  unsigned short* Khg = (unsigned short*)ws; ws += (size_t)256 * 8192 * 2;
  float* bvg          = (float*)ws;          ws += (size_t)256 * 8192 * 4;
  float* esg          = (float*)ws;          ws += 256 * 4;
  float* Wbt          = (float*)ws;          ws += (size_t)32 * HID * 4;     // 256 KB

  cast_bf16<<<dim3(SEQ * HID / 1024), 256, 0, stream>>>(hid, Xb, SEQ * HID);
  transpose_cast<<<dim3(NQKVZ / 32, HID / 32), 256, 0, stream>>>(W_qkvz, W1t, HID, NQKVZ);
  transpose_cast<<<dim3(HID / 32, HID / 32), 256, 0, stream>>>(W_out, W2t, HID, HID);
  transpose_f32<<<dim3(1, HID / 32), 256, 0, stream>>>(W_ba, Wbt, HID, 32);
  ba_kernel<<<dim3(SEQ / 4), 256, 0, stream>>>(hid, Wbt, A_log, dt_bias, gbuf, bet);
  gemm_bf16<4><<<dim3(NQKVZ / 128, SEQ / 128), 256, 0, stream>>>(Xb, W1t, qkvz,
                                                                 SEQ, NQKVZ, HID);
  conv_kernel<<<dim3(32, SEQ), 128, 0, stream>>>(qkvz, conv_w, qn, kn, vc);
  chunk_prep<<<dim3(256), 256, 0, stream>>>(qn, kn, vc, gbuf, bet,
                                            Tg, Gg, Wtg, Qtg, Khg, bvg, esg);
  scan_rec<<<dim3(128), 256, 0, stream>>>(Tg, Gg, Wtg, Qtg, Khg, bvg, esg, obuf);
  rmsnorm_kernel<<<dim3(16, SEQ), 128, 0, stream>>>(obuf, qkvz, norm_w, on_bf);
  gemm_bf16<2><<<dim3(HID / 64, SEQ / 128), 256, 0, stream>>>(on_bf, W2t, out,
                                                              SEQ, HID, HID);
}

// Round 7
// 234.679 us; speedup vs baseline: 6.0519x; 1.0769x over previous
//
#include <hip/hip_runtime.h>
#include <hip/hip_bf16.h>
#include <math.h>

// Qwen3-Next GatedDeltaNet, B=1, S=1024, HIDDEN=2048
// H_K=8, H_V=16, DK=DV=128, KDIM=1024, VDIM=2048, CONV_DIM=4096, KS=4
// Scan via chunked delta rule: C=64, 16 chunks.

#define SEQ 1024
#define HID 2048
#define NQKVZ 6144

typedef __attribute__((ext_vector_type(8))) short short8;
typedef __attribute__((ext_vector_type(4))) float f32x4;

__device__ __forceinline__ unsigned short f2bf(float f) {
  __hip_bfloat16 h = __float2bfloat16(f);
  return *reinterpret_cast<unsigned short*>(&h);
}
__device__ __forceinline__ float bf2f(unsigned short u) {
  unsigned int x = ((unsigned int)u) << 16;
  return __int_as_float(x);
}

// async global->LDS, 16B per lane (dest = wave-uniform base + lane*16)
typedef __attribute__((address_space(3))) void lds_void;
typedef const __attribute__((address_space(1))) void g_void;
__device__ __forceinline__ void gload16(const void* g, void* l) {
  __builtin_amdgcn_global_load_lds((g_void*)g, (lds_void*)l, 16, 0, 0);
}

// ---------------------------------------------------------------------------
// elementwise f32 -> bf16 cast
// ---------------------------------------------------------------------------
__global__ __launch_bounds__(256) void cast_bf16(const float* __restrict__ in,
                                                 unsigned short* __restrict__ out,
                                                 int n) {
  const int i = (blockIdx.x * 256 + threadIdx.x) * 4;
  if (i < n) {
    const float4 v = *(const float4*)&in[i];
    ushort4 o;
    o.x = f2bf(v.x); o.y = f2bf(v.y); o.z = f2bf(v.z); o.w = f2bf(v.w);
    *(ushort4*)&out[i] = o;
  }
}

// ---------------------------------------------------------------------------
// W[K][N] f32 -> Wt[N][K] bf16
// ---------------------------------------------------------------------------
__global__ __launch_bounds__(256) void transpose_cast(const float* __restrict__ W,
                                                      unsigned short* __restrict__ Wt,
                                                      int K, int N) {
  __shared__ float tile[32][33];
  const int n0 = blockIdx.x * 32, k0 = blockIdx.y * 32;
  const int tx = threadIdx.x & 31, ty = threadIdx.x >> 5;
#pragma unroll
  for (int r = 0; r < 32; r += 8)
    tile[ty + r][tx] = W[(size_t)(k0 + ty + r) * N + n0 + tx];
  __syncthreads();
#pragma unroll
  for (int r = 0; r < 32; r += 8)
    Wt[(size_t)(n0 + ty + r) * K + k0 + tx] = f2bf(tile[tx][ty + r]);
}

// ---------------------------------------------------------------------------
// W[K][N] f32 -> Wt[N][K] f32 (for W_ba)
// ---------------------------------------------------------------------------
__global__ __launch_bounds__(256) void transpose_f32(const float* __restrict__ W,
                                                     float* __restrict__ Wt,
                                                     int K, int N) {
  __shared__ float tile[32][33];
  const int n0 = blockIdx.x * 32, k0 = blockIdx.y * 32;
  const int tx = threadIdx.x & 31, ty = threadIdx.x >> 5;
#pragma unroll
  for (int r = 0; r < 32; r += 8)
    tile[ty + r][tx] = W[(size_t)(k0 + ty + r) * N + n0 + tx];
  __syncthreads();
#pragma unroll
  for (int r = 0; r < 32; r += 8)
    Wt[(size_t)(n0 + ty + r) * K + k0 + tx] = tile[tx][ty + r];
}

// ---------------------------------------------------------------------------
// bf16 MFMA GEMM: C[M][N] f32 = A[M][K] @ Bt[N][K]^T, both bf16 K-contiguous.
// Block tile 128 x (32*NF), BK=32, 4 waves (2x2), wave tile 64 x (16*NF).
// Double-buffered LDS; staging via global_load_lds width-16 with PRE-SWIZZLED
// global source (LDS dest linear). Swizzle: slot ^= (row>>1)&3.
// ---------------------------------------------------------------------------
template <int NF>
__global__ __launch_bounds__(256) void gemm_bf16(const unsigned short* __restrict__ A,
                                                 const unsigned short* __restrict__ Bt,
                                                 float* __restrict__ C,
                                                 int M, int N, int K) {
  constexpr int BN = 32 * NF;
  __shared__ unsigned short As[2][128 * 32];
  __shared__ unsigned short Bs[2][BN * 32];

  const int tid  = threadIdx.x;
  const int lane = tid & 63;
  const int w    = tid >> 6;
  const int wm   = w >> 1, wn = w & 1;
  const int row0 = blockIdx.y * 128, col0 = blockIdx.x * BN;

  const int srow  = lane >> 2;
  const int sslot = lane & 3;
  const int r0s   = w * 16 + srow;
  const int sg    = sslot ^ ((r0s >> 1) & 3);

  const unsigned short* agp0 = A  + (size_t)(row0 + r0s) * K + sg * 8;
  const unsigned short* agp1 = agp0 + (size_t)64 * K;
  const unsigned short* bgp0 = Bt + (size_t)(col0 + r0s) * K + sg * 8;
  const unsigned short* bgp1 = bgp0 + (size_t)64 * K;

  const int arow = lane & 15;
  const int asl  = lane >> 4;

  f32x4 acc[4][NF];
#pragma unroll
  for (int m = 0; m < 4; ++m)
#pragma unroll
    for (int n = 0; n < NF; ++n) acc[m][n] = (f32x4){0.f, 0.f, 0.f, 0.f};

  const int nk = K >> 5;

#define STAGE(bi, kt)                                                        \
  {                                                                          \
    const int ko = (kt) * 32;                                                \
    gload16(agp0 + ko, (char*)As[bi] + w * 1024);                            \
    gload16(agp1 + ko, (char*)As[bi] + 4096 + w * 1024);                     \
    gload16(bgp0 + ko, (char*)Bs[bi] + w * 1024);                            \
    if (NF == 4) gload16(bgp1 + ko, (char*)Bs[bi] + 4096 + w * 1024);        \
  }

  STAGE(0, 0);
  __syncthreads();

  int cur = 0;
  for (int kt = 0; kt < nk; ++kt) {
    if (kt + 1 < nk) STAGE(cur ^ 1, kt + 1);

    const char* asb = (const char*)As[cur];
    const char* bsb = (const char*)Bs[cur];
    short8 af[4], bf[NF];
#pragma unroll
    for (int m = 0; m < 4; ++m) {
      const int row = wm * 64 + m * 16 + arow;
      af[m] = *(const short8*)(asb + row * 64 + ((asl ^ ((row >> 1) & 3)) * 16));
    }
#pragma unroll
    for (int n = 0; n < NF; ++n) {
      const int row = wn * (16 * NF) + n * 16 + arow;
      bf[n] = *(const short8*)(bsb + row * 64 + ((asl ^ ((row >> 1) & 3)) * 16));
    }
#pragma unroll
    for (int m = 0; m < 4; ++m)
#pragma unroll
      for (int n = 0; n < NF; ++n)
        acc[m][n] = __builtin_amdgcn_mfma_f32_16x16x32_bf16(af[m], bf[n], acc[m][n], 0, 0, 0);

    __syncthreads();
    cur ^= 1;
  }
#undef STAGE

#pragma unroll
  for (int m = 0; m < 4; ++m)
#pragma unroll
    for (int n = 0; n < NF; ++n) {
      const int r0 = row0 + wm * 64 + m * 16 + (lane >> 4) * 4;
      const int c  = col0 + wn * (16 * NF) + n * 16 + (lane & 15);
#pragma unroll
      for (int r = 0; r < 4; ++r)
        C[(size_t)(r0 + r) * N + c] = acc[m][n][r];
    }
}

// ---------------------------------------------------------------------------
// ba: split-K GEMV vs W_ba^T[32][2048] f32, fused activations.
// ---------------------------------------------------------------------------
__global__ __launch_bounds__(256) void ba_kernel(const float* __restrict__ X,
                                                 const float* __restrict__ Wbt,
                                                 const float* __restrict__ A_log,
                                                 const float* __restrict__ dt_bias,
                                                 float* __restrict__ gbuf,
                                                 float* __restrict__ bet) {
  const int col = threadIdx.x & 31;
  const int kg  = threadIdx.x >> 5;
  const int s0  = blockIdx.x * 4;
  const float* wp = Wbt + (size_t)col * HID + kg * 256;
  const float* xp = X + (size_t)s0 * HID + kg * 256;

  float a0 = 0.f, a1 = 0.f, a2 = 0.f, a3 = 0.f;
  for (int kk = 0; kk < 256; kk += 4) {
    const float4 w4 = *(const float4*)&wp[kk];
    const float4 x0 = *(const float4*)&xp[kk];
    const float4 x1 = *(const float4*)&xp[kk + HID];
    const float4 x2 = *(const float4*)&xp[kk + 2 * HID];
    const float4 x3 = *(const float4*)&xp[kk + 3 * HID];
    a0 += x0.x * w4.x + x0.y * w4.y + x0.z * w4.z + x0.w * w4.w;
    a1 += x1.x * w4.x + x1.y * w4.y + x1.z * w4.z + x1.w * w4.w;
    a2 += x2.x * w4.x + x2.y * w4.y + x2.z * w4.z + x2.w * w4.w;
    a3 += x3.x * w4.x + x3.y * w4.y + x3.z * w4.z + x3.w * w4.w;
  }
  __shared__ float red[4][32][9];
  red[0][col][kg] = a0;
  red[1][col][kg] = a1;
  red[2][col][kg] = a2;
  red[3][col][kg] = a3;
  __syncthreads();
  if (threadIdx.x < 128) {
    const int r = threadIdx.x >> 5;
    const int c = threadIdx.x & 31;
    float acc = 0.f;
#pragma unroll
    for (int g = 0; g < 8; ++g) acc += red[r][c][g];
    const int s = s0 + r;
    const int hk = c >> 2, j = c & 3;
    if (j < 2) {
      bet[s * 16 + hk * 2 + j] = 1.f / (1.f + expf(-acc));
    } else {
      const int vh = hk * 2 + (j - 2);
      const float x = acc + dt_bias[vh];
      const float sp = (x > 20.f) ? x : log1pf(expf(x));
      gbuf[s * 16 + vh] = -expf(A_log[vh]) * sp;
    }
  }
}

// ---------------------------------------------------------------------------
// depthwise causal conv (KS=4) + SiLU; l2norm on q,k (q also * DK^-0.5)
// ---------------------------------------------------------------------------
__global__ __launch_bounds__(128) void conv_kernel(const float* __restrict__ qkvz,
                                                   const float* __restrict__ conv_w,
                                                   float* __restrict__ qn,
                                                   float* __restrict__ kn,
                                                   float* __restrict__ vc) {
  const int slot = blockIdx.x;
  const int s    = blockIdx.y;
  const int d    = threadIdx.x;

  int col, ch;
  if (slot < 8) {
    col = slot * 768 + d;
    ch  = slot * 128 + d;
  } else if (slot < 16) {
    const int hk = slot - 8;
    col = hk * 768 + 128 + d;
    ch  = 1024 + hk * 128 + d;
  } else {
    const int vh = slot - 16;
    col = (vh >> 1) * 768 + 256 + (vh & 1) * 128 + d;
    ch  = 2048 + vh * 128 + d;
  }

  float acc = 0.f;
#pragma unroll
  for (int j = 0; j < 4; ++j) {
    const int sr = s - 3 + j;
    const float x = (sr >= 0) ? qkvz[(size_t)sr * NQKVZ + col] : 0.f;
    acc += conv_w[ch * 4 + j] * x;
  }
  float y = acc / (1.f + expf(-acc));  // silu

  if (slot < 16) {
    float ss = y * y;
#pragma unroll
    for (int m = 1; m < 64; m <<= 1) ss += __shfl_xor(ss, m);
    __shared__ float red[2];
    if ((threadIdx.x & 63) == 0) red[threadIdx.x >> 6] = ss;
    __syncthreads();
    const float tot = red[0] + red[1];
    float sc = rsqrtf(tot + 1e-6f);
    if (slot < 8) sc *= 0.08838834764831845f;  // DK^-0.5
    y *= sc;
    if (slot < 8) qn[((size_t)s * 8 + slot) * 128 + d] = y;
    else          kn[((size_t)s * 8 + (slot - 8)) * 128 + d] = y;
  } else {
    vc[((size_t)s * 16 + (slot - 16)) * 128 + d] = y;
  }
}

// ---------------------------------------------------------------------------
// chunk_prep v2: K,Q staged bf16 in XOR-swizzled LDS; KK^T/QK^T via MFMA;
// B bf16; T=(I+B)^-1 f32 forward substitution (wave 0); bf16 operand outputs.
// ---------------------------------------------------------------------------
__global__ __launch_bounds__(256) void chunk_prep(
    const float* __restrict__ qn, const float* __restrict__ kn,
    const float* __restrict__ vc, const float* __restrict__ gbuf,
    const float* __restrict__ bet,
    unsigned short* __restrict__ Tg, unsigned short* __restrict__ Gg,
    unsigned short* __restrict__ Wtg, unsigned short* __restrict__ Qtg,
    unsigned short* __restrict__ Khg, float* __restrict__ bvg,
    float* __restrict__ esg) {
  const int h  = blockIdx.x >> 4;
  const int c  = blockIdx.x & 15;
  const int hk = h >> 1;
  const int tid = threadIdx.x;
  const int lane = tid & 63;
  const int w    = tid >> 6;
  const int lr   = lane & 15;
  const int lk   = lane >> 4;

  __shared__ unsigned short Kb[64 * 128];   // 16 KB, swizzled rows of 256B
  __shared__ unsigned short Qb[64 * 128];   // 16 KB
  __shared__ unsigned short Bm[64][64];     // 8 KB  (bf16 B matrix)
  __shared__ float Tm[64][65];              // 16.6 KB
  __shared__ float cg[64];
  __shared__ float btl[64];

#pragma unroll
  for (int n = 0; n < 8; ++n) {
    const int idx = tid + 256 * n;
    const int row = idx >> 5;
    const int col = (idx & 31) * 4;
    const float4 kv = *(const float4*)&kn[((size_t)(c * 64 + row) * 8 + hk) * 128 + col];
    const float4 qv = *(const float4*)&qn[((size_t)(c * 64 + row) * 8 + hk) * 128 + col];
    const int boff = row * 256 + ((col * 2) ^ ((row & 7) << 4));
    ushort4 ko = {f2bf(kv.x), f2bf(kv.y), f2bf(kv.z), f2bf(kv.w)};
    ushort4 qo = {f2bf(qv.x), f2bf(qv.y), f2bf(qv.z), f2bf(qv.w)};
    *(ushort4*)((char*)Kb + boff) = ko;
    *(ushort4*)((char*)Qb + boff) = qo;
  }
  if (tid < 64) {
    float g = gbuf[(c * 64 + tid) * 16 + h];
#pragma unroll
    for (int d = 1; d < 64; d <<= 1) {
      const float o = __shfl_up(g, d);
      if (tid >= d) g += o;
    }
    cg[tid] = g;
    btl[tid] = bet[(c * 64 + tid) * 16 + h];
  }
  __syncthreads();

  f32x4 kkacc[4], qkacc[4];
#pragma unroll
  for (int ct = 0; ct < 4; ++ct) {
    kkacc[ct] = (f32x4){0.f, 0.f, 0.f, 0.f};
    qkacc[ct] = (f32x4){0.f, 0.f, 0.f, 0.f};
  }
  {
    const int rowA = 16 * w + lr;
    const int swA  = (rowA & 7) << 4;
#pragma unroll
    for (int ks = 0; ks < 4; ++ks) {
      const int kb = ks * 64 + lk * 16;
      const short8 aK = *(const short8*)((char*)Kb + rowA * 256 + (kb ^ swA));
      const short8 aQ = *(const short8*)((char*)Qb + rowA * 256 + (kb ^ swA));
#pragma unroll
      for (int ct = 0; ct < 4; ++ct) {
        const int rowB = ct * 16 + lr;
        const short8 bK = *(const short8*)((char*)Kb + rowB * 256 + (kb ^ ((rowB & 7) << 4)));
        kkacc[ct] = __builtin_amdgcn_mfma_f32_16x16x32_bf16(aK, bK, kkacc[ct], 0, 0, 0);
        qkacc[ct] = __builtin_amdgcn_mfma_f32_16x16x32_bf16(aQ, bK, qkacc[ct], 0, 0, 0);
      }
    }
  }
#pragma unroll
  for (int ct = 0; ct < 4; ++ct) {
#pragma unroll
    for (int r = 0; r < 4; ++r) {
      const int i = 16 * w + lk * 4 + r;
      const int j = ct * 16 + lr;
      const float e = __expf(cg[i] - cg[j]);
      Bm[i][j] = f2bf((j < i) ? btl[i] * e * kkacc[ct][r] : 0.f);
      const float gv = (j <= i) ? e * qkacc[ct][r] : 0.f;
      Gg[(size_t)blockIdx.x * 4096 + i * 64 + j] = f2bf(gv);
    }
  }
  __syncthreads();

  if (tid < 64) {
    const int l = tid;
    for (int i = 0; i < 64; ++i) {
      float v = (i == l) ? 1.f : 0.f;
      for (int j = 0; j < i; ++j) v -= bf2f(Bm[i][j]) * Tm[j][l];
      Tm[i][l] = v;
    }
  }
  __syncthreads();

#pragma unroll
  for (int n = 0; n < 16; ++n) {
    const int lin = tid + 256 * n;
    Tg[(size_t)blockIdx.x * 4096 + lin] = f2bf(Tm[lin >> 6][lin & 63]);
  }

  const float cglast = cg[63];
#pragma unroll
  for (int n = 0; n < 8; ++n) {
    const int idx = tid + 256 * n;
    const int i = idx >> 5;
    const int dk = (idx & 31) * 4;
    const int boff = i * 256 + ((dk * 2) ^ ((i & 7) << 4));
    const ushort4 kq = *(const ushort4*)((char*)Kb + boff);
    const ushort4 qq = *(const ushort4*)((char*)Qb + boff);
    const float ei = __expf(cg[i]);
    const float wi = btl[i] * ei;
    ushort4 wo = {f2bf(wi * bf2f(kq.x)), f2bf(wi * bf2f(kq.y)),
                  f2bf(wi * bf2f(kq.z)), f2bf(wi * bf2f(kq.w))};
    ushort4 qo = {f2bf(ei * bf2f(qq.x)), f2bf(ei * bf2f(qq.y)),
                  f2bf(ei * bf2f(qq.z)), f2bf(ei * bf2f(qq.w))};
    *(ushort4*)&Wtg[(size_t)blockIdx.x * 8192 + i * 128 + dk] = wo;
    *(ushort4*)&Qtg[(size_t)blockIdx.x * 8192 + i * 128 + dk] = qo;
    const float4 vv = *(const float4*)&vc[((size_t)(c * 64 + i) * 16 + h) * 128 + dk];
    float4 bv4 = {btl[i] * vv.x, btl[i] * vv.y, btl[i] * vv.z, btl[i] * vv.w};
    *(float4*)&bvg[(size_t)blockIdx.x * 8192 + i * 128 + dk] = bv4;
  }
#pragma unroll
  for (int n = 0; n < 32; ++n) {
    const int lin = tid + 256 * n;         // layout [dk][i]
    const int dk = lin >> 6, i = lin & 63;
    const unsigned short kraw =
        *(const unsigned short*)((char*)Kb + i * 256 + ((dk * 2) ^ ((i & 7) << 4)));
    Khg[(size_t)blockIdx.x * 8192 + lin] = f2bf(__expf(cglast - cg[i]) * bf2f(kraw));
  }
  if (tid == 0) esg[blockIdx.x] = __expf(cglast);
}

// ---------------------------------------------------------------------------
// scan_rec v2: serial over 16 chunks, parallel over (h, dv-block of 16).
// Grid mapping h = bid&15 puts all 8 dv-blocks of a head on ONE XCD (L2 share).
// Next-chunk operand fragments prefetched into registers (2 named sets).
// 3 barriers/chunk; Sb fragments read once per chunk.
// ---------------------------------------------------------------------------
struct SFrags {
  short8 wf[4];
  short8 tf[2];
  short8 qf[4];
  short8 gf[2];
  short8 kh[2][2];
  float  bv[4];
  float  es;
};

__device__ __forceinline__ void sload(SFrags& F,
    const unsigned short* __restrict__ Tg, const unsigned short* __restrict__ Gg,
    const unsigned short* __restrict__ Wtg, const unsigned short* __restrict__ Qtg,
    const unsigned short* __restrict__ Khg, const float* __restrict__ bvg,
    const float* __restrict__ esg,
    size_t base, int w, int lr, int lk, int dv0) {
  const unsigned short* T_  = Tg  + base * 4096;
  const unsigned short* G_  = Gg  + base * 4096;
  const unsigned short* W_  = Wtg + base * 8192;
  const unsigned short* Q_  = Qtg + base * 8192;
  const unsigned short* Kh_ = Khg + base * 8192;
  const float* bv_ = bvg + base * 8192;
#pragma unroll
  for (int ks = 0; ks < 4; ++ks) {
    F.wf[ks] = *(const short8*)(W_ + (16 * w + lr) * 128 + ks * 32 + lk * 8);
    F.qf[ks] = *(const short8*)(Q_ + (16 * w + lr) * 128 + ks * 32 + lk * 8);
  }
#pragma unroll
  for (int ks = 0; ks < 2; ++ks) {
    F.tf[ks]    = *(const short8*)(T_ + (16 * w + lr) * 64 + ks * 32 + lk * 8);
    F.gf[ks]    = *(const short8*)(G_ + (16 * w + lr) * 64 + ks * 32 + lk * 8);
    F.kh[0][ks] = *(const short8*)(Kh_ + (32 * w + lr) * 64 + ks * 32 + lk * 8);
    F.kh[1][ks] = *(const short8*)(Kh_ + (32 * w + 16 + lr) * 64 + ks * 32 + lk * 8);
  }
#pragma unroll
  for (int r = 0; r < 4; ++r)
    F.bv[r] = bv_[(16 * w + lk * 4 + r) * 128 + dv0 + lr];
  F.es = esg[base];
}

__global__ __launch_bounds__(256) void scan_rec(
    const unsigned short* __restrict__ Tg, const unsigned short* __restrict__ Gg,
    const unsigned short* __restrict__ Wtg, const unsigned short* __restrict__ Qtg,
    const unsigned short* __restrict__ Khg, const float* __restrict__ bvg,
    const float* __restrict__ esg, float* __restrict__ obuf) {
  const int h   = blockIdx.x & 15;   // same-head blocks -> same XCD
  const int dvb = blockIdx.x >> 4;
  const int dv0 = dvb * 16;
  const int tid = threadIdx.x;
  const int lane = tid & 63;
  const int w   = tid >> 6;
  const int lr  = lane & 15;
  const int lk  = lane >> 4;

  __shared__ unsigned short Sb[16][136];
  __shared__ unsigned short Ub[16][72];
  __shared__ unsigned short Db[16][72];

  for (int n = tid; n < 16 * 136 / 2; n += 256) ((unsigned int*)Sb)[n] = 0u;

  f32x4 sacc0 = {0.f, 0.f, 0.f, 0.f};
  f32x4 sacc1 = {0.f, 0.f, 0.f, 0.f};

  SFrags fA, fB;
  sload(fA, Tg, Gg, Wtg, Qtg, Khg, bvg, esg, (size_t)h * 16, w, lr, lk, dv0);
  __syncthreads();

#define SCAN_CHUNK(F, c)                                                      \
  {                                                                           \
    short8 sb[4];                                                             \
    _Pragma("unroll")                                                         \
    for (int ks = 0; ks < 4; ++ks)                                            \
      sb[ks] = *(const short8*)(&Sb[lr][ks * 32 + lk * 8]);                   \
    f32x4 au = {0.f, 0.f, 0.f, 0.f};                                          \
    _Pragma("unroll")                                                         \
    for (int ks = 0; ks < 4; ++ks)                                            \
      au = __builtin_amdgcn_mfma_f32_16x16x32_bf16(F.wf[ks], sb[ks], au, 0, 0, 0); \
    {                                                                         \
      ushort4 pk;                                                             \
      _Pragma("unroll")                                                       \
      for (int r = 0; r < 4; ++r)                                             \
        ((unsigned short*)&pk)[r] = f2bf(F.bv[r] - au[r]);                    \
      *(ushort4*)&Ub[lr][16 * w + lk * 4] = pk;                               \
    }                                                                         \
    __syncthreads();                                                          \
    f32x4 ad = {0.f, 0.f, 0.f, 0.f};                                          \
    _Pragma("unroll")                                                         \
    for (int ks = 0; ks < 2; ++ks) {                                          \
      const short8 ub = *(const short8*)(&Ub[lr][ks * 32 + lk * 8]);          \
      ad = __builtin_amdgcn_mfma_f32_16x16x32_bf16(F.tf[ks], ub, ad, 0, 0, 0); \
    }                                                                         \
    {                                                                         \
      ushort4 pk;                                                             \
      _Pragma("unroll")                                                       \
      for (int r = 0; r < 4; ++r) ((unsigned short*)&pk)[r] = f2bf(ad[r]);    \
      *(ushort4*)&Db[lr][16 * w + lk * 4] = pk;                               \
    }                                                                         \
    __syncthreads();                                                          \
    short8 dbf[2];                                                            \
    _Pragma("unroll")                                                         \
    for (int ks = 0; ks < 2; ++ks)                                            \
      dbf[ks] = *(const short8*)(&Db[lr][ks * 32 + lk * 8]);                  \
    f32x4 ao = {0.f, 0.f, 0.f, 0.f};                                          \
    _Pragma("unroll")                                                         \
    for (int ks = 0; ks < 4; ++ks)                                            \
      ao = __builtin_amdgcn_mfma_f32_16x16x32_bf16(F.qf[ks], sb[ks], ao, 0, 0, 0); \
    _Pragma("unroll")                                                         \
    for (int ks = 0; ks < 2; ++ks)                                            \
      ao = __builtin_amdgcn_mfma_f32_16x16x32_bf16(F.gf[ks], dbf[ks], ao, 0, 0, 0); \
    _Pragma("unroll")                                                         \
    for (int r = 0; r < 4; ++r) {                                             \
      const int i = 16 * w + lk * 4 + r;                                      \
      obuf[((size_t)((c) * 64 + i) * 16 + h) * 128 + dv0 + lr] = ao[r];       \
    }                                                                         \
    sacc0 *= F.es;                                                            \
    sacc1 *= F.es;                                                            \
    _Pragma("unroll")                                                         \
    for (int ks = 0; ks < 2; ++ks) {                                          \
      sacc0 = __builtin_amdgcn_mfma_f32_16x16x32_bf16(F.kh[0][ks], dbf[ks], sacc0, 0, 0, 0); \
      sacc1 = __builtin_amdgcn_mfma_f32_16x16x32_bf16(F.kh[1][ks], dbf[ks], sacc1, 0, 0, 0); \
    }                                                                         \
    {                                                                         \
      ushort4 p0, p1;                                                         \
      _Pragma("unroll")                                                       \
      for (int r = 0; r < 4; ++r) {                                           \
        ((unsigned short*)&p0)[r] = f2bf(sacc0[r]);                           \
        ((unsigned short*)&p1)[r] = f2bf(sacc1[r]);                           \
      }                                                                       \
      *(ushort4*)&Sb[lr][32 * w + lk * 4] = p0;                               \
      *(ushort4*)&Sb[lr][32 * w + 16 + lk * 4] = p1;                          \
    }                                                                         \
    __syncthreads();                                                          \
  }

  for (int c = 0; c < 16; c += 2) {
    const int c1 = (c + 1 < 15) ? c + 1 : 15;
    const int c2 = (c + 2 < 15) ? c + 2 : 15;
    sload(fB, Tg, Gg, Wtg, Qtg, Khg, bvg, esg, (size_t)h * 16 + c1, w, lr, lk, dv0);
    SCAN_CHUNK(fA, c);
    sload(fA, Tg, Gg, Wtg, Qtg, Khg, bvg, esg, (size_t)h * 16 + c2, w, lr, lk, dv0);
    SCAN_CHUNK(fB, c + 1);
  }
#undef SCAN_CHUNK
}

// ---------------------------------------------------------------------------
// gated RMSNorm -> bf16
// ---------------------------------------------------------------------------
__global__ __launch_bounds__(128) void rmsnorm_kernel(const float* __restrict__ obuf,
                                                      const float* __restrict__ qkvz,
                                                      const float* __restrict__ nw,
                                                      unsigned short* __restrict__ on) {
  const int vh = blockIdx.x;
  const int s  = blockIdx.y;
  const int d  = threadIdx.x;

  const float x = obuf[((size_t)s * 16 + vh) * 128 + d];
  float ss = x * x;
#pragma unroll
  for (int m = 1; m < 64; m <<= 1) ss += __shfl_xor(ss, m);
  __shared__ float red[2];
  if ((threadIdx.x & 63) == 0) red[threadIdx.x >> 6] = ss;
  __syncthreads();
  const float tot = red[0] + red[1];

  const float z = qkvz[(size_t)s * NQKVZ + (vh >> 1) * 768 + 512 + (vh & 1) * 128 + d];
  const float y = x * rsqrtf(tot * (1.f / 128.f) + 1e-6f) * nw[d] *
                  (z / (1.f + expf(-z)));
  on[(size_t)s * 2048 + vh * 128 + d] = f2bf(y);
}

// ---------------------------------------------------------------------------
extern "C" void kernel_launch(void* const* d_in, const int* in_sizes, int n_in,
                              void* d_out, int out_size, void* d_ws, size_t ws_size,
                              hipStream_t stream) {
  const float* hid     = (const float*)d_in[0];
  const float* W_qkvz  = (const float*)d_in[1];
  const float* W_ba    = (const float*)d_in[2];
  const float* conv_w  = (const float*)d_in[3];
  const float* dt_bias = (const float*)d_in[4];
  const float* A_log   = (const float*)d_in[5];
  const float* norm_w  = (const float*)d_in[6];
  const float* W_out   = (const float*)d_in[7];
  float* out = (float*)d_out;

  char* ws = (char*)d_ws;
  float* qkvz = (float*)ws;                 ws += (size_t)SEQ * NQKVZ * 4;   // 24 MB
  char* region2 = ws;                       ws += (size_t)HID * NQKVZ * 2;   // 24 MB
  unsigned short* W1t = (unsigned short*)region2;
  float* qn   = (float*)(region2);
  float* kn   = (float*)(region2 + 4194304);
  float* vc   = (float*)(region2 + 8388608);
  float* obuf = (float*)(region2 + 16777216);
  unsigned short* Xb = (unsigned short*)ws; ws += (size_t)SEQ * HID * 2;     // 4 MB
  unsigned short* on_bf = Xb;
  unsigned short* W2t = (unsigned short*)ws; ws += (size_t)HID * HID * 2;    // 8 MB
  float* gbuf = (float*)ws;                  ws += (size_t)SEQ * 16 * 4;
  float* bet  = (float*)ws;                  ws += (size_t)SEQ * 16 * 4;
  unsigned short* Tg  = (unsigned short*)ws; ws += (size_t)256 * 4096 * 2;
  unsigned short* Gg  = (unsigned short*)ws; ws += (size_t)256 * 4096 * 2;
  unsigned short* Wtg = (unsigned short*)ws; ws += (size_t)256 * 8192 * 2;
  unsigned short* Qtg = (unsigned short*)ws; ws += (size_t)256 * 8192 * 2;
  unsigned short* Khg = (unsigned short*)ws; ws += (size_t)256 * 8192 * 2;
  float* bvg          = (float*)ws;          ws += (size_t)256 * 8192 * 4;
  float* esg          = (float*)ws;          ws += 256 * 4;
  float* Wbt          = (float*)ws;          ws += (size_t)32 * HID * 4;     // 256 KB

  cast_bf16<<<dim3(SEQ * HID / 1024), 256, 0, stream>>>(hid, Xb, SEQ * HID);
  transpose_cast<<<dim3(NQKVZ / 32, HID / 32), 256, 0, stream>>>(W_qkvz, W1t, HID, NQKVZ);
  transpose_cast<<<dim3(HID / 32, HID / 32), 256, 0, stream>>>(W_out, W2t, HID, HID);
  transpose_f32<<<dim3(1, HID / 32), 256, 0, stream>>>(W_ba, Wbt, HID, 32);
  ba_kernel<<<dim3(SEQ / 4), 256, 0, stream>>>(hid, Wbt, A_log, dt_bias, gbuf, bet);
  gemm_bf16<4><<<dim3(NQKVZ / 128, SEQ / 128), 256, 0, stream>>>(Xb, W1t, qkvz,
                                                                 SEQ, NQKVZ, HID);
  conv_kernel<<<dim3(32, SEQ), 128, 0, stream>>>(qkvz, conv_w, qn, kn, vc);
  chunk_prep<<<dim3(256), 256, 0, stream>>>(qn, kn, vc, gbuf, bet,
                                            Tg, Gg, Wtg, Qtg, Khg, bvg, esg);
  scan_rec<<<dim3(128), 256, 0, stream>>>(Tg, Gg, Wtg, Qtg, Khg, bvg, esg, obuf);
  rmsnorm_kernel<<<dim3(16, SEQ), 128, 0, stream>>>(obuf, qkvz, norm_w, on_bf);
  gemm_bf16<2><<<dim3(HID / 64, SEQ / 128), 256, 0, stream>>>(on_bf, W2t, out,
                                                              SEQ, HID, HID);
}

// Round 8
// 218.304 us; speedup vs baseline: 6.5058x; 1.0750x over previous
//
#include <hip/hip_runtime.h>
#include <hip/hip_bf16.h>
#include <math.h>

// Qwen3-Next GatedDeltaNet, B=1, S=1024, HIDDEN=2048
// H_K=8, H_V=16, DK=DV=128, KDIM=1024, VDIM=2048, CONV_DIM=4096, KS=4
// Scan via chunked delta rule: C=64, 16 chunks. Conv fused into chunk_prep.

#define SEQ 1024
#define HID 2048
#define NQKVZ 6144

typedef __attribute__((ext_vector_type(8))) short short8;
typedef __attribute__((ext_vector_type(4))) float f32x4;

__device__ __forceinline__ unsigned short f2bf(float f) {
  __hip_bfloat16 h = __float2bfloat16(f);
  return *reinterpret_cast<unsigned short*>(&h);
}
__device__ __forceinline__ float bf2f(unsigned short u) {
  unsigned int x = ((unsigned int)u) << 16;
  return __int_as_float(x);
}

// async global->LDS, 16B per lane (dest = wave-uniform base + lane*16)
typedef __attribute__((address_space(3))) void lds_void;
typedef const __attribute__((address_space(1))) void g_void;
__device__ __forceinline__ void gload16(const void* g, void* l) {
  __builtin_amdgcn_global_load_lds((g_void*)g, (lds_void*)l, 16, 0, 0);
}

// ---------------------------------------------------------------------------
// elementwise f32 -> bf16 cast
// ---------------------------------------------------------------------------
__global__ __launch_bounds__(256) void cast_bf16(const float* __restrict__ in,
                                                 unsigned short* __restrict__ out,
                                                 int n) {
  const int i = (blockIdx.x * 256 + threadIdx.x) * 4;
  if (i < n) {
    const float4 v = *(const float4*)&in[i];
    ushort4 o;
    o.x = f2bf(v.x); o.y = f2bf(v.y); o.z = f2bf(v.z); o.w = f2bf(v.w);
    *(ushort4*)&out[i] = o;
  }
}

// ---------------------------------------------------------------------------
// W[K][N] f32 -> Wt[N][K] bf16
// ---------------------------------------------------------------------------
__global__ __launch_bounds__(256) void transpose_cast(const float* __restrict__ W,
                                                      unsigned short* __restrict__ Wt,
                                                      int K, int N) {
  __shared__ float tile[32][33];
  const int n0 = blockIdx.x * 32, k0 = blockIdx.y * 32;
  const int tx = threadIdx.x & 31, ty = threadIdx.x >> 5;
#pragma unroll
  for (int r = 0; r < 32; r += 8)
    tile[ty + r][tx] = W[(size_t)(k0 + ty + r) * N + n0 + tx];
  __syncthreads();
#pragma unroll
  for (int r = 0; r < 32; r += 8)
    Wt[(size_t)(n0 + ty + r) * K + k0 + tx] = f2bf(tile[tx][ty + r]);
}

// ---------------------------------------------------------------------------
// W[K][N] f32 -> Wt[N][K] f32 (for W_ba)
// ---------------------------------------------------------------------------
__global__ __launch_bounds__(256) void transpose_f32(const float* __restrict__ W,
                                                     float* __restrict__ Wt,
                                                     int K, int N) {
  __shared__ float tile[32][33];
  const int n0 = blockIdx.x * 32, k0 = blockIdx.y * 32;
  const int tx = threadIdx.x & 31, ty = threadIdx.x >> 5;
#pragma unroll
  for (int r = 0; r < 32; r += 8)
    tile[ty + r][tx] = W[(size_t)(k0 + ty + r) * N + n0 + tx];
  __syncthreads();
#pragma unroll
  for (int r = 0; r < 32; r += 8)
    Wt[(size_t)(n0 + ty + r) * K + k0 + tx] = tile[tx][ty + r];
}

// ---------------------------------------------------------------------------
// bf16 MFMA GEMM: C[M][N] f32 = A[M][K] @ Bt[N][K]^T, both bf16 K-contiguous.
// Block tile (32*MF) x (32*NF), BK=32, 4 waves (2x2), wave (16*MF)x(16*NF).
// Double-buffered LDS; global_load_lds width-16 with PRE-SWIZZLED global src.
// Swizzle: slot ^= (row>>1)&3 -> 16 consecutive rows cover all 8 slots/128B.
// ---------------------------------------------------------------------------
template <int MF, int NF>
__global__ __launch_bounds__(256) void gemm_bf16(const unsigned short* __restrict__ A,
                                                 const unsigned short* __restrict__ Bt,
                                                 float* __restrict__ C,
                                                 int M, int N, int K) {
  constexpr int BM = 32 * MF;
  constexpr int BN = 32 * NF;
  __shared__ unsigned short As[2][BM * 32];
  __shared__ unsigned short Bs[2][BN * 32];

  const int tid  = threadIdx.x;
  const int lane = tid & 63;
  const int w    = tid >> 6;
  const int wm   = w >> 1, wn = w & 1;
  const int row0 = blockIdx.y * BM, col0 = blockIdx.x * BN;

  const int srow  = lane >> 2;
  const int sslot = lane & 3;
  const int r0s   = w * 16 + srow;
  const int sg    = sslot ^ ((r0s >> 1) & 3);

  const unsigned short* agp0 = A  + (size_t)(row0 + r0s) * K + sg * 8;
  const unsigned short* agp1 = agp0 + (size_t)64 * K;
  const unsigned short* bgp0 = Bt + (size_t)(col0 + r0s) * K + sg * 8;
  const unsigned short* bgp1 = bgp0 + (size_t)64 * K;

  const int arow = lane & 15;
  const int asl  = lane >> 4;

  f32x4 acc[MF][NF];
#pragma unroll
  for (int m = 0; m < MF; ++m)
#pragma unroll
    for (int n = 0; n < NF; ++n) acc[m][n] = (f32x4){0.f, 0.f, 0.f, 0.f};

  const int nk = K >> 5;

#define STAGE(bi, kt)                                                        \
  {                                                                          \
    const int ko = (kt) * 32;                                                \
    gload16(agp0 + ko, (char*)As[bi] + w * 1024);                            \
    if (BM == 128) gload16(agp1 + ko, (char*)As[bi] + 4096 + w * 1024);      \
    gload16(bgp0 + ko, (char*)Bs[bi] + w * 1024);                            \
    if (BN == 128) gload16(bgp1 + ko, (char*)Bs[bi] + 4096 + w * 1024);      \
  }

  STAGE(0, 0);
  __syncthreads();

  int cur = 0;
  for (int kt = 0; kt < nk; ++kt) {
    if (kt + 1 < nk) STAGE(cur ^ 1, kt + 1);

    const char* asb = (const char*)As[cur];
    const char* bsb = (const char*)Bs[cur];
    short8 af[MF], bf[NF];
#pragma unroll
    for (int m = 0; m < MF; ++m) {
      const int row = wm * (16 * MF) + m * 16 + arow;
      af[m] = *(const short8*)(asb + row * 64 + ((asl ^ ((row >> 1) & 3)) * 16));
    }
#pragma unroll
    for (int n = 0; n < NF; ++n) {
      const int row = wn * (16 * NF) + n * 16 + arow;
      bf[n] = *(const short8*)(bsb + row * 64 + ((asl ^ ((row >> 1) & 3)) * 16));
    }
#pragma unroll
    for (int m = 0; m < MF; ++m)
#pragma unroll
      for (int n = 0; n < NF; ++n)
        acc[m][n] = __builtin_amdgcn_mfma_f32_16x16x32_bf16(af[m], bf[n], acc[m][n], 0, 0, 0);

    __syncthreads();
    cur ^= 1;
  }
#undef STAGE

#pragma unroll
  for (int m = 0; m < MF; ++m)
#pragma unroll
    for (int n = 0; n < NF; ++n) {
      const int r0 = row0 + wm * (16 * MF) + m * 16 + (lane >> 4) * 4;
      const int c  = col0 + wn * (16 * NF) + n * 16 + (lane & 15);
#pragma unroll
      for (int r = 0; r < 4; ++r)
        C[(size_t)(r0 + r) * N + c] = acc[m][n][r];
    }
}

// ---------------------------------------------------------------------------
// ba: split-K GEMV vs W_ba^T[32][2048] f32, fused activations.
// ---------------------------------------------------------------------------
__global__ __launch_bounds__(256) void ba_kernel(const float* __restrict__ X,
                                                 const float* __restrict__ Wbt,
                                                 const float* __restrict__ A_log,
                                                 const float* __restrict__ dt_bias,
                                                 float* __restrict__ gbuf,
                                                 float* __restrict__ bet) {
  const int col = threadIdx.x & 31;
  const int kg  = threadIdx.x >> 5;
  const int s0  = blockIdx.x * 4;
  const float* wp = Wbt + (size_t)col * HID + kg * 256;
  const float* xp = X + (size_t)s0 * HID + kg * 256;

  float a0 = 0.f, a1 = 0.f, a2 = 0.f, a3 = 0.f;
  for (int kk = 0; kk < 256; kk += 4) {
    const float4 w4 = *(const float4*)&wp[kk];
    const float4 x0 = *(const float4*)&xp[kk];
    const float4 x1 = *(const float4*)&xp[kk + HID];
    const float4 x2 = *(const float4*)&xp[kk + 2 * HID];
    const float4 x3 = *(const float4*)&xp[kk + 3 * HID];
    a0 += x0.x * w4.x + x0.y * w4.y + x0.z * w4.z + x0.w * w4.w;
    a1 += x1.x * w4.x + x1.y * w4.y + x1.z * w4.z + x1.w * w4.w;
    a2 += x2.x * w4.x + x2.y * w4.y + x2.z * w4.z + x2.w * w4.w;
    a3 += x3.x * w4.x + x3.y * w4.y + x3.z * w4.z + x3.w * w4.w;
  }
  __shared__ float red[4][32][9];
  red[0][col][kg] = a0;
  red[1][col][kg] = a1;
  red[2][col][kg] = a2;
  red[3][col][kg] = a3;
  __syncthreads();
  if (threadIdx.x < 128) {
    const int r = threadIdx.x >> 5;
    const int c = threadIdx.x & 31;
    float acc = 0.f;
#pragma unroll
    for (int g = 0; g < 8; ++g) acc += red[r][c][g];
    const int s = s0 + r;
    const int hk = c >> 2, j = c & 3;
    if (j < 2) {
      bet[s * 16 + hk * 2 + j] = 1.f / (1.f + expf(-acc));
    } else {
      const int vh = hk * 2 + (j - 2);
      const float x = acc + dt_bias[vh];
      const float sp = (x > 20.f) ? x : log1pf(expf(x));
      gbuf[s * 16 + vh] = -expf(A_log[vh]) * sp;
    }
  }
}

// ---------------------------------------------------------------------------
// chunk_prep v3: conv+silu+l2norm FUSED into staging (reads qkvz directly).
// K,Q staged bf16 in XOR-swizzled LDS; KK^T/QK^T via MFMA; B bf16;
// T=(I+B)^-1 f32 forward substitution (wave 0); bf16 operand outputs;
// bvg = beta * silu(conv(v)) computed inline.
// ---------------------------------------------------------------------------
__global__ __launch_bounds__(256) void chunk_prep(
    const float* __restrict__ qkvz, const float* __restrict__ conv_w,
    const float* __restrict__ gbuf, const float* __restrict__ bet,
    unsigned short* __restrict__ Tg, unsigned short* __restrict__ Gg,
    unsigned short* __restrict__ Wtg, unsigned short* __restrict__ Qtg,
    unsigned short* __restrict__ Khg, float* __restrict__ bvg,
    float* __restrict__ esg) {
  const int h  = blockIdx.x >> 4;
  const int c  = blockIdx.x & 15;
  const int hk = h >> 1;
  const int tid = threadIdx.x;
  const int lane = tid & 63;
  const int w    = tid >> 6;
  const int lr   = lane & 15;
  const int lk   = lane >> 4;

  __shared__ unsigned short Kb[64 * 128];   // 16 KB, swizzled rows of 256B
  __shared__ unsigned short Qb[64 * 128];   // 16 KB
  __shared__ unsigned short Bm[64][64];     // 8 KB
  __shared__ float Tm[64][65];              // 16.6 KB
  __shared__ float cg[64];
  __shared__ float btl[64];

  const int qcol0 = hk * 768;
  const int kcol0 = hk * 768 + 128;

  // ---- staging with fused conv(KS=4) + SiLU + l2norm
#pragma unroll
  for (int n = 0; n < 8; ++n) {
    const int idx = tid + 256 * n;
    const int row = idx >> 5;         // 0..63 (32 consecutive tids per row)
    const int col = (idx & 31) * 4;
    const int s   = c * 64 + row;
    float wq[4][4], wk[4][4];
#pragma unroll
    for (int x = 0; x < 4; ++x) {
      const float4 a = *(const float4*)&conv_w[(hk * 128 + col + x) * 4];
      const float4 b = *(const float4*)&conv_w[(1024 + hk * 128 + col + x) * 4];
      wq[x][0] = a.x; wq[x][1] = a.y; wq[x][2] = a.z; wq[x][3] = a.w;
      wk[x][0] = b.x; wk[x][1] = b.y; wk[x][2] = b.z; wk[x][3] = b.w;
    }
    float4 qa = {0.f, 0.f, 0.f, 0.f}, ka = {0.f, 0.f, 0.f, 0.f};
#pragma unroll
    for (int j = 0; j < 4; ++j) {
      const int sr = s - 3 + j;
      if (sr >= 0) {
        const float4 xq = *(const float4*)&qkvz[(size_t)sr * NQKVZ + qcol0 + col];
        const float4 xk = *(const float4*)&qkvz[(size_t)sr * NQKVZ + kcol0 + col];
        qa.x = fmaf(wq[0][j], xq.x, qa.x); qa.y = fmaf(wq[1][j], xq.y, qa.y);
        qa.z = fmaf(wq[2][j], xq.z, qa.z); qa.w = fmaf(wq[3][j], xq.w, qa.w);
        ka.x = fmaf(wk[0][j], xk.x, ka.x); ka.y = fmaf(wk[1][j], xk.y, ka.y);
        ka.z = fmaf(wk[2][j], xk.z, ka.z); ka.w = fmaf(wk[3][j], xk.w, ka.w);
      }
    }
    float4 qy, ky;
    qy.x = qa.x / (1.f + __expf(-qa.x)); qy.y = qa.y / (1.f + __expf(-qa.y));
    qy.z = qa.z / (1.f + __expf(-qa.z)); qy.w = qa.w / (1.f + __expf(-qa.w));
    ky.x = ka.x / (1.f + __expf(-ka.x)); ky.y = ka.y / (1.f + __expf(-ka.y));
    ky.z = ka.z / (1.f + __expf(-ka.z)); ky.w = ka.w / (1.f + __expf(-ka.w));
    float qss = qy.x * qy.x + qy.y * qy.y + qy.z * qy.z + qy.w * qy.w;
    float kss = ky.x * ky.x + ky.y * ky.y + ky.z * ky.z + ky.w * ky.w;
#pragma unroll
    for (int m = 1; m <= 16; m <<= 1) {
      qss += __shfl_xor(qss, m);
      kss += __shfl_xor(kss, m);
    }
    const float qsc = rsqrtf(qss + 1e-6f) * 0.08838834764831845f;  // * DK^-0.5
    const float ksc = rsqrtf(kss + 1e-6f);
    const int boff = row * 256 + ((col * 2) ^ ((row & 7) << 4));
    ushort4 ko = {f2bf(ky.x * ksc), f2bf(ky.y * ksc), f2bf(ky.z * ksc), f2bf(ky.w * ksc)};
    ushort4 qo = {f2bf(qy.x * qsc), f2bf(qy.y * qsc), f2bf(qy.z * qsc), f2bf(qy.w * qsc)};
    *(ushort4*)((char*)Kb + boff) = ko;
    *(ushort4*)((char*)Qb + boff) = qo;
  }
  if (tid < 64) {
    float g = gbuf[(c * 64 + tid) * 16 + h];
#pragma unroll
    for (int d = 1; d < 64; d <<= 1) {
      const float o = __shfl_up(g, d);
      if (tid >= d) g += o;
    }
    cg[tid] = g;
    btl[tid] = bet[(c * 64 + tid) * 16 + h];
  }
  __syncthreads();

  // ---- KK^T / QK^T via MFMA
  f32x4 kkacc[4], qkacc[4];
#pragma unroll
  for (int ct = 0; ct < 4; ++ct) {
    kkacc[ct] = (f32x4){0.f, 0.f, 0.f, 0.f};
    qkacc[ct] = (f32x4){0.f, 0.f, 0.f, 0.f};
  }
  {
    const int rowA = 16 * w + lr;
    const int swA  = (rowA & 7) << 4;
#pragma unroll
    for (int ks = 0; ks < 4; ++ks) {
      const int kb = ks * 64 + lk * 16;
      const short8 aK = *(const short8*)((char*)Kb + rowA * 256 + (kb ^ swA));
      const short8 aQ = *(const short8*)((char*)Qb + rowA * 256 + (kb ^ swA));
#pragma unroll
      for (int ct = 0; ct < 4; ++ct) {
        const int rowB = ct * 16 + lr;
        const short8 bK = *(const short8*)((char*)Kb + rowB * 256 + (kb ^ ((rowB & 7) << 4)));
        kkacc[ct] = __builtin_amdgcn_mfma_f32_16x16x32_bf16(aK, bK, kkacc[ct], 0, 0, 0);
        qkacc[ct] = __builtin_amdgcn_mfma_f32_16x16x32_bf16(aQ, bK, qkacc[ct], 0, 0, 0);
      }
    }
  }
#pragma unroll
  for (int ct = 0; ct < 4; ++ct) {
#pragma unroll
    for (int r = 0; r < 4; ++r) {
      const int i = 16 * w + lk * 4 + r;
      const int j = ct * 16 + lr;
      const float e = __expf(cg[i] - cg[j]);
      Bm[i][j] = f2bf((j < i) ? btl[i] * e * kkacc[ct][r] : 0.f);
      const float gv = (j <= i) ? e * qkacc[ct][r] : 0.f;
      Gg[(size_t)blockIdx.x * 4096 + i * 64 + j] = f2bf(gv);
    }
  }
  __syncthreads();

  // ---- T = (I + B)^-1, forward substitution (wave 0, lanes = columns)
  if (tid < 64) {
    const int l = tid;
    for (int i = 0; i < 64; ++i) {
      float v = (i == l) ? 1.f : 0.f;
      for (int j = 0; j < i; ++j) v -= bf2f(Bm[i][j]) * Tm[j][l];
      Tm[i][l] = v;
    }
  }
  __syncthreads();

#pragma unroll
  for (int n = 0; n < 16; ++n) {
    const int lin = tid + 256 * n;
    Tg[(size_t)blockIdx.x * 4096 + lin] = f2bf(Tm[lin >> 6][lin & 63]);
  }

  // ---- chunk operand outputs (+ inline v-conv for bvg)
  const float cglast = cg[63];
  const int vcol0 = hk * 768 + 256 + (h & 1) * 128;
#pragma unroll
  for (int n = 0; n < 8; ++n) {
    const int idx = tid + 256 * n;
    const int i = idx >> 5;
    const int dk = (idx & 31) * 4;
    const int boff = i * 256 + ((dk * 2) ^ ((i & 7) << 4));
    const ushort4 kq = *(const ushort4*)((char*)Kb + boff);
    const ushort4 qq = *(const ushort4*)((char*)Qb + boff);
    const float ei = __expf(cg[i]);
    const float wi = btl[i] * ei;
    ushort4 wo = {f2bf(wi * bf2f(kq.x)), f2bf(wi * bf2f(kq.y)),
                  f2bf(wi * bf2f(kq.z)), f2bf(wi * bf2f(kq.w))};
    ushort4 qo = {f2bf(ei * bf2f(qq.x)), f2bf(ei * bf2f(qq.y)),
                  f2bf(ei * bf2f(qq.z)), f2bf(ei * bf2f(qq.w))};
    *(ushort4*)&Wtg[(size_t)blockIdx.x * 8192 + i * 128 + dk] = wo;
    *(ushort4*)&Qtg[(size_t)blockIdx.x * 8192 + i * 128 + dk] = qo;

    float wv[4][4];
#pragma unroll
    for (int x = 0; x < 4; ++x) {
      const float4 a = *(const float4*)&conv_w[(2048 + h * 128 + dk + x) * 4];
      wv[x][0] = a.x; wv[x][1] = a.y; wv[x][2] = a.z; wv[x][3] = a.w;
    }
    float4 va = {0.f, 0.f, 0.f, 0.f};
    const int s = c * 64 + i;
#pragma unroll
    for (int j = 0; j < 4; ++j) {
      const int sr = s - 3 + j;
      if (sr >= 0) {
        const float4 xv = *(const float4*)&qkvz[(size_t)sr * NQKVZ + vcol0 + dk];
        va.x = fmaf(wv[0][j], xv.x, va.x); va.y = fmaf(wv[1][j], xv.y, va.y);
        va.z = fmaf(wv[2][j], xv.z, va.z); va.w = fmaf(wv[3][j], xv.w, va.w);
      }
    }
    float4 bv4;
    bv4.x = btl[i] * va.x / (1.f + __expf(-va.x));
    bv4.y = btl[i] * va.y / (1.f + __expf(-va.y));
    bv4.z = btl[i] * va.z / (1.f + __expf(-va.z));
    bv4.w = btl[i] * va.w / (1.f + __expf(-va.w));
    *(float4*)&bvg[(size_t)blockIdx.x * 8192 + i * 128 + dk] = bv4;
  }
#pragma unroll
  for (int n = 0; n < 32; ++n) {
    const int lin = tid + 256 * n;         // layout [dk][i]
    const int dk = lin >> 6, i = lin & 63;
    const unsigned short kraw =
        *(const unsigned short*)((char*)Kb + i * 256 + ((dk * 2) ^ ((i & 7) << 4)));
    Khg[(size_t)blockIdx.x * 8192 + lin] = f2bf(__expf(cglast - cg[i]) * bf2f(kraw));
  }
  if (tid == 0) esg[blockIdx.x] = __expf(cglast);
}

// ---------------------------------------------------------------------------
// scan_rec v2 (unchanged): serial over 16 chunks, (h, dv-block) parallel,
// h = bid&15 -> same-head blocks share one XCD's L2; reg-prefetch 2 sets.
// ---------------------------------------------------------------------------
struct SFrags {
  short8 wf[4];
  short8 tf[2];
  short8 qf[4];
  short8 gf[2];
  short8 kh[2][2];
  float  bv[4];
  float  es;
};

__device__ __forceinline__ void sload(SFrags& F,
    const unsigned short* __restrict__ Tg, const unsigned short* __restrict__ Gg,
    const unsigned short* __restrict__ Wtg, const unsigned short* __restrict__ Qtg,
    const unsigned short* __restrict__ Khg, const float* __restrict__ bvg,
    const float* __restrict__ esg,
    size_t base, int w, int lr, int lk, int dv0) {
  const unsigned short* T_  = Tg  + base * 4096;
  const unsigned short* G_  = Gg  + base * 4096;
  const unsigned short* W_  = Wtg + base * 8192;
  const unsigned short* Q_  = Qtg + base * 8192;
  const unsigned short* Kh_ = Khg + base * 8192;
  const float* bv_ = bvg + base * 8192;
#pragma unroll
  for (int ks = 0; ks < 4; ++ks) {
    F.wf[ks] = *(const short8*)(W_ + (16 * w + lr) * 128 + ks * 32 + lk * 8);
    F.qf[ks] = *(const short8*)(Q_ + (16 * w + lr) * 128 + ks * 32 + lk * 8);
  }
#pragma unroll
  for (int ks = 0; ks < 2; ++ks) {
    F.tf[ks]    = *(const short8*)(T_ + (16 * w + lr) * 64 + ks * 32 + lk * 8);
    F.gf[ks]    = *(const short8*)(G_ + (16 * w + lr) * 64 + ks * 32 + lk * 8);
    F.kh[0][ks] = *(const short8*)(Kh_ + (32 * w + lr) * 64 + ks * 32 + lk * 8);
    F.kh[1][ks] = *(const short8*)(Kh_ + (32 * w + 16 + lr) * 64 + ks * 32 + lk * 8);
  }
#pragma unroll
  for (int r = 0; r < 4; ++r)
    F.bv[r] = bv_[(16 * w + lk * 4 + r) * 128 + dv0 + lr];
  F.es = esg[base];
}

__global__ __launch_bounds__(256) void scan_rec(
    const unsigned short* __restrict__ Tg, const unsigned short* __restrict__ Gg,
    const unsigned short* __restrict__ Wtg, const unsigned short* __restrict__ Qtg,
    const unsigned short* __restrict__ Khg, const float* __restrict__ bvg,
    const float* __restrict__ esg, float* __restrict__ obuf) {
  const int h   = blockIdx.x & 15;   // same-head blocks -> same XCD
  const int dvb = blockIdx.x >> 4;
  const int dv0 = dvb * 16;
  const int tid = threadIdx.x;
  const int lane = tid & 63;
  const int w   = tid >> 6;
  const int lr  = lane & 15;
  const int lk  = lane >> 4;

  __shared__ unsigned short Sb[16][136];
  __shared__ unsigned short Ub[16][72];
  __shared__ unsigned short Db[16][72];

  for (int n = tid; n < 16 * 136 / 2; n += 256) ((unsigned int*)Sb)[n] = 0u;

  f32x4 sacc0 = {0.f, 0.f, 0.f, 0.f};
  f32x4 sacc1 = {0.f, 0.f, 0.f, 0.f};

  SFrags fA, fB;
  sload(fA, Tg, Gg, Wtg, Qtg, Khg, bvg, esg, (size_t)h * 16, w, lr, lk, dv0);
  __syncthreads();

#define SCAN_CHUNK(F, c)                                                      \
  {                                                                           \
    short8 sb[4];                                                             \
    _Pragma("unroll")                                                         \
    for (int ks = 0; ks < 4; ++ks)                                            \
      sb[ks] = *(const short8*)(&Sb[lr][ks * 32 + lk * 8]);                   \
    f32x4 au = {0.f, 0.f, 0.f, 0.f};                                          \
    _Pragma("unroll")                                                         \
    for (int ks = 0; ks < 4; ++ks)                                            \
      au = __builtin_amdgcn_mfma_f32_16x16x32_bf16(F.wf[ks], sb[ks], au, 0, 0, 0); \
    {                                                                         \
      ushort4 pk;                                                             \
      _Pragma("unroll")                                                       \
      for (int r = 0; r < 4; ++r)                                             \
        ((unsigned short*)&pk)[r] = f2bf(F.bv[r] - au[r]);                    \
      *(ushort4*)&Ub[lr][16 * w + lk * 4] = pk;                               \
    }                                                                         \
    __syncthreads();                                                          \
    f32x4 ad = {0.f, 0.f, 0.f, 0.f};                                          \
    _Pragma("unroll")                                                         \
    for (int ks = 0; ks < 2; ++ks) {                                          \
      const short8 ub = *(const short8*)(&Ub[lr][ks * 32 + lk * 8]);          \
      ad = __builtin_amdgcn_mfma_f32_16x16x32_bf16(F.tf[ks], ub, ad, 0, 0, 0); \
    }                                                                         \
    {                                                                         \
      ushort4 pk;                                                             \
      _Pragma("unroll")                                                       \
      for (int r = 0; r < 4; ++r) ((unsigned short*)&pk)[r] = f2bf(ad[r]);    \
      *(ushort4*)&Db[lr][16 * w + lk * 4] = pk;                               \
    }                                                                         \
    __syncthreads();                                                          \
    short8 dbf[2];                                                            \
    _Pragma("unroll")                                                         \
    for (int ks = 0; ks < 2; ++ks)                                            \
      dbf[ks] = *(const short8*)(&Db[lr][ks * 32 + lk * 8]);                  \
    f32x4 ao = {0.f, 0.f, 0.f, 0.f};                                          \
    _Pragma("unroll")                                                         \
    for (int ks = 0; ks < 4; ++ks)                                            \
      ao = __builtin_amdgcn_mfma_f32_16x16x32_bf16(F.qf[ks], sb[ks], ao, 0, 0, 0); \
    _Pragma("unroll")                                                         \
    for (int ks = 0; ks < 2; ++ks)                                            \
      ao = __builtin_amdgcn_mfma_f32_16x16x32_bf16(F.gf[ks], dbf[ks], ao, 0, 0, 0); \
    _Pragma("unroll")                                                         \
    for (int r = 0; r < 4; ++r) {                                             \
      const int i = 16 * w + lk * 4 + r;                                      \
      obuf[((size_t)((c) * 64 + i) * 16 + h) * 128 + dv0 + lr] = ao[r];       \
    }                                                                         \
    sacc0 *= F.es;                                                            \
    sacc1 *= F.es;                                                            \
    _Pragma("unroll")                                                         \
    for (int ks = 0; ks < 2; ++ks) {                                          \
      sacc0 = __builtin_amdgcn_mfma_f32_16x16x32_bf16(F.kh[0][ks], dbf[ks], sacc0, 0, 0, 0); \
      sacc1 = __builtin_amdgcn_mfma_f32_16x16x32_bf16(F.kh[1][ks], dbf[ks], sacc1, 0, 0, 0); \
    }                                                                         \
    {                                                                         \
      ushort4 p0, p1;                                                         \
      _Pragma("unroll")                                                       \
      for (int r = 0; r < 4; ++r) {                                           \
        ((unsigned short*)&p0)[r] = f2bf(sacc0[r]);                           \
        ((unsigned short*)&p1)[r] = f2bf(sacc1[r]);                           \
      }                                                                       \
      *(ushort4*)&Sb[lr][32 * w + lk * 4] = p0;                               \
      *(ushort4*)&Sb[lr][32 * w + 16 + lk * 4] = p1;                          \
    }                                                                         \
    __syncthreads();                                                          \
  }

  for (int c = 0; c < 16; c += 2) {
    const int c1 = (c + 1 < 15) ? c + 1 : 15;
    const int c2 = (c + 2 < 15) ? c + 2 : 15;
    sload(fB, Tg, Gg, Wtg, Qtg, Khg, bvg, esg, (size_t)h * 16 + c1, w, lr, lk, dv0);
    SCAN_CHUNK(fA, c);
    sload(fA, Tg, Gg, Wtg, Qtg, Khg, bvg, esg, (size_t)h * 16 + c2, w, lr, lk, dv0);
    SCAN_CHUNK(fB, c + 1);
  }
#undef SCAN_CHUNK
}

// ---------------------------------------------------------------------------
// gated RMSNorm -> bf16
// ---------------------------------------------------------------------------
__global__ __launch_bounds__(128) void rmsnorm_kernel(const float* __restrict__ obuf,
                                                      const float* __restrict__ qkvz,
                                                      const float* __restrict__ nw,
                                                      unsigned short* __restrict__ on) {
  const int vh = blockIdx.x;
  const int s  = blockIdx.y;
  const int d  = threadIdx.x;

  const float x = obuf[((size_t)s * 16 + vh) * 128 + d];
  float ss = x * x;
#pragma unroll
  for (int m = 1; m < 64; m <<= 1) ss += __shfl_xor(ss, m);
  __shared__ float red[2];
  if ((threadIdx.x & 63) == 0) red[threadIdx.x >> 6] = ss;
  __syncthreads();
  const float tot = red[0] + red[1];

  const float z = qkvz[(size_t)s * NQKVZ + (vh >> 1) * 768 + 512 + (vh & 1) * 128 + d];
  const float y = x * rsqrtf(tot * (1.f / 128.f) + 1e-6f) * nw[d] *
                  (z / (1.f + expf(-z)));
  on[(size_t)s * 2048 + vh * 128 + d] = f2bf(y);
}

// ---------------------------------------------------------------------------
extern "C" void kernel_launch(void* const* d_in, const int* in_sizes, int n_in,
                              void* d_out, int out_size, void* d_ws, size_t ws_size,
                              hipStream_t stream) {
  const float* hid     = (const float*)d_in[0];
  const float* W_qkvz  = (const float*)d_in[1];
  const float* W_ba    = (const float*)d_in[2];
  const float* conv_w  = (const float*)d_in[3];
  const float* dt_bias = (const float*)d_in[4];
  const float* A_log   = (const float*)d_in[5];
  const float* norm_w  = (const float*)d_in[6];
  const float* W_out   = (const float*)d_in[7];
  float* out = (float*)d_out;

  char* ws = (char*)d_ws;
  float* qkvz = (float*)ws;                 ws += (size_t)SEQ * NQKVZ * 4;   // 24 MB
  // region2: W1t bf16 (until gemm1); obuf reuses its tail after
  char* region2 = ws;                       ws += (size_t)HID * NQKVZ * 2;   // 24 MB
  unsigned short* W1t = (unsigned short*)region2;
  float* obuf = (float*)(region2 + 16777216);
  unsigned short* Xb = (unsigned short*)ws; ws += (size_t)SEQ * HID * 2;     // 4 MB
  unsigned short* on_bf = Xb;
  unsigned short* W2t = (unsigned short*)ws; ws += (size_t)HID * HID * 2;    // 8 MB
  float* gbuf = (float*)ws;                  ws += (size_t)SEQ * 16 * 4;
  float* bet  = (float*)ws;                  ws += (size_t)SEQ * 16 * 4;
  unsigned short* Tg  = (unsigned short*)ws; ws += (size_t)256 * 4096 * 2;
  unsigned short* Gg  = (unsigned short*)ws; ws += (size_t)256 * 4096 * 2;
  unsigned short* Wtg = (unsigned short*)ws; ws += (size_t)256 * 8192 * 2;
  unsigned short* Qtg = (unsigned short*)ws; ws += (size_t)256 * 8192 * 2;
  unsigned short* Khg = (unsigned short*)ws; ws += (size_t)256 * 8192 * 2;
  float* bvg          = (float*)ws;          ws += (size_t)256 * 8192 * 4;
  float* esg          = (float*)ws;          ws += 256 * 4;
  float* Wbt          = (float*)ws;          ws += (size_t)32 * HID * 4;     // 256 KB

  cast_bf16<<<dim3(SEQ * HID / 1024), 256, 0, stream>>>(hid, Xb, SEQ * HID);
  transpose_cast<<<dim3(NQKVZ / 32, HID / 32), 256, 0, stream>>>(W_qkvz, W1t, HID, NQKVZ);
  transpose_cast<<<dim3(HID / 32, HID / 32), 256, 0, stream>>>(W_out, W2t, HID, HID);
  transpose_f32<<<dim3(1, HID / 32), 256, 0, stream>>>(W_ba, Wbt, HID, 32);
  ba_kernel<<<dim3(SEQ / 4), 256, 0, stream>>>(hid, Wbt, A_log, dt_bias, gbuf, bet);
  // qkvz = X @ W_qkvz  (128x64 tile -> 768 blocks = 3/CU)
  gemm_bf16<4, 2><<<dim3(NQKVZ / 64, SEQ / 128), 256, 0, stream>>>(Xb, W1t, qkvz,
                                                                   SEQ, NQKVZ, HID);
  // conv fused into chunk_prep (reads qkvz directly)
  chunk_prep<<<dim3(256), 256, 0, stream>>>(qkvz, conv_w, gbuf, bet,
                                            Tg, Gg, Wtg, Qtg, Khg, bvg, esg);
  scan_rec<<<dim3(128), 256, 0, stream>>>(Tg, Gg, Wtg, Qtg, Khg, bvg, esg, obuf);
  rmsnorm_kernel<<<dim3(16, SEQ), 128, 0, stream>>>(obuf, qkvz, norm_w, on_bf);
  // out = on @ W_out  (64x64 tile -> 512 blocks = 2/CU)
  gemm_bf16<2, 2><<<dim3(HID / 64, SEQ / 64), 256, 0, stream>>>(on_bf, W2t, out,
                                                                SEQ, HID, HID);
}

// Round 9
// 213.268 us; speedup vs baseline: 6.6595x; 1.0236x over previous
//
#include <hip/hip_runtime.h>
#include <hip/hip_bf16.h>
#include <math.h>

// Qwen3-Next GatedDeltaNet, B=1, S=1024, HIDDEN=2048
// H_K=8, H_V=16, DK=DV=128, KDIM=1024, VDIM=2048, CONV_DIM=4096, KS=4
// Scan via chunked delta rule: C=64, 16 chunks. Conv fused into chunk_prep.
// chunk_prep: wave 0 does the triangular solve WHILE waves 1-3 do the
// operand-output epilogue (independent LDS regions) -> latency overlap.

#define SEQ 1024
#define HID 2048
#define NQKVZ 6144

typedef __attribute__((ext_vector_type(8))) short short8;
typedef __attribute__((ext_vector_type(4))) float f32x4;

__device__ __forceinline__ unsigned short f2bf(float f) {
  __hip_bfloat16 h = __float2bfloat16(f);
  return *reinterpret_cast<unsigned short*>(&h);
}
__device__ __forceinline__ float bf2f(unsigned short u) {
  unsigned int x = ((unsigned int)u) << 16;
  return __int_as_float(x);
}

// async global->LDS, 16B per lane (dest = wave-uniform base + lane*16)
typedef __attribute__((address_space(3))) void lds_void;
typedef const __attribute__((address_space(1))) void g_void;
__device__ __forceinline__ void gload16(const void* g, void* l) {
  __builtin_amdgcn_global_load_lds((g_void*)g, (lds_void*)l, 16, 0, 0);
}

// ---------------------------------------------------------------------------
// elementwise f32 -> bf16 cast
// ---------------------------------------------------------------------------
__global__ __launch_bounds__(256) void cast_bf16(const float* __restrict__ in,
                                                 unsigned short* __restrict__ out,
                                                 int n) {
  const int i = (blockIdx.x * 256 + threadIdx.x) * 4;
  if (i < n) {
    const float4 v = *(const float4*)&in[i];
    ushort4 o;
    o.x = f2bf(v.x); o.y = f2bf(v.y); o.z = f2bf(v.z); o.w = f2bf(v.w);
    *(ushort4*)&out[i] = o;
  }
}

// ---------------------------------------------------------------------------
// merged W_qkvz / W_out transpose-cast: W[K=2048][N] f32 -> Wt[N][K] bf16
// bx < 192 -> W_qkvz (N=6144); else W_out (N=2048)
// ---------------------------------------------------------------------------
__global__ __launch_bounds__(256) void transpose_cast2(const float* __restrict__ W1,
                                                       unsigned short* __restrict__ W1t,
                                                       const float* __restrict__ W2,
                                                       unsigned short* __restrict__ W2t) {
  __shared__ float tile[32][33];
  int bx = blockIdx.x;
  const float* W;
  unsigned short* Wt;
  int N;
  if (bx < 192) { W = W1; Wt = W1t; N = NQKVZ; }
  else          { W = W2; Wt = W2t; N = HID; bx -= 192; }
  const int n0 = bx * 32, k0 = blockIdx.y * 32;
  const int tx = threadIdx.x & 31, ty = threadIdx.x >> 5;
#pragma unroll
  for (int r = 0; r < 32; r += 8)
    tile[ty + r][tx] = W[(size_t)(k0 + ty + r) * N + n0 + tx];
  __syncthreads();
#pragma unroll
  for (int r = 0; r < 32; r += 8)
    Wt[(size_t)(n0 + ty + r) * HID + k0 + tx] = f2bf(tile[tx][ty + r]);
}

// ---------------------------------------------------------------------------
// W[K][N] f32 -> Wt[N][K] f32 (for W_ba)
// ---------------------------------------------------------------------------
__global__ __launch_bounds__(256) void transpose_f32(const float* __restrict__ W,
                                                     float* __restrict__ Wt,
                                                     int K, int N) {
  __shared__ float tile[32][33];
  const int n0 = blockIdx.x * 32, k0 = blockIdx.y * 32;
  const int tx = threadIdx.x & 31, ty = threadIdx.x >> 5;
#pragma unroll
  for (int r = 0; r < 32; r += 8)
    tile[ty + r][tx] = W[(size_t)(k0 + ty + r) * N + n0 + tx];
  __syncthreads();
#pragma unroll
  for (int r = 0; r < 32; r += 8)
    Wt[(size_t)(n0 + ty + r) * K + k0 + tx] = tile[tx][ty + r];
}

// ---------------------------------------------------------------------------
// bf16 MFMA GEMM: C[M][N] f32 = A[M][K] @ Bt[N][K]^T, both bf16 K-contiguous.
// Block tile (32*MF) x (32*NF), BK=32, 4 waves (2x2), wave (16*MF)x(16*NF).
// Double-buffered LDS; global_load_lds width-16 with PRE-SWIZZLED global src.
// Swizzle: slot ^= (row>>1)&3.
// ---------------------------------------------------------------------------
template <int MF, int NF>
__global__ __launch_bounds__(256) void gemm_bf16(const unsigned short* __restrict__ A,
                                                 const unsigned short* __restrict__ Bt,
                                                 float* __restrict__ C,
                                                 int M, int N, int K) {
  constexpr int BM = 32 * MF;
  constexpr int BN = 32 * NF;
  __shared__ unsigned short As[2][BM * 32];
  __shared__ unsigned short Bs[2][BN * 32];

  const int tid  = threadIdx.x;
  const int lane = tid & 63;
  const int w    = tid >> 6;
  const int wm   = w >> 1, wn = w & 1;
  const int row0 = blockIdx.y * BM, col0 = blockIdx.x * BN;

  const int srow  = lane >> 2;
  const int sslot = lane & 3;
  const int r0s   = w * 16 + srow;
  const int sg    = sslot ^ ((r0s >> 1) & 3);

  const unsigned short* agp0 = A  + (size_t)(row0 + r0s) * K + sg * 8;
  const unsigned short* agp1 = agp0 + (size_t)64 * K;
  const unsigned short* bgp0 = Bt + (size_t)(col0 + r0s) * K + sg * 8;
  const unsigned short* bgp1 = bgp0 + (size_t)64 * K;

  const int arow = lane & 15;
  const int asl  = lane >> 4;

  f32x4 acc[MF][NF];
#pragma unroll
  for (int m = 0; m < MF; ++m)
#pragma unroll
    for (int n = 0; n < NF; ++n) acc[m][n] = (f32x4){0.f, 0.f, 0.f, 0.f};

  const int nk = K >> 5;

#define STAGE(bi, kt)                                                        \
  {                                                                          \
    const int ko = (kt) * 32;                                                \
    gload16(agp0 + ko, (char*)As[bi] + w * 1024);                            \
    if (BM == 128) gload16(agp1 + ko, (char*)As[bi] + 4096 + w * 1024);      \
    gload16(bgp0 + ko, (char*)Bs[bi] + w * 1024);                            \
    if (BN == 128) gload16(bgp1 + ko, (char*)Bs[bi] + 4096 + w * 1024);      \
  }

  STAGE(0, 0);
  __syncthreads();

  int cur = 0;
  for (int kt = 0; kt < nk; ++kt) {
    if (kt + 1 < nk) STAGE(cur ^ 1, kt + 1);

    const char* asb = (const char*)As[cur];
    const char* bsb = (const char*)Bs[cur];
    short8 af[MF], bf[NF];
#pragma unroll
    for (int m = 0; m < MF; ++m) {
      const int row = wm * (16 * MF) + m * 16 + arow;
      af[m] = *(const short8*)(asb + row * 64 + ((asl ^ ((row >> 1) & 3)) * 16));
    }
#pragma unroll
    for (int n = 0; n < NF; ++n) {
      const int row = wn * (16 * NF) + n * 16 + arow;
      bf[n] = *(const short8*)(bsb + row * 64 + ((asl ^ ((row >> 1) & 3)) * 16));
    }
#pragma unroll
    for (int m = 0; m < MF; ++m)
#pragma unroll
      for (int n = 0; n < NF; ++n)
        acc[m][n] = __builtin_amdgcn_mfma_f32_16x16x32_bf16(af[m], bf[n], acc[m][n], 0, 0, 0);

    __syncthreads();
    cur ^= 1;
  }
#undef STAGE

#pragma unroll
  for (int m = 0; m < MF; ++m)
#pragma unroll
    for (int n = 0; n < NF; ++n) {
      const int r0 = row0 + wm * (16 * MF) + m * 16 + (lane >> 4) * 4;
      const int c  = col0 + wn * (16 * NF) + n * 16 + (lane & 15);
#pragma unroll
      for (int r = 0; r < 4; ++r)
        C[(size_t)(r0 + r) * N + c] = acc[m][n][r];
    }
}

// ---------------------------------------------------------------------------
// ba: split-K GEMV vs W_ba^T[32][2048] f32, fused activations.
// ---------------------------------------------------------------------------
__global__ __launch_bounds__(256) void ba_kernel(const float* __restrict__ X,
                                                 const float* __restrict__ Wbt,
                                                 const float* __restrict__ A_log,
                                                 const float* __restrict__ dt_bias,
                                                 float* __restrict__ gbuf,
                                                 float* __restrict__ bet) {
  const int col = threadIdx.x & 31;
  const int kg  = threadIdx.x >> 5;
  const int s0  = blockIdx.x * 4;
  const float* wp = Wbt + (size_t)col * HID + kg * 256;
  const float* xp = X + (size_t)s0 * HID + kg * 256;

  float a0 = 0.f, a1 = 0.f, a2 = 0.f, a3 = 0.f;
  for (int kk = 0; kk < 256; kk += 4) {
    const float4 w4 = *(const float4*)&wp[kk];
    const float4 x0 = *(const float4*)&xp[kk];
    const float4 x1 = *(const float4*)&xp[kk + HID];
    const float4 x2 = *(const float4*)&xp[kk + 2 * HID];
    const float4 x3 = *(const float4*)&xp[kk + 3 * HID];
    a0 += x0.x * w4.x + x0.y * w4.y + x0.z * w4.z + x0.w * w4.w;
    a1 += x1.x * w4.x + x1.y * w4.y + x1.z * w4.z + x1.w * w4.w;
    a2 += x2.x * w4.x + x2.y * w4.y + x2.z * w4.z + x2.w * w4.w;
    a3 += x3.x * w4.x + x3.y * w4.y + x3.z * w4.z + x3.w * w4.w;
  }
  __shared__ float red[4][32][9];
  red[0][col][kg] = a0;
  red[1][col][kg] = a1;
  red[2][col][kg] = a2;
  red[3][col][kg] = a3;
  __syncthreads();
  if (threadIdx.x < 128) {
    const int r = threadIdx.x >> 5;
    const int c = threadIdx.x & 31;
    float acc = 0.f;
#pragma unroll
    for (int g = 0; g < 8; ++g) acc += red[r][c][g];
    const int s = s0 + r;
    const int hk = c >> 2, j = c & 3;
    if (j < 2) {
      bet[s * 16 + hk * 2 + j] = 1.f / (1.f + expf(-acc));
    } else {
      const int vh = hk * 2 + (j - 2);
      const float x = acc + dt_bias[vh];
      const float sp = (x > 20.f) ? x : log1pf(expf(x));
      gbuf[s * 16 + vh] = -expf(A_log[vh]) * sp;
    }
  }
}

// ---------------------------------------------------------------------------
// chunk_prep v4: conv+silu+l2norm fused staging; KK^T/QK^T via MFMA;
// WAVE-SPECIALIZED tail: wave 0 runs T=(I+B)^-1 forward substitution while
// waves 1-3 write Wtg/Qtg/bvg/Khg (independent data) -> latency overlap.
// ---------------------------------------------------------------------------
__global__ __launch_bounds__(256) void chunk_prep(
    const float* __restrict__ qkvz, const float* __restrict__ conv_w,
    const float* __restrict__ gbuf, const float* __restrict__ bet,
    unsigned short* __restrict__ Tg, unsigned short* __restrict__ Gg,
    unsigned short* __restrict__ Wtg, unsigned short* __restrict__ Qtg,
    unsigned short* __restrict__ Khg, float* __restrict__ bvg,
    float* __restrict__ esg) {
  const int h  = blockIdx.x >> 4;
  const int c  = blockIdx.x & 15;
  const int hk = h >> 1;
  const int tid = threadIdx.x;
  const int lane = tid & 63;
  const int w    = tid >> 6;
  const int lr   = lane & 15;
  const int lk   = lane >> 4;

  __shared__ unsigned short Kb[64 * 128];   // 16 KB, swizzled rows of 256B
  __shared__ unsigned short Qb[64 * 128];   // 16 KB
  __shared__ unsigned short Bm[64][64];     // 8 KB
  __shared__ float Tm[64][65];              // 16.6 KB
  __shared__ float cg[64];
  __shared__ float btl[64];

  const int qcol0 = hk * 768;
  const int kcol0 = hk * 768 + 128;

  // ---- staging with fused conv(KS=4) + SiLU + l2norm
#pragma unroll
  for (int n = 0; n < 8; ++n) {
    const int idx = tid + 256 * n;
    const int row = idx >> 5;         // 0..63 (32 consecutive tids per row)
    const int col = (idx & 31) * 4;
    const int s   = c * 64 + row;
    float wq[4][4], wk[4][4];
#pragma unroll
    for (int x = 0; x < 4; ++x) {
      const float4 a = *(const float4*)&conv_w[(hk * 128 + col + x) * 4];
      const float4 b = *(const float4*)&conv_w[(1024 + hk * 128 + col + x) * 4];
      wq[x][0] = a.x; wq[x][1] = a.y; wq[x][2] = a.z; wq[x][3] = a.w;
      wk[x][0] = b.x; wk[x][1] = b.y; wk[x][2] = b.z; wk[x][3] = b.w;
    }
    float4 qa = {0.f, 0.f, 0.f, 0.f}, ka = {0.f, 0.f, 0.f, 0.f};
#pragma unroll
    for (int j = 0; j < 4; ++j) {
      const int sr = s - 3 + j;
      if (sr >= 0) {
        const float4 xq = *(const float4*)&qkvz[(size_t)sr * NQKVZ + qcol0 + col];
        const float4 xk = *(const float4*)&qkvz[(size_t)sr * NQKVZ + kcol0 + col];
        qa.x = fmaf(wq[0][j], xq.x, qa.x); qa.y = fmaf(wq[1][j], xq.y, qa.y);
        qa.z = fmaf(wq[2][j], xq.z, qa.z); qa.w = fmaf(wq[3][j], xq.w, qa.w);
        ka.x = fmaf(wk[0][j], xk.x, ka.x); ka.y = fmaf(wk[1][j], xk.y, ka.y);
        ka.z = fmaf(wk[2][j], xk.z, ka.z); ka.w = fmaf(wk[3][j], xk.w, ka.w);
      }
    }
    float4 qy, ky;
    qy.x = qa.x / (1.f + __expf(-qa.x)); qy.y = qa.y / (1.f + __expf(-qa.y));
    qy.z = qa.z / (1.f + __expf(-qa.z)); qy.w = qa.w / (1.f + __expf(-qa.w));
    ky.x = ka.x / (1.f + __expf(-ka.x)); ky.y = ka.y / (1.f + __expf(-ka.y));
    ky.z = ka.z / (1.f + __expf(-ka.z)); ky.w = ka.w / (1.f + __expf(-ka.w));
    float qss = qy.x * qy.x + qy.y * qy.y + qy.z * qy.z + qy.w * qy.w;
    float kss = ky.x * ky.x + ky.y * ky.y + ky.z * ky.z + ky.w * ky.w;
#pragma unroll
    for (int m = 1; m <= 16; m <<= 1) {
      qss += __shfl_xor(qss, m);
      kss += __shfl_xor(kss, m);
    }
    const float qsc = rsqrtf(qss + 1e-6f) * 0.08838834764831845f;  // * DK^-0.5
    const float ksc = rsqrtf(kss + 1e-6f);
    const int boff = row * 256 + ((col * 2) ^ ((row & 7) << 4));
    ushort4 ko = {f2bf(ky.x * ksc), f2bf(ky.y * ksc), f2bf(ky.z * ksc), f2bf(ky.w * ksc)};
    ushort4 qo = {f2bf(qy.x * qsc), f2bf(qy.y * qsc), f2bf(qy.z * qsc), f2bf(qy.w * qsc)};
    *(ushort4*)((char*)Kb + boff) = ko;
    *(ushort4*)((char*)Qb + boff) = qo;
  }
  if (tid < 64) {
    float g = gbuf[(c * 64 + tid) * 16 + h];
#pragma unroll
    for (int d = 1; d < 64; d <<= 1) {
      const float o = __shfl_up(g, d);
      if (tid >= d) g += o;
    }
    cg[tid] = g;
    btl[tid] = bet[(c * 64 + tid) * 16 + h];
  }
  __syncthreads();

  // ---- KK^T / QK^T via MFMA
  f32x4 kkacc[4], qkacc[4];
#pragma unroll
  for (int ct = 0; ct < 4; ++ct) {
    kkacc[ct] = (f32x4){0.f, 0.f, 0.f, 0.f};
    qkacc[ct] = (f32x4){0.f, 0.f, 0.f, 0.f};
  }
  {
    const int rowA = 16 * w + lr;
    const int swA  = (rowA & 7) << 4;
#pragma unroll
    for (int ks = 0; ks < 4; ++ks) {
      const int kb = ks * 64 + lk * 16;
      const short8 aK = *(const short8*)((char*)Kb + rowA * 256 + (kb ^ swA));
      const short8 aQ = *(const short8*)((char*)Qb + rowA * 256 + (kb ^ swA));
#pragma unroll
      for (int ct = 0; ct < 4; ++ct) {
        const int rowB = ct * 16 + lr;
        const short8 bK = *(const short8*)((char*)Kb + rowB * 256 + (kb ^ ((rowB & 7) << 4)));
        kkacc[ct] = __builtin_amdgcn_mfma_f32_16x16x32_bf16(aK, bK, kkacc[ct], 0, 0, 0);
        qkacc[ct] = __builtin_amdgcn_mfma_f32_16x16x32_bf16(aQ, bK, qkacc[ct], 0, 0, 0);
      }
    }
  }
#pragma unroll
  for (int ct = 0; ct < 4; ++ct) {
#pragma unroll
    for (int r = 0; r < 4; ++r) {
      const int i = 16 * w + lk * 4 + r;
      const int j = ct * 16 + lr;
      const float e = __expf(cg[i] - cg[j]);
      Bm[i][j] = f2bf((j < i) ? btl[i] * e * kkacc[ct][r] : 0.f);
      const float gv = (j <= i) ? e * qkacc[ct][r] : 0.f;
      Gg[(size_t)blockIdx.x * 4096 + i * 64 + j] = f2bf(gv);
    }
  }
  __syncthreads();

  // ---- WAVE-SPECIALIZED: wave 0 solves T=(I+B)^-1 while waves 1-3 write
  //      Wtg/Qtg/bvg/Khg (only need Kb/Qb/cg/btl -> no conflict with Tm).
  const float cglast = cg[63];
  if (w == 0) {
    const int l = lane;
    for (int i = 0; i < 64; ++i) {
      float v = (i == l) ? 1.f : 0.f;
      for (int j = 0; j < i; ++j) v -= bf2f(Bm[i][j]) * Tm[j][l];
      Tm[i][l] = v;
    }
    if (lane == 0) esg[blockIdx.x] = __expf(cglast);
  } else {
    const int t2 = tid - 64;  // 0..191
    const int vcol0 = hk * 768 + 256 + (h & 1) * 128;
    for (int idx = t2; idx < 2048; idx += 192) {
      const int i = idx >> 5;
      const int dk = (idx & 31) * 4;
      const int boff = i * 256 + ((dk * 2) ^ ((i & 7) << 4));
      const ushort4 kq = *(const ushort4*)((char*)Kb + boff);
      const ushort4 qq = *(const ushort4*)((char*)Qb + boff);
      const float ei = __expf(cg[i]);
      const float wi = btl[i] * ei;
      ushort4 wo = {f2bf(wi * bf2f(kq.x)), f2bf(wi * bf2f(kq.y)),
                    f2bf(wi * bf2f(kq.z)), f2bf(wi * bf2f(kq.w))};
      ushort4 qo = {f2bf(ei * bf2f(qq.x)), f2bf(ei * bf2f(qq.y)),
                    f2bf(ei * bf2f(qq.z)), f2bf(ei * bf2f(qq.w))};
      *(ushort4*)&Wtg[(size_t)blockIdx.x * 8192 + i * 128 + dk] = wo;
      *(ushort4*)&Qtg[(size_t)blockIdx.x * 8192 + i * 128 + dk] = qo;

      float wv[4][4];
#pragma unroll
      for (int x = 0; x < 4; ++x) {
        const float4 a = *(const float4*)&conv_w[(2048 + h * 128 + dk + x) * 4];
        wv[x][0] = a.x; wv[x][1] = a.y; wv[x][2] = a.z; wv[x][3] = a.w;
      }
      float4 va = {0.f, 0.f, 0.f, 0.f};
      const int s = c * 64 + i;
#pragma unroll
      for (int j = 0; j < 4; ++j) {
        const int sr = s - 3 + j;
        if (sr >= 0) {
          const float4 xv = *(const float4*)&qkvz[(size_t)sr * NQKVZ + vcol0 + dk];
          va.x = fmaf(wv[0][j], xv.x, va.x); va.y = fmaf(wv[1][j], xv.y, va.y);
          va.z = fmaf(wv[2][j], xv.z, va.z); va.w = fmaf(wv[3][j], xv.w, va.w);
        }
      }
      float4 bv4;
      bv4.x = btl[i] * va.x / (1.f + __expf(-va.x));
      bv4.y = btl[i] * va.y / (1.f + __expf(-va.y));
      bv4.z = btl[i] * va.z / (1.f + __expf(-va.z));
      bv4.w = btl[i] * va.w / (1.f + __expf(-va.w));
      *(float4*)&bvg[(size_t)blockIdx.x * 8192 + i * 128 + dk] = bv4;
    }
    for (int lin = t2; lin < 8192; lin += 192) {  // layout [dk][i]
      const int dk = lin >> 6, i = lin & 63;
      const unsigned short kraw =
          *(const unsigned short*)((char*)Kb + i * 256 + ((dk * 2) ^ ((i & 7) << 4)));
      Khg[(size_t)blockIdx.x * 8192 + lin] = f2bf(__expf(cglast - cg[i]) * bf2f(kraw));
    }
  }
  __syncthreads();

#pragma unroll
  for (int n = 0; n < 16; ++n) {
    const int lin = tid + 256 * n;
    Tg[(size_t)blockIdx.x * 4096 + lin] = f2bf(Tm[lin >> 6][lin & 63]);
  }
}

// ---------------------------------------------------------------------------
// scan_rec (unchanged): serial over 16 chunks, (h, dv-block) parallel,
// h = bid&15 -> same-head blocks share one XCD's L2; reg-prefetch 2 sets.
// ---------------------------------------------------------------------------
struct SFrags {
  short8 wf[4];
  short8 tf[2];
  short8 qf[4];
  short8 gf[2];
  short8 kh[2][2];
  float  bv[4];
  float  es;
};

__device__ __forceinline__ void sload(SFrags& F,
    const unsigned short* __restrict__ Tg, const unsigned short* __restrict__ Gg,
    const unsigned short* __restrict__ Wtg, const unsigned short* __restrict__ Qtg,
    const unsigned short* __restrict__ Khg, const float* __restrict__ bvg,
    const float* __restrict__ esg,
    size_t base, int w, int lr, int lk, int dv0) {
  const unsigned short* T_  = Tg  + base * 4096;
  const unsigned short* G_  = Gg  + base * 4096;
  const unsigned short* W_  = Wtg + base * 8192;
  const unsigned short* Q_  = Qtg + base * 8192;
  const unsigned short* Kh_ = Khg + base * 8192;
  const float* bv_ = bvg + base * 8192;
#pragma unroll
  for (int ks = 0; ks < 4; ++ks) {
    F.wf[ks] = *(const short8*)(W_ + (16 * w + lr) * 128 + ks * 32 + lk * 8);
    F.qf[ks] = *(const short8*)(Q_ + (16 * w + lr) * 128 + ks * 32 + lk * 8);
  }
#pragma unroll
  for (int ks = 0; ks < 2; ++ks) {
    F.tf[ks]    = *(const short8*)(T_ + (16 * w + lr) * 64 + ks * 32 + lk * 8);
    F.gf[ks]    = *(const short8*)(G_ + (16 * w + lr) * 64 + ks * 32 + lk * 8);
    F.kh[0][ks] = *(const short8*)(Kh_ + (32 * w + lr) * 64 + ks * 32 + lk * 8);
    F.kh[1][ks] = *(const short8*)(Kh_ + (32 * w + 16 + lr) * 64 + ks * 32 + lk * 8);
  }
#pragma unroll
  for (int r = 0; r < 4; ++r)
    F.bv[r] = bv_[(16 * w + lk * 4 + r) * 128 + dv0 + lr];
  F.es = esg[base];
}

__global__ __launch_bounds__(256) void scan_rec(
    const unsigned short* __restrict__ Tg, const unsigned short* __restrict__ Gg,
    const unsigned short* __restrict__ Wtg, const unsigned short* __restrict__ Qtg,
    const unsigned short* __restrict__ Khg, const float* __restrict__ bvg,
    const float* __restrict__ esg, float* __restrict__ obuf) {
  const int h   = blockIdx.x & 15;   // same-head blocks -> same XCD
  const int dvb = blockIdx.x >> 4;
  const int dv0 = dvb * 16;
  const int tid = threadIdx.x;
  const int lane = tid & 63;
  const int w   = tid >> 6;
  const int lr  = lane & 15;
  const int lk  = lane >> 4;

  __shared__ unsigned short Sb[16][136];
  __shared__ unsigned short Ub[16][72];
  __shared__ unsigned short Db[16][72];

  for (int n = tid; n < 16 * 136 / 2; n += 256) ((unsigned int*)Sb)[n] = 0u;

  f32x4 sacc0 = {0.f, 0.f, 0.f, 0.f};
  f32x4 sacc1 = {0.f, 0.f, 0.f, 0.f};

  SFrags fA, fB;
  sload(fA, Tg, Gg, Wtg, Qtg, Khg, bvg, esg, (size_t)h * 16, w, lr, lk, dv0);
  __syncthreads();

#define SCAN_CHUNK(F, c)                                                      \
  {                                                                           \
    short8 sb[4];                                                             \
    _Pragma("unroll")                                                         \
    for (int ks = 0; ks < 4; ++ks)                                            \
      sb[ks] = *(const short8*)(&Sb[lr][ks * 32 + lk * 8]);                   \
    f32x4 au = {0.f, 0.f, 0.f, 0.f};                                          \
    _Pragma("unroll")                                                         \
    for (int ks = 0; ks < 4; ++ks)                                            \
      au = __builtin_amdgcn_mfma_f32_16x16x32_bf16(F.wf[ks], sb[ks], au, 0, 0, 0); \
    {                                                                         \
      ushort4 pk;                                                             \
      _Pragma("unroll")                                                       \
      for (int r = 0; r < 4; ++r)                                             \
        ((unsigned short*)&pk)[r] = f2bf(F.bv[r] - au[r]);                    \
      *(ushort4*)&Ub[lr][16 * w + lk * 4] = pk;                               \
    }                                                                         \
    __syncthreads();                                                          \
    f32x4 ad = {0.f, 0.f, 0.f, 0.f};                                          \
    _Pragma("unroll")                                                         \
    for (int ks = 0; ks < 2; ++ks) {                                          \
      const short8 ub = *(const short8*)(&Ub[lr][ks * 32 + lk * 8]);          \
      ad = __builtin_amdgcn_mfma_f32_16x16x32_bf16(F.tf[ks], ub, ad, 0, 0, 0); \
    }                                                                         \
    {                                                                         \
      ushort4 pk;                                                             \
      _Pragma("unroll")                                                       \
      for (int r = 0; r < 4; ++r) ((unsigned short*)&pk)[r] = f2bf(ad[r]);    \
      *(ushort4*)&Db[lr][16 * w + lk * 4] = pk;                               \
    }                                                                         \
    __syncthreads();                                                          \
    short8 dbf[2];                                                            \
    _Pragma("unroll")                                                         \
    for (int ks = 0; ks < 2; ++ks)                                            \
      dbf[ks] = *(const short8*)(&Db[lr][ks * 32 + lk * 8]);                  \
    f32x4 ao = {0.f, 0.f, 0.f, 0.f};                                          \
    _Pragma("unroll")                                                         \
    for (int ks = 0; ks < 4; ++ks)                                            \
      ao = __builtin_amdgcn_mfma_f32_16x16x32_bf16(F.qf[ks], sb[ks], ao, 0, 0, 0); \
    _Pragma("unroll")                                                         \
    for (int ks = 0; ks < 2; ++ks)                                            \
      ao = __builtin_amdgcn_mfma_f32_16x16x32_bf16(F.gf[ks], dbf[ks], ao, 0, 0, 0); \
    _Pragma("unroll")                                                         \
    for (int r = 0; r < 4; ++r) {                                             \
      const int i = 16 * w + lk * 4 + r;                                      \
      obuf[((size_t)((c) * 64 + i) * 16 + h) * 128 + dv0 + lr] = ao[r];       \
    }                                                                         \
    sacc0 *= F.es;                                                            \
    sacc1 *= F.es;                                                            \
    _Pragma("unroll")                                                         \
    for (int ks = 0; ks < 2; ++ks) {                                          \
      sacc0 = __builtin_amdgcn_mfma_f32_16x16x32_bf16(F.kh[0][ks], dbf[ks], sacc0, 0, 0, 0); \
      sacc1 = __builtin_amdgcn_mfma_f32_16x16x32_bf16(F.kh[1][ks], dbf[ks], sacc1, 0, 0, 0); \
    }                                                                         \
    {                                                                         \
      ushort4 p0, p1;                                                         \
      _Pragma("unroll")                                                       \
      for (int r = 0; r < 4; ++r) {                                           \
        ((unsigned short*)&p0)[r] = f2bf(sacc0[r]);                           \
        ((unsigned short*)&p1)[r] = f2bf(sacc1[r]);                           \
      }                                                                       \
      *(ushort4*)&Sb[lr][32 * w + lk * 4] = p0;                               \
      *(ushort4*)&Sb[lr][32 * w + 16 + lk * 4] = p1;                          \
    }                                                                         \
    __syncthreads();                                                          \
  }

  for (int c = 0; c < 16; c += 2) {
    const int c1 = (c + 1 < 15) ? c + 1 : 15;
    const int c2 = (c + 2 < 15) ? c + 2 : 15;
    sload(fB, Tg, Gg, Wtg, Qtg, Khg, bvg, esg, (size_t)h * 16 + c1, w, lr, lk, dv0);
    SCAN_CHUNK(fA, c);
    sload(fA, Tg, Gg, Wtg, Qtg, Khg, bvg, esg, (size_t)h * 16 + c2, w, lr, lk, dv0);
    SCAN_CHUNK(fB, c + 1);
  }
#undef SCAN_CHUNK
}

// ---------------------------------------------------------------------------
// gated RMSNorm -> bf16
// ---------------------------------------------------------------------------
__global__ __launch_bounds__(128) void rmsnorm_kernel(const float* __restrict__ obuf,
                                                      const float* __restrict__ qkvz,
                                                      const float* __restrict__ nw,
                                                      unsigned short* __restrict__ on) {
  const int vh = blockIdx.x;
  const int s  = blockIdx.y;
  const int d  = threadIdx.x;

  const float x = obuf[((size_t)s * 16 + vh) * 128 + d];
  float ss = x * x;
#pragma unroll
  for (int m = 1; m < 64; m <<= 1) ss += __shfl_xor(ss, m);
  __shared__ float red[2];
  if ((threadIdx.x & 63) == 0) red[threadIdx.x >> 6] = ss;
  __syncthreads();
  const float tot = red[0] + red[1];

  const float z = qkvz[(size_t)s * NQKVZ + (vh >> 1) * 768 + 512 + (vh & 1) * 128 + d];
  const float y = x * rsqrtf(tot * (1.f / 128.f) + 1e-6f) * nw[d] *
                  (z / (1.f + expf(-z)));
  on[(size_t)s * 2048 + vh * 128 + d] = f2bf(y);
}

// ---------------------------------------------------------------------------
extern "C" void kernel_launch(void* const* d_in, const int* in_sizes, int n_in,
                              void* d_out, int out_size, void* d_ws, size_t ws_size,
                              hipStream_t stream) {
  const float* hid     = (const float*)d_in[0];
  const float* W_qkvz  = (const float*)d_in[1];
  const float* W_ba    = (const float*)d_in[2];
  const float* conv_w  = (const float*)d_in[3];
  const float* dt_bias = (const float*)d_in[4];
  const float* A_log   = (const float*)d_in[5];
  const float* norm_w  = (const float*)d_in[6];
  const float* W_out   = (const float*)d_in[7];
  float* out = (float*)d_out;

  char* ws = (char*)d_ws;
  float* qkvz = (float*)ws;                 ws += (size_t)SEQ * NQKVZ * 4;   // 24 MB
  // region2: W1t bf16 (until gemm1); obuf reuses its tail after
  char* region2 = ws;                       ws += (size_t)HID * NQKVZ * 2;   // 24 MB
  unsigned short* W1t = (unsigned short*)region2;
  float* obuf = (float*)(region2 + 16777216);
  unsigned short* Xb = (unsigned short*)ws; ws += (size_t)SEQ * HID * 2;     // 4 MB
  unsigned short* on_bf = Xb;
  unsigned short* W2t = (unsigned short*)ws; ws += (size_t)HID * HID * 2;    // 8 MB
  float* gbuf = (float*)ws;                  ws += (size_t)SEQ * 16 * 4;
  float* bet  = (float*)ws;                  ws += (size_t)SEQ * 16 * 4;
  unsigned short* Tg  = (unsigned short*)ws; ws += (size_t)256 * 4096 * 2;
  unsigned short* Gg  = (unsigned short*)ws; ws += (size_t)256 * 4096 * 2;
  unsigned short* Wtg = (unsigned short*)ws; ws += (size_t)256 * 8192 * 2;
  unsigned short* Qtg = (unsigned short*)ws; ws += (size_t)256 * 8192 * 2;
  unsigned short* Khg = (unsigned short*)ws; ws += (size_t)256 * 8192 * 2;
  float* bvg          = (float*)ws;          ws += (size_t)256 * 8192 * 4;
  float* esg          = (float*)ws;          ws += 256 * 4;
  float* Wbt          = (float*)ws;          ws += (size_t)32 * HID * 4;     // 256 KB

  cast_bf16<<<dim3(SEQ * HID / 1024), 256, 0, stream>>>(hid, Xb, SEQ * HID);
  transpose_cast2<<<dim3(256, 64), 256, 0, stream>>>(W_qkvz, W1t, W_out, W2t);
  transpose_f32<<<dim3(1, HID / 32), 256, 0, stream>>>(W_ba, Wbt, HID, 32);
  ba_kernel<<<dim3(SEQ / 4), 256, 0, stream>>>(hid, Wbt, A_log, dt_bias, gbuf, bet);
  // qkvz = X @ W_qkvz  (128x64 tile -> 768 blocks = 3/CU)
  gemm_bf16<4, 2><<<dim3(NQKVZ / 64, SEQ / 128), 256, 0, stream>>>(Xb, W1t, qkvz,
                                                                   SEQ, NQKVZ, HID);
  // conv fused into chunk_prep (reads qkvz directly)
  chunk_prep<<<dim3(256), 256, 0, stream>>>(qkvz, conv_w, gbuf, bet,
                                            Tg, Gg, Wtg, Qtg, Khg, bvg, esg);
  scan_rec<<<dim3(128), 256, 0, stream>>>(Tg, Gg, Wtg, Qtg, Khg, bvg, esg, obuf);
  rmsnorm_kernel<<<dim3(16, SEQ), 128, 0, stream>>>(obuf, qkvz, norm_w, on_bf);
  // out = on @ W_out  (64x64 tile -> 512 blocks = 2/CU)
  gemm_bf16<2, 2><<<dim3(HID / 64, SEQ / 64), 256, 0, stream>>>(on_bf, W2t, out,
                                                                SEQ, HID, HID);
}

// Round 10
// 188.755 us; speedup vs baseline: 7.5243x; 1.1299x over previous
//
#include <hip/hip_runtime.h>
#include <hip/hip_bf16.h>
#include <math.h>

// Qwen3-Next GatedDeltaNet, B=1, S=1024, HIDDEN=2048
// H_K=8, H_V=16, DK=DV=128, KDIM=1024, VDIM=2048, CONV_DIM=4096, KS=4
// Scan via chunked delta rule: C=64, 16 chunks. Conv fused into chunk_prep
// (LDS-staged conv input); triangular solve in wave-0 registers.

#define SEQ 1024
#define HID 2048
#define NQKVZ 6144

typedef __attribute__((ext_vector_type(8))) short short8;
typedef __attribute__((ext_vector_type(4))) float f32x4;

__device__ __forceinline__ unsigned short f2bf(float f) {
  __hip_bfloat16 h = __float2bfloat16(f);
  return *reinterpret_cast<unsigned short*>(&h);
}
__device__ __forceinline__ float bf2f(unsigned short u) {
  unsigned int x = ((unsigned int)u) << 16;
  return __int_as_float(x);
}

// async global->LDS, 16B per lane (dest = wave-uniform base + lane*16)
typedef __attribute__((address_space(3))) void lds_void;
typedef const __attribute__((address_space(1))) void g_void;
__device__ __forceinline__ void gload16(const void* g, void* l) {
  __builtin_amdgcn_global_load_lds((g_void*)g, (lds_void*)l, 16, 0, 0);
}

// ---------------------------------------------------------------------------
// elementwise f32 -> bf16 cast
// ---------------------------------------------------------------------------
__global__ __launch_bounds__(256) void cast_bf16(const float* __restrict__ in,
                                                 unsigned short* __restrict__ out,
                                                 int n) {
  const int i = (blockIdx.x * 256 + threadIdx.x) * 4;
  if (i < n) {
    const float4 v = *(const float4*)&in[i];
    ushort4 o;
    o.x = f2bf(v.x); o.y = f2bf(v.y); o.z = f2bf(v.z); o.w = f2bf(v.w);
    *(ushort4*)&out[i] = o;
  }
}

// ---------------------------------------------------------------------------
// merged W_qkvz / W_out transpose-cast: W[K=2048][N] f32 -> Wt[N][K] bf16
// ---------------------------------------------------------------------------
__global__ __launch_bounds__(256) void transpose_cast2(const float* __restrict__ W1,
                                                       unsigned short* __restrict__ W1t,
                                                       const float* __restrict__ W2,
                                                       unsigned short* __restrict__ W2t) {
  __shared__ float tile[32][33];
  int bx = blockIdx.x;
  const float* W;
  unsigned short* Wt;
  int N;
  if (bx < 192) { W = W1; Wt = W1t; N = NQKVZ; }
  else          { W = W2; Wt = W2t; N = HID; bx -= 192; }
  const int n0 = bx * 32, k0 = blockIdx.y * 32;
  const int tx = threadIdx.x & 31, ty = threadIdx.x >> 5;
#pragma unroll
  for (int r = 0; r < 32; r += 8)
    tile[ty + r][tx] = W[(size_t)(k0 + ty + r) * N + n0 + tx];
  __syncthreads();
#pragma unroll
  for (int r = 0; r < 32; r += 8)
    Wt[(size_t)(n0 + ty + r) * HID + k0 + tx] = f2bf(tile[tx][ty + r]);
}

// ---------------------------------------------------------------------------
// W[K][N] f32 -> Wt[N][K] f32 (for W_ba)
// ---------------------------------------------------------------------------
__global__ __launch_bounds__(256) void transpose_f32(const float* __restrict__ W,
                                                     float* __restrict__ Wt,
                                                     int K, int N) {
  __shared__ float tile[32][33];
  const int n0 = blockIdx.x * 32, k0 = blockIdx.y * 32;
  const int tx = threadIdx.x & 31, ty = threadIdx.x >> 5;
#pragma unroll
  for (int r = 0; r < 32; r += 8)
    tile[ty + r][tx] = W[(size_t)(k0 + ty + r) * N + n0 + tx];
  __syncthreads();
#pragma unroll
  for (int r = 0; r < 32; r += 8)
    Wt[(size_t)(n0 + ty + r) * K + k0 + tx] = tile[tx][ty + r];
}

// ---------------------------------------------------------------------------
// bf16 MFMA GEMM: C[M][N] f32 = A[M][K] @ Bt[N][K]^T, both bf16 K-contiguous.
// Block tile (32*MF)x(32*NF), BK=32*KF, 4 waves (2x2), wave (16MF)x(16NF).
// Double-buffered LDS; global_load_lds width-16 with PRE-SWIZZLED global src.
// Swizzle: KF=1: slot ^= (row>>1)&3 (4 slots/64B row);
//          KF=2: slot ^= row&7      (8 slots/128B row). Both 2-way max (free).
// ---------------------------------------------------------------------------
#define SWZ(row) ((KF == 1) ? (((row) >> 1) & 3) : ((row) & 7))

template <int MF, int NF, int KF>
__global__ __launch_bounds__(256) void gemm_bf16(const unsigned short* __restrict__ A,
                                                 const unsigned short* __restrict__ Bt,
                                                 float* __restrict__ C,
                                                 int M, int N, int K) {
  constexpr int BM = 32 * MF, BN = 32 * NF, BK = 32 * KF;
  constexpr int RB  = BK * 2;            // LDS row bytes
  constexpr int APW = (BM * KF / 16) / 4;  // gload16 per wave for A
  constexpr int BPW = (BN * KF / 16) / 4;
  constexpr int RPG = 16 / KF;           // rows per gload16
  __shared__ unsigned short As[2][BM * BK];
  __shared__ unsigned short Bs[2][BN * BK];

  const int tid  = threadIdx.x;
  const int lane = tid & 63;
  const int w    = tid >> 6;
  const int wm   = w >> 1, wn = w & 1;
  const int row0 = blockIdx.y * BM, col0 = blockIdx.x * BN;

  const int lrow  = (KF == 1) ? (lane >> 2) : (lane >> 3);
  const int lslot = lane & (4 * KF - 1);
  const int arow  = lane & 15;

  f32x4 acc[MF][NF];
#pragma unroll
  for (int m = 0; m < MF; ++m)
#pragma unroll
    for (int n = 0; n < NF; ++n) acc[m][n] = (f32x4){0.f, 0.f, 0.f, 0.f};

  auto stage = [&](int bi, int kt) {
    const int ko = kt * BK;
#pragma unroll
    for (int u = 0; u < APW; ++u) {
      const int gu = w * APW + u;
      const int row = gu * RPG + lrow;
      const int sg = lslot ^ SWZ(row);
      gload16(A + (size_t)(row0 + row) * K + ko + sg * 8,
              (char*)As[bi] + gu * 1024 + lane * 16);
    }
#pragma unroll
    for (int u = 0; u < BPW; ++u) {
      const int gu = w * BPW + u;
      const int row = gu * RPG + lrow;
      const int sg = lslot ^ SWZ(row);
      gload16(Bt + (size_t)(col0 + row) * K + ko + sg * 8,
              (char*)Bs[bi] + gu * 1024 + lane * 16);
    }
  };

  stage(0, 0);
  __syncthreads();

  int cur = 0;
  const int nk = K / BK;
  for (int kt = 0; kt < nk; ++kt) {
    if (kt + 1 < nk) stage(cur ^ 1, kt + 1);

    const char* asb = (const char*)As[cur];
    const char* bsb = (const char*)Bs[cur];
    short8 af[MF][KF], bf[NF][KF];
#pragma unroll
    for (int m = 0; m < MF; ++m)
#pragma unroll
      for (int kk = 0; kk < KF; ++kk) {
        const int row = wm * (16 * MF) + m * 16 + arow;
        const int slot = kk * 4 + (lane >> 4);
        af[m][kk] = *(const short8*)(asb + row * RB + ((slot ^ SWZ(row)) * 16));
      }
#pragma unroll
    for (int n = 0; n < NF; ++n)
#pragma unroll
      for (int kk = 0; kk < KF; ++kk) {
        const int row = wn * (16 * NF) + n * 16 + arow;
        const int slot = kk * 4 + (lane >> 4);
        bf[n][kk] = *(const short8*)(bsb + row * RB + ((slot ^ SWZ(row)) * 16));
      }
#pragma unroll
    for (int m = 0; m < MF; ++m)
#pragma unroll
      for (int n = 0; n < NF; ++n)
#pragma unroll
        for (int kk = 0; kk < KF; ++kk)
          acc[m][n] = __builtin_amdgcn_mfma_f32_16x16x32_bf16(af[m][kk], bf[n][kk],
                                                              acc[m][n], 0, 0, 0);

    __syncthreads();
    cur ^= 1;
  }

#pragma unroll
  for (int m = 0; m < MF; ++m)
#pragma unroll
    for (int n = 0; n < NF; ++n) {
      const int r0 = row0 + wm * (16 * MF) + m * 16 + (lane >> 4) * 4;
      const int c  = col0 + wn * (16 * NF) + n * 16 + (lane & 15);
#pragma unroll
      for (int r = 0; r < 4; ++r)
        C[(size_t)(r0 + r) * N + c] = acc[m][n][r];
    }
}

// ---------------------------------------------------------------------------
// ba: split-K GEMV vs W_ba^T[32][2048] f32, fused activations.
// ---------------------------------------------------------------------------
__global__ __launch_bounds__(256) void ba_kernel(const float* __restrict__ X,
                                                 const float* __restrict__ Wbt,
                                                 const float* __restrict__ A_log,
                                                 const float* __restrict__ dt_bias,
                                                 float* __restrict__ gbuf,
                                                 float* __restrict__ bet) {
  const int col = threadIdx.x & 31;
  const int kg  = threadIdx.x >> 5;
  const int s0  = blockIdx.x * 4;
  const float* wp = Wbt + (size_t)col * HID + kg * 256;
  const float* xp = X + (size_t)s0 * HID + kg * 256;

  float a0 = 0.f, a1 = 0.f, a2 = 0.f, a3 = 0.f;
  for (int kk = 0; kk < 256; kk += 4) {
    const float4 w4 = *(const float4*)&wp[kk];
    const float4 x0 = *(const float4*)&xp[kk];
    const float4 x1 = *(const float4*)&xp[kk + HID];
    const float4 x2 = *(const float4*)&xp[kk + 2 * HID];
    const float4 x3 = *(const float4*)&xp[kk + 3 * HID];
    a0 += x0.x * w4.x + x0.y * w4.y + x0.z * w4.z + x0.w * w4.w;
    a1 += x1.x * w4.x + x1.y * w4.y + x1.z * w4.z + x1.w * w4.w;
    a2 += x2.x * w4.x + x2.y * w4.y + x2.z * w4.z + x2.w * w4.w;
    a3 += x3.x * w4.x + x3.y * w4.y + x3.z * w4.z + x3.w * w4.w;
  }
  __shared__ float red[4][32][9];
  red[0][col][kg] = a0;
  red[1][col][kg] = a1;
  red[2][col][kg] = a2;
  red[3][col][kg] = a3;
  __syncthreads();
  if (threadIdx.x < 128) {
    const int r = threadIdx.x >> 5;
    const int c = threadIdx.x & 31;
    float acc = 0.f;
#pragma unroll
    for (int g = 0; g < 8; ++g) acc += red[r][c][g];
    const int s = s0 + r;
    const int hk = c >> 2, j = c & 3;
    if (j < 2) {
      bet[s * 16 + hk * 2 + j] = 1.f / (1.f + expf(-acc));
    } else {
      const int vh = hk * 2 + (j - 2);
      const float x = acc + dt_bias[vh];
      const float sp = (x > 20.f) ? x : log1pf(expf(x));
      gbuf[s * 16 + vh] = -expf(A_log[vh]) * sp;
    }
  }
}

// ---------------------------------------------------------------------------
// chunk_prep v5: conv input rows STAGED into LDS raw buffer (q, then k, then
// v — reused); conv+silu+l2norm from LDS; KK^T/QK^T via MFMA; T=(I+B)^-1 in
// wave-0 REGISTERS (fully unrolled, lane=column) while waves 1-3 write the
// operand outputs. LDS ~77KB -> 2 blocks/CU.
// ---------------------------------------------------------------------------
__global__ __launch_bounds__(256) void chunk_prep(
    const float* __restrict__ qkvz, const float* __restrict__ conv_w,
    const float* __restrict__ gbuf, const float* __restrict__ bet,
    unsigned short* __restrict__ Tg, unsigned short* __restrict__ Gg,
    unsigned short* __restrict__ Wtg, unsigned short* __restrict__ Qtg,
    unsigned short* __restrict__ Khg, float* __restrict__ bvg,
    float* __restrict__ esg) {
  const int h  = blockIdx.x >> 4;
  const int c  = blockIdx.x & 15;
  const int hk = h >> 1;
  const int tid = threadIdx.x;
  const int lane = tid & 63;
  const int w    = tid >> 6;
  const int lr   = lane & 15;
  const int lk   = lane >> 4;

  __shared__ float raw[67][132];            // 35.4 KB conv-input staging
  __shared__ unsigned short Kb[64 * 128];   // 16 KB, swizzled rows of 256B
  __shared__ unsigned short Qb[64 * 128];   // 16 KB
  __shared__ unsigned short Bm[64][64];     // 8 KB
  __shared__ float cg[64];
  __shared__ float btl[64];

  const int s0 = c * 64;
  const int qcol0 = hk * 768;
  const int kcol0 = hk * 768 + 128;
  const int vcol0 = hk * 768 + 256 + (h & 1) * 128;

  // cumulative decay + beta (wave-0 lanes; overlaps with staging issue)
  if (tid < 64) {
    float g = gbuf[(s0 + tid) * 16 + h];
#pragma unroll
    for (int d = 1; d < 64; d <<= 1) {
      const float o = __shfl_up(g, d);
      if (tid >= d) g += o;
    }
    cg[tid] = g;
    btl[tid] = bet[(s0 + tid) * 16 + h];
  }

#define STAGE_RAW(col0_)                                                      \
  for (int idx = tid; idx < 67 * 32; idx += 256) {                            \
    const int r = idx >> 5;                                                   \
    const int cq = (idx & 31) * 4;                                            \
    const int sr = s0 - 3 + r;                                                \
    float4 v = {0.f, 0.f, 0.f, 0.f};                                          \
    if (sr >= 0) v = *(const float4*)&qkvz[(size_t)sr * NQKVZ + (col0_) + cq];\
    *(float4*)&raw[r][cq] = v;                                                \
  }

#define CONV_TO(dst, wbase, isq)                                              \
  for (int n = 0; n < 8; ++n) {                                               \
    const int idx = tid + 256 * n;                                            \
    const int row = idx >> 5;                                                 \
    const int col = (idx & 31) * 4;                                           \
    float wgt[4][4];                                                          \
    _Pragma("unroll")                                                         \
    for (int x = 0; x < 4; ++x) {                                             \
      const float4 a = *(const float4*)&conv_w[((wbase) + hk * 128 + col + x) * 4]; \
      wgt[x][0] = a.x; wgt[x][1] = a.y; wgt[x][2] = a.z; wgt[x][3] = a.w;     \
    }                                                                         \
    float4 ac = {0.f, 0.f, 0.f, 0.f};                                         \
    _Pragma("unroll")                                                         \
    for (int j = 0; j < 4; ++j) {                                             \
      const float4 xr = *(const float4*)&raw[row + j][col];                   \
      ac.x = fmaf(wgt[0][j], xr.x, ac.x); ac.y = fmaf(wgt[1][j], xr.y, ac.y); \
      ac.z = fmaf(wgt[2][j], xr.z, ac.z); ac.w = fmaf(wgt[3][j], xr.w, ac.w); \
    }                                                                         \
    float4 y;                                                                 \
    y.x = ac.x / (1.f + __expf(-ac.x)); y.y = ac.y / (1.f + __expf(-ac.y));   \
    y.z = ac.z / (1.f + __expf(-ac.z)); y.w = ac.w / (1.f + __expf(-ac.w));   \
    float ss = y.x * y.x + y.y * y.y + y.z * y.z + y.w * y.w;                 \
    _Pragma("unroll")                                                         \
    for (int m = 1; m <= 16; m <<= 1) ss += __shfl_xor(ss, m);                \
    float sc = rsqrtf(ss + 1e-6f);                                            \
    if (isq) sc *= 0.08838834764831845f;                                      \
    const int boff = row * 256 + ((col * 2) ^ ((row & 7) << 4));              \
    ushort4 o = {f2bf(y.x * sc), f2bf(y.y * sc), f2bf(y.z * sc), f2bf(y.w * sc)}; \
    *(ushort4*)((char*)(dst) + boff) = o;                                     \
  }

  // Phase A: q
  STAGE_RAW(qcol0);
  __syncthreads();
  CONV_TO(Qb, 0, true);
  __syncthreads();
  // Phase B: k
  STAGE_RAW(kcol0);
  __syncthreads();
  CONV_TO(Kb, 1024, false);
  __syncthreads();
  // Phase C: v staged (consumed after next barrier by epilogue)
  STAGE_RAW(vcol0);

  // ---- KK^T / QK^T via MFMA (reads Kb/Qb only)
  f32x4 kkacc[4], qkacc[4];
#pragma unroll
  for (int ct = 0; ct < 4; ++ct) {
    kkacc[ct] = (f32x4){0.f, 0.f, 0.f, 0.f};
    qkacc[ct] = (f32x4){0.f, 0.f, 0.f, 0.f};
  }
  {
    const int rowA = 16 * w + lr;
    const int swA  = (rowA & 7) << 4;
#pragma unroll
    for (int ks = 0; ks < 4; ++ks) {
      const int kb = ks * 64 + lk * 16;
      const short8 aK = *(const short8*)((char*)Kb + rowA * 256 + (kb ^ swA));
      const short8 aQ = *(const short8*)((char*)Qb + rowA * 256 + (kb ^ swA));
#pragma unroll
      for (int ct = 0; ct < 4; ++ct) {
        const int rowB = ct * 16 + lr;
        const short8 bK = *(const short8*)((char*)Kb + rowB * 256 + (kb ^ ((rowB & 7) << 4)));
        kkacc[ct] = __builtin_amdgcn_mfma_f32_16x16x32_bf16(aK, bK, kkacc[ct], 0, 0, 0);
        qkacc[ct] = __builtin_amdgcn_mfma_f32_16x16x32_bf16(aQ, bK, qkacc[ct], 0, 0, 0);
      }
    }
  }
#pragma unroll
  for (int ct = 0; ct < 4; ++ct) {
#pragma unroll
    for (int r = 0; r < 4; ++r) {
      const int i = 16 * w + lk * 4 + r;
      const int j = ct * 16 + lr;
      const float e = __expf(cg[i] - cg[j]);
      Bm[i][j] = f2bf((j < i) ? btl[i] * e * kkacc[ct][r] : 0.f);
      const float gv = (j <= i) ? e * qkacc[ct][r] : 0.f;
      Gg[(size_t)blockIdx.x * 4096 + i * 64 + j] = f2bf(gv);
    }
  }
  __syncthreads();  // Bm complete; raw-v visible

  // ---- WAVE-SPECIALIZED: wave 0 solves T in registers (lane = column),
  //      waves 1-3 write Wtg/Qtg/bvg/Khg (v-conv from raw LDS).
  const float cglast = cg[63];
  if (w == 0) {
    const int l = lane;
    float Tc[64];
#pragma unroll
    for (int i = 0; i < 64; ++i) {
      float v = (i == l) ? 1.f : 0.f;
#pragma unroll
      for (int j = 0; j < i; ++j) v -= bf2f(Bm[i][j]) * Tc[j];
      Tc[i] = v;
    }
#pragma unroll
    for (int i = 0; i < 64; ++i)
      Tg[(size_t)blockIdx.x * 4096 + i * 64 + l] = f2bf(Tc[i]);
    if (lane == 0) esg[blockIdx.x] = __expf(cglast);
  } else {
    const int t2 = tid - 64;  // 0..191
    for (int idx = t2; idx < 2048; idx += 192) {
      const int i = idx >> 5;
      const int dk = (idx & 31) * 4;
      const int boff = i * 256 + ((dk * 2) ^ ((i & 7) << 4));
      const ushort4 kq = *(const ushort4*)((char*)Kb + boff);
      const ushort4 qq = *(const ushort4*)((char*)Qb + boff);
      const float ei = __expf(cg[i]);
      const float wi = btl[i] * ei;
      ushort4 wo = {f2bf(wi * bf2f(kq.x)), f2bf(wi * bf2f(kq.y)),
                    f2bf(wi * bf2f(kq.z)), f2bf(wi * bf2f(kq.w))};
      ushort4 qo = {f2bf(ei * bf2f(qq.x)), f2bf(ei * bf2f(qq.y)),
                    f2bf(ei * bf2f(qq.z)), f2bf(ei * bf2f(qq.w))};
      *(ushort4*)&Wtg[(size_t)blockIdx.x * 8192 + i * 128 + dk] = wo;
      *(ushort4*)&Qtg[(size_t)blockIdx.x * 8192 + i * 128 + dk] = qo;

      float wv[4][4];
#pragma unroll
      for (int x = 0; x < 4; ++x) {
        const float4 a = *(const float4*)&conv_w[(2048 + h * 128 + dk + x) * 4];
        wv[x][0] = a.x; wv[x][1] = a.y; wv[x][2] = a.z; wv[x][3] = a.w;
      }
      float4 va = {0.f, 0.f, 0.f, 0.f};
#pragma unroll
      for (int j = 0; j < 4; ++j) {
        const float4 xv = *(const float4*)&raw[i + j][dk];
        va.x = fmaf(wv[0][j], xv.x, va.x); va.y = fmaf(wv[1][j], xv.y, va.y);
        va.z = fmaf(wv[2][j], xv.z, va.z); va.w = fmaf(wv[3][j], xv.w, va.w);
      }
      float4 bv4;
      bv4.x = btl[i] * va.x / (1.f + __expf(-va.x));
      bv4.y = btl[i] * va.y / (1.f + __expf(-va.y));
      bv4.z = btl[i] * va.z / (1.f + __expf(-va.z));
      bv4.w = btl[i] * va.w / (1.f + __expf(-va.w));
      *(float4*)&bvg[(size_t)blockIdx.x * 8192 + i * 128 + dk] = bv4;
    }
    for (int lin = t2; lin < 8192; lin += 192) {  // layout [dk][i]
      const int dk = lin >> 6, i = lin & 63;
      const unsigned short kraw =
          *(const unsigned short*)((char*)Kb + i * 256 + ((dk * 2) ^ ((i & 7) << 4)));
      Khg[(size_t)blockIdx.x * 8192 + lin] = f2bf(__expf(cglast - cg[i]) * bf2f(kraw));
    }
  }
#undef STAGE_RAW
#undef CONV_TO
}

// ---------------------------------------------------------------------------
// scan_rec (unchanged): serial over 16 chunks, (h, dv-block) parallel,
// h = bid&15 -> same-head blocks share one XCD's L2; reg-prefetch 2 sets.
// ---------------------------------------------------------------------------
struct SFrags {
  short8 wf[4];
  short8 tf[2];
  short8 qf[4];
  short8 gf[2];
  short8 kh[2][2];
  float  bv[4];
  float  es;
};

__device__ __forceinline__ void sload(SFrags& F,
    const unsigned short* __restrict__ Tg, const unsigned short* __restrict__ Gg,
    const unsigned short* __restrict__ Wtg, const unsigned short* __restrict__ Qtg,
    const unsigned short* __restrict__ Khg, const float* __restrict__ bvg,
    const float* __restrict__ esg,
    size_t base, int w, int lr, int lk, int dv0) {
  const unsigned short* T_  = Tg  + base * 4096;
  const unsigned short* G_  = Gg  + base * 4096;
  const unsigned short* W_  = Wtg + base * 8192;
  const unsigned short* Q_  = Qtg + base * 8192;
  const unsigned short* Kh_ = Khg + base * 8192;
  const float* bv_ = bvg + base * 8192;
#pragma unroll
  for (int ks = 0; ks < 4; ++ks) {
    F.wf[ks] = *(const short8*)(W_ + (16 * w + lr) * 128 + ks * 32 + lk * 8);
    F.qf[ks] = *(const short8*)(Q_ + (16 * w + lr) * 128 + ks * 32 + lk * 8);
  }
#pragma unroll
  for (int ks = 0; ks < 2; ++ks) {
    F.tf[ks]    = *(const short8*)(T_ + (16 * w + lr) * 64 + ks * 32 + lk * 8);
    F.gf[ks]    = *(const short8*)(G_ + (16 * w + lr) * 64 + ks * 32 + lk * 8);
    F.kh[0][ks] = *(const short8*)(Kh_ + (32 * w + lr) * 64 + ks * 32 + lk * 8);
    F.kh[1][ks] = *(const short8*)(Kh_ + (32 * w + 16 + lr) * 64 + ks * 32 + lk * 8);
  }
#pragma unroll
  for (int r = 0; r < 4; ++r)
    F.bv[r] = bv_[(16 * w + lk * 4 + r) * 128 + dv0 + lr];
  F.es = esg[base];
}

__global__ __launch_bounds__(256) void scan_rec(
    const unsigned short* __restrict__ Tg, const unsigned short* __restrict__ Gg,
    const unsigned short* __restrict__ Wtg, const unsigned short* __restrict__ Qtg,
    const unsigned short* __restrict__ Khg, const float* __restrict__ bvg,
    const float* __restrict__ esg, float* __restrict__ obuf) {
  const int h   = blockIdx.x & 15;   // same-head blocks -> same XCD
  const int dvb = blockIdx.x >> 4;
  const int dv0 = dvb * 16;
  const int tid = threadIdx.x;
  const int lane = tid & 63;
  const int w   = tid >> 6;
  const int lr  = lane & 15;
  const int lk  = lane >> 4;

  __shared__ unsigned short Sb[16][136];
  __shared__ unsigned short Ub[16][72];
  __shared__ unsigned short Db[16][72];

  for (int n = tid; n < 16 * 136 / 2; n += 256) ((unsigned int*)Sb)[n] = 0u;

  f32x4 sacc0 = {0.f, 0.f, 0.f, 0.f};
  f32x4 sacc1 = {0.f, 0.f, 0.f, 0.f};

  SFrags fA, fB;
  sload(fA, Tg, Gg, Wtg, Qtg, Khg, bvg, esg, (size_t)h * 16, w, lr, lk, dv0);
  __syncthreads();

#define SCAN_CHUNK(F, c)                                                      \
  {                                                                           \
    short8 sb[4];                                                             \
    _Pragma("unroll")                                                         \
    for (int ks = 0; ks < 4; ++ks)                                            \
      sb[ks] = *(const short8*)(&Sb[lr][ks * 32 + lk * 8]);                   \
    f32x4 au = {0.f, 0.f, 0.f, 0.f};                                          \
    _Pragma("unroll")                                                         \
    for (int ks = 0; ks < 4; ++ks)                                            \
      au = __builtin_amdgcn_mfma_f32_16x16x32_bf16(F.wf[ks], sb[ks], au, 0, 0, 0); \
    {                                                                         \
      ushort4 pk;                                                             \
      _Pragma("unroll")                                                       \
      for (int r = 0; r < 4; ++r)                                             \
        ((unsigned short*)&pk)[r] = f2bf(F.bv[r] - au[r]);                    \
      *(ushort4*)&Ub[lr][16 * w + lk * 4] = pk;                               \
    }                                                                         \
    __syncthreads();                                                          \
    f32x4 ad = {0.f, 0.f, 0.f, 0.f};                                          \
    _Pragma("unroll")                                                         \
    for (int ks = 0; ks < 2; ++ks) {                                          \
      const short8 ub = *(const short8*)(&Ub[lr][ks * 32 + lk * 8]);          \
      ad = __builtin_amdgcn_mfma_f32_16x16x32_bf16(F.tf[ks], ub, ad, 0, 0, 0); \
    }                                                                         \
    {                                                                         \
      ushort4 pk;                                                             \
      _Pragma("unroll")                                                       \
      for (int r = 0; r < 4; ++r) ((unsigned short*)&pk)[r] = f2bf(ad[r]);    \
      *(ushort4*)&Db[lr][16 * w + lk * 4] = pk;                               \
    }                                                                         \
    __syncthreads();                                                          \
    short8 dbf[2];                                                            \
    _Pragma("unroll")                                                         \
    for (int ks = 0; ks < 2; ++ks)                                            \
      dbf[ks] = *(const short8*)(&Db[lr][ks * 32 + lk * 8]);                  \
    f32x4 ao = {0.f, 0.f, 0.f, 0.f};                                          \
    _Pragma("unroll")                                                         \
    for (int ks = 0; ks < 4; ++ks)                                            \
      ao = __builtin_amdgcn_mfma_f32_16x16x32_bf16(F.qf[ks], sb[ks], ao, 0, 0, 0); \
    _Pragma("unroll")                                                         \
    for (int ks = 0; ks < 2; ++ks)                                            \
      ao = __builtin_amdgcn_mfma_f32_16x16x32_bf16(F.gf[ks], dbf[ks], ao, 0, 0, 0); \
    _Pragma("unroll")                                                         \
    for (int r = 0; r < 4; ++r) {                                             \
      const int i = 16 * w + lk * 4 + r;                                      \
      obuf[((size_t)((c) * 64 + i) * 16 + h) * 128 + dv0 + lr] = ao[r];       \
    }                                                                         \
    sacc0 *= F.es;                                                            \
    sacc1 *= F.es;                                                            \
    _Pragma("unroll")                                                         \
    for (int ks = 0; ks < 2; ++ks) {                                          \
      sacc0 = __builtin_amdgcn_mfma_f32_16x16x32_bf16(F.kh[0][ks], dbf[ks], sacc0, 0, 0, 0); \
      sacc1 = __builtin_amdgcn_mfma_f32_16x16x32_bf16(F.kh[1][ks], dbf[ks], sacc1, 0, 0, 0); \
    }                                                                         \
    {                                                                         \
      ushort4 p0, p1;                                                         \
      _Pragma("unroll")                                                       \
      for (int r = 0; r < 4; ++r) {                                           \
        ((unsigned short*)&p0)[r] = f2bf(sacc0[r]);                           \
        ((unsigned short*)&p1)[r] = f2bf(sacc1[r]);                           \
      }                                                                       \
      *(ushort4*)&Sb[lr][32 * w + lk * 4] = p0;                               \
      *(ushort4*)&Sb[lr][32 * w + 16 + lk * 4] = p1;                          \
    }                                                                         \
    __syncthreads();                                                          \
  }

  for (int c = 0; c < 16; c += 2) {
    const int c1 = (c + 1 < 15) ? c + 1 : 15;
    const int c2 = (c + 2 < 15) ? c + 2 : 15;
    sload(fB, Tg, Gg, Wtg, Qtg, Khg, bvg, esg, (size_t)h * 16 + c1, w, lr, lk, dv0);
    SCAN_CHUNK(fA, c);
    sload(fA, Tg, Gg, Wtg, Qtg, Khg, bvg, esg, (size_t)h * 16 + c2, w, lr, lk, dv0);
    SCAN_CHUNK(fB, c + 1);
  }
#undef SCAN_CHUNK
}

// ---------------------------------------------------------------------------
// gated RMSNorm -> bf16
// ---------------------------------------------------------------------------
__global__ __launch_bounds__(128) void rmsnorm_kernel(const float* __restrict__ obuf,
                                                      const float* __restrict__ qkvz,
                                                      const float* __restrict__ nw,
                                                      unsigned short* __restrict__ on) {
  const int vh = blockIdx.x;
  const int s  = blockIdx.y;
  const int d  = threadIdx.x;

  const float x = obuf[((size_t)s * 16 + vh) * 128 + d];
  float ss = x * x;
#pragma unroll
  for (int m = 1; m < 64; m <<= 1) ss += __shfl_xor(ss, m);
  __shared__ float red[2];
  if ((threadIdx.x & 63) == 0) red[threadIdx.x >> 6] = ss;
  __syncthreads();
  const float tot = red[0] + red[1];

  const float z = qkvz[(size_t)s * NQKVZ + (vh >> 1) * 768 + 512 + (vh & 1) * 128 + d];
  const float y = x * rsqrtf(tot * (1.f / 128.f) + 1e-6f) * nw[d] *
                  (z / (1.f + expf(-z)));
  on[(size_t)s * 2048 + vh * 128 + d] = f2bf(y);
}

// ---------------------------------------------------------------------------
extern "C" void kernel_launch(void* const* d_in, const int* in_sizes, int n_in,
                              void* d_out, int out_size, void* d_ws, size_t ws_size,
                              hipStream_t stream) {
  const float* hid     = (const float*)d_in[0];
  const float* W_qkvz  = (const float*)d_in[1];
  const float* W_ba    = (const float*)d_in[2];
  const float* conv_w  = (const float*)d_in[3];
  const float* dt_bias = (const float*)d_in[4];
  const float* A_log   = (const float*)d_in[5];
  const float* norm_w  = (const float*)d_in[6];
  const float* W_out   = (const float*)d_in[7];
  float* out = (float*)d_out;

  char* ws = (char*)d_ws;
  float* qkvz = (float*)ws;                 ws += (size_t)SEQ * NQKVZ * 4;   // 24 MB
  // region2: W1t bf16 (until gemm1); obuf reuses its tail after
  char* region2 = ws;                       ws += (size_t)HID * NQKVZ * 2;   // 24 MB
  unsigned short* W1t = (unsigned short*)region2;
  float* obuf = (float*)(region2 + 16777216);
  unsigned short* Xb = (unsigned short*)ws; ws += (size_t)SEQ * HID * 2;     // 4 MB
  unsigned short* on_bf = Xb;
  unsigned short* W2t = (unsigned short*)ws; ws += (size_t)HID * HID * 2;    // 8 MB
  float* gbuf = (float*)ws;                  ws += (size_t)SEQ * 16 * 4;
  float* bet  = (float*)ws;                  ws += (size_t)SEQ * 16 * 4;
  unsigned short* Tg  = (unsigned short*)ws; ws += (size_t)256 * 4096 * 2;
  unsigned short* Gg  = (unsigned short*)ws; ws += (size_t)256 * 4096 * 2;
  unsigned short* Wtg = (unsigned short*)ws; ws += (size_t)256 * 8192 * 2;
  unsigned short* Qtg = (unsigned short*)ws; ws += (size_t)256 * 8192 * 2;
  unsigned short* Khg = (unsigned short*)ws; ws += (size_t)256 * 8192 * 2;
  float* bvg          = (float*)ws;          ws += (size_t)256 * 8192 * 4;
  float* esg          = (float*)ws;          ws += 256 * 4;
  float* Wbt          = (float*)ws;          ws += (size_t)32 * HID * 4;     // 256 KB

  cast_bf16<<<dim3(SEQ * HID / 1024), 256, 0, stream>>>(hid, Xb, SEQ * HID);
  transpose_cast2<<<dim3(256, 64), 256, 0, stream>>>(W_qkvz, W1t, W_out, W2t);
  transpose_f32<<<dim3(1, HID / 32), 256, 0, stream>>>(W_ba, Wbt, HID, 32);
  ba_kernel<<<dim3(SEQ / 4), 256, 0, stream>>>(hid, Wbt, A_log, dt_bias, gbuf, bet);
  // qkvz = X @ W_qkvz  (128x128 tile, BK=64 -> half the barrier drains)
  gemm_bf16<4, 4, 2><<<dim3(NQKVZ / 128, SEQ / 128), 256, 0, stream>>>(Xb, W1t, qkvz,
                                                                       SEQ, NQKVZ, HID);
  // conv fused into chunk_prep (LDS-staged conv input)
  chunk_prep<<<dim3(256), 256, 0, stream>>>(qkvz, conv_w, gbuf, bet,
                                            Tg, Gg, Wtg, Qtg, Khg, bvg, esg);
  scan_rec<<<dim3(128), 256, 0, stream>>>(Tg, Gg, Wtg, Qtg, Khg, bvg, esg, obuf);
  rmsnorm_kernel<<<dim3(16, SEQ), 128, 0, stream>>>(obuf, qkvz, norm_w, on_bf);
  // out = on @ W_out  (64x64 tile, BK=32 -> 512 blocks = 2/CU)
  gemm_bf16<2, 2, 1><<<dim3(HID / 64, SEQ / 64), 256, 0, stream>>>(on_bf, W2t, out,
                                                                   SEQ, HID, HID);
}

// Round 11
// 176.801 us; speedup vs baseline: 8.0330x; 1.0676x over previous
//
#include <hip/hip_runtime.h>
#include <hip/hip_bf16.h>
#include <math.h>

// Qwen3-Next GatedDeltaNet, B=1, S=1024, HIDDEN=2048
// H_K=8, H_V=16, DK=DV=128, KDIM=1024, VDIM=2048, CONV_DIM=4096, KS=4
// Chunked delta rule: C=64, 16 chunks. Conv fused in chunk_prep (512 thr,
// reg-prefetch staging pipeline, wave0 solve || 7-wave epilogue).

#define SEQ 1024
#define HID 2048
#define NQKVZ 6144

typedef __attribute__((ext_vector_type(8))) short short8;
typedef __attribute__((ext_vector_type(4))) float f32x4;

__device__ __forceinline__ unsigned short f2bf(float f) {
  __hip_bfloat16 h = __float2bfloat16(f);
  return *reinterpret_cast<unsigned short*>(&h);
}
__device__ __forceinline__ float bf2f(unsigned short u) {
  unsigned int x = ((unsigned int)u) << 16;
  return __int_as_float(x);
}

// async global->LDS, 16B per lane (dest = wave-uniform base + lane*16)
typedef __attribute__((address_space(3))) void lds_void;
typedef const __attribute__((address_space(1))) void g_void;
__device__ __forceinline__ void gload16(const void* g, void* l) {
  __builtin_amdgcn_global_load_lds((g_void*)g, (lds_void*)l, 16, 0, 0);
}

// ---------------------------------------------------------------------------
// elementwise f32 -> bf16 cast
// ---------------------------------------------------------------------------
__global__ __launch_bounds__(256) void cast_bf16(const float* __restrict__ in,
                                                 unsigned short* __restrict__ out,
                                                 int n) {
  const int i = (blockIdx.x * 256 + threadIdx.x) * 4;
  if (i < n) {
    const float4 v = *(const float4*)&in[i];
    ushort4 o;
    o.x = f2bf(v.x); o.y = f2bf(v.y); o.z = f2bf(v.z); o.w = f2bf(v.w);
    *(ushort4*)&out[i] = o;
  }
}

// ---------------------------------------------------------------------------
// merged W_qkvz / W_out transpose-cast: W[K=2048][N] f32 -> Wt[N][K] bf16
// ---------------------------------------------------------------------------
__global__ __launch_bounds__(256) void transpose_cast2(const float* __restrict__ W1,
                                                       unsigned short* __restrict__ W1t,
                                                       const float* __restrict__ W2,
                                                       unsigned short* __restrict__ W2t) {
  __shared__ float tile[32][33];
  int bx = blockIdx.x;
  const float* W;
  unsigned short* Wt;
  int N;
  if (bx < 192) { W = W1; Wt = W1t; N = NQKVZ; }
  else          { W = W2; Wt = W2t; N = HID; bx -= 192; }
  const int n0 = bx * 32, k0 = blockIdx.y * 32;
  const int tx = threadIdx.x & 31, ty = threadIdx.x >> 5;
#pragma unroll
  for (int r = 0; r < 32; r += 8)
    tile[ty + r][tx] = W[(size_t)(k0 + ty + r) * N + n0 + tx];
  __syncthreads();
#pragma unroll
  for (int r = 0; r < 32; r += 8)
    Wt[(size_t)(n0 + ty + r) * HID + k0 + tx] = f2bf(tile[tx][ty + r]);
}

// ---------------------------------------------------------------------------
// W[K][N] f32 -> Wt[N][K] f32 (for W_ba)
// ---------------------------------------------------------------------------
__global__ __launch_bounds__(256) void transpose_f32(const float* __restrict__ W,
                                                     float* __restrict__ Wt,
                                                     int K, int N) {
  __shared__ float tile[32][33];
  const int n0 = blockIdx.x * 32, k0 = blockIdx.y * 32;
  const int tx = threadIdx.x & 31, ty = threadIdx.x >> 5;
#pragma unroll
  for (int r = 0; r < 32; r += 8)
    tile[ty + r][tx] = W[(size_t)(k0 + ty + r) * N + n0 + tx];
  __syncthreads();
#pragma unroll
  for (int r = 0; r < 32; r += 8)
    Wt[(size_t)(n0 + ty + r) * K + k0 + tx] = tile[tx][ty + r];
}

// ---------------------------------------------------------------------------
// bf16 MFMA GEMM: C[M][N] f32 = A[M][K] @ Bt[N][K]^T, both bf16 K-contiguous.
// Block tile (32*MF)x(32*NF), BK=32*KF, 4 waves (2x2), wave (16MF)x(16NF).
// Double-buffered LDS; global_load_lds width-16 with PRE-SWIZZLED global src.
// ---------------------------------------------------------------------------
#define SWZ(row) ((KF == 1) ? (((row) >> 1) & 3) : ((row) & 7))

template <int MF, int NF, int KF>
__global__ __launch_bounds__(256) void gemm_bf16(const unsigned short* __restrict__ A,
                                                 const unsigned short* __restrict__ Bt,
                                                 float* __restrict__ C,
                                                 int M, int N, int K) {
  constexpr int BM = 32 * MF, BN = 32 * NF, BK = 32 * KF;
  constexpr int RB  = BK * 2;
  constexpr int APW = (BM * KF / 16) / 4;
  constexpr int BPW = (BN * KF / 16) / 4;
  constexpr int RPG = 16 / KF;
  __shared__ unsigned short As[2][BM * BK];
  __shared__ unsigned short Bs[2][BN * BK];

  const int tid  = threadIdx.x;
  const int lane = tid & 63;
  const int w    = tid >> 6;
  const int wm   = w >> 1, wn = w & 1;
  const int row0 = blockIdx.y * BM, col0 = blockIdx.x * BN;

  const int lrow  = (KF == 1) ? (lane >> 2) : (lane >> 3);
  const int lslot = lane & (4 * KF - 1);
  const int arow  = lane & 15;

  f32x4 acc[MF][NF];
#pragma unroll
  for (int m = 0; m < MF; ++m)
#pragma unroll
    for (int n = 0; n < NF; ++n) acc[m][n] = (f32x4){0.f, 0.f, 0.f, 0.f};

  auto stage = [&](int bi, int kt) {
    const int ko = kt * BK;
#pragma unroll
    for (int u = 0; u < APW; ++u) {
      const int gu = w * APW + u;
      const int row = gu * RPG + lrow;
      const int sg = lslot ^ SWZ(row);
      gload16(A + (size_t)(row0 + row) * K + ko + sg * 8,
              (char*)As[bi] + gu * 1024 + lane * 16);
    }
#pragma unroll
    for (int u = 0; u < BPW; ++u) {
      const int gu = w * BPW + u;
      const int row = gu * RPG + lrow;
      const int sg = lslot ^ SWZ(row);
      gload16(Bt + (size_t)(col0 + row) * K + ko + sg * 8,
              (char*)Bs[bi] + gu * 1024 + lane * 16);
    }
  };

  stage(0, 0);
  __syncthreads();

  int cur = 0;
  const int nk = K / BK;
  for (int kt = 0; kt < nk; ++kt) {
    if (kt + 1 < nk) stage(cur ^ 1, kt + 1);

    const char* asb = (const char*)As[cur];
    const char* bsb = (const char*)Bs[cur];
    short8 af[MF][KF], bf[NF][KF];
#pragma unroll
    for (int m = 0; m < MF; ++m)
#pragma unroll
      for (int kk = 0; kk < KF; ++kk) {
        const int row = wm * (16 * MF) + m * 16 + arow;
        const int slot = kk * 4 + (lane >> 4);
        af[m][kk] = *(const short8*)(asb + row * RB + ((slot ^ SWZ(row)) * 16));
      }
#pragma unroll
    for (int n = 0; n < NF; ++n)
#pragma unroll
      for (int kk = 0; kk < KF; ++kk) {
        const int row = wn * (16 * NF) + n * 16 + arow;
        const int slot = kk * 4 + (lane >> 4);
        bf[n][kk] = *(const short8*)(bsb + row * RB + ((slot ^ SWZ(row)) * 16));
      }
#pragma unroll
    for (int m = 0; m < MF; ++m)
#pragma unroll
      for (int n = 0; n < NF; ++n)
#pragma unroll
        for (int kk = 0; kk < KF; ++kk)
          acc[m][n] = __builtin_amdgcn_mfma_f32_16x16x32_bf16(af[m][kk], bf[n][kk],
                                                              acc[m][n], 0, 0, 0);

    __syncthreads();
    cur ^= 1;
  }

#pragma unroll
  for (int m = 0; m < MF; ++m)
#pragma unroll
    for (int n = 0; n < NF; ++n) {
      const int r0 = row0 + wm * (16 * MF) + m * 16 + (lane >> 4) * 4;
      const int c  = col0 + wn * (16 * NF) + n * 16 + (lane & 15);
#pragma unroll
      for (int r = 0; r < 4; ++r)
        C[(size_t)(r0 + r) * N + c] = acc[m][n][r];
    }
}

// ---------------------------------------------------------------------------
// ba: split-K GEMV vs W_ba^T[32][2048] f32, fused activations.
// ---------------------------------------------------------------------------
__global__ __launch_bounds__(256) void ba_kernel(const float* __restrict__ X,
                                                 const float* __restrict__ Wbt,
                                                 const float* __restrict__ A_log,
                                                 const float* __restrict__ dt_bias,
                                                 float* __restrict__ gbuf,
                                                 float* __restrict__ bet) {
  const int col = threadIdx.x & 31;
  const int kg  = threadIdx.x >> 5;
  const int s0  = blockIdx.x * 4;
  const float* wp = Wbt + (size_t)col * HID + kg * 256;
  const float* xp = X + (size_t)s0 * HID + kg * 256;

  float a0 = 0.f, a1 = 0.f, a2 = 0.f, a3 = 0.f;
  for (int kk = 0; kk < 256; kk += 4) {
    const float4 w4 = *(const float4*)&wp[kk];
    const float4 x0 = *(const float4*)&xp[kk];
    const float4 x1 = *(const float4*)&xp[kk + HID];
    const float4 x2 = *(const float4*)&xp[kk + 2 * HID];
    const float4 x3 = *(const float4*)&xp[kk + 3 * HID];
    a0 += x0.x * w4.x + x0.y * w4.y + x0.z * w4.z + x0.w * w4.w;
    a1 += x1.x * w4.x + x1.y * w4.y + x1.z * w4.z + x1.w * w4.w;
    a2 += x2.x * w4.x + x2.y * w4.y + x2.z * w4.z + x2.w * w4.w;
    a3 += x3.x * w4.x + x3.y * w4.y + x3.z * w4.z + x3.w * w4.w;
  }
  __shared__ float red[4][32][9];
  red[0][col][kg] = a0;
  red[1][col][kg] = a1;
  red[2][col][kg] = a2;
  red[3][col][kg] = a3;
  __syncthreads();
  if (threadIdx.x < 128) {
    const int r = threadIdx.x >> 5;
    const int c = threadIdx.x & 31;
    float acc = 0.f;
#pragma unroll
    for (int g = 0; g < 8; ++g) acc += red[r][c][g];
    const int s = s0 + r;
    const int hk = c >> 2, j = c & 3;
    if (j < 2) {
      bet[s * 16 + hk * 2 + j] = 1.f / (1.f + expf(-acc));
    } else {
      const int vh = hk * 2 + (j - 2);
      const float x = acc + dt_bias[vh];
      const float sp = (x > 20.f) ? x : log1pf(expf(x));
      gbuf[s * 16 + vh] = -expf(A_log[vh]) * sp;
    }
  }
}

// ---------------------------------------------------------------------------
// chunk_prep v6: 512 threads (8 waves). Conv input staged via REGISTER
// prefetch pipeline (T14): issue next phase's global loads before current
// conv. Dots: waves 0-3 = KK^T, waves 4-7 = QK^T (16 MFMA each). Tail:
// wave 0 solves T=(I+B)^-1 in registers; waves 1-7 write operand outputs.
// ---------------------------------------------------------------------------
#define NT 512
__global__ __launch_bounds__(NT) void chunk_prep(
    const float* __restrict__ qkvz, const float* __restrict__ conv_w,
    const float* __restrict__ gbuf, const float* __restrict__ bet,
    unsigned short* __restrict__ Tg, unsigned short* __restrict__ Gg,
    unsigned short* __restrict__ Wtg, unsigned short* __restrict__ Qtg,
    unsigned short* __restrict__ Khg, float* __restrict__ bvg,
    float* __restrict__ esg) {
  const int h  = blockIdx.x >> 4;
  const int c  = blockIdx.x & 15;
  const int hk = h >> 1;
  const int tid = threadIdx.x;
  const int lane = tid & 63;
  const int w    = tid >> 6;
  const int lr   = lane & 15;
  const int lk   = lane >> 4;

  __shared__ float raw[67][128];            // 34.3 KB conv-input staging
  __shared__ unsigned short Kb[64 * 128];   // 16 KB, swizzled rows of 256B
  __shared__ unsigned short Qb[64 * 128];   // 16 KB
  __shared__ unsigned short Bm[64][64];     // 8 KB
  __shared__ float cg[64];
  __shared__ float btl[64];

  const int s0 = c * 64;
  const int qcol0 = hk * 768;
  const int kcol0 = hk * 768 + 128;
  const int vcol0 = hk * 768 + 256 + (h & 1) * 128;

  if (tid < 64) {
    float g = gbuf[(s0 + tid) * 16 + h];
#pragma unroll
    for (int d = 1; d < 64; d <<= 1) {
      const float o = __shfl_up(g, d);
      if (tid >= d) g += o;
    }
    cg[tid] = g;
    btl[tid] = bet[(s0 + tid) * 16 + h];
  }

  float4 rq[5], rk[5], rv[5];

#define ISSUE(col0_, rg)                                                      \
  _Pragma("unroll")                                                           \
  for (int ii = 0; ii < 5; ++ii) {                                            \
    const int idx = tid + NT * ii;                                            \
    if (idx < 67 * 32) {                                                      \
      const int r = idx >> 5, cq = (idx & 31) * 4;                            \
      const int sr = s0 - 3 + r;                                              \
      if (sr >= 0)                                                            \
        rg[ii] = *(const float4*)&qkvz[(size_t)sr * NQKVZ + (col0_) + cq];    \
      else { rg[ii].x = 0.f; rg[ii].y = 0.f; rg[ii].z = 0.f; rg[ii].w = 0.f; }\
    }                                                                         \
  }

#define WRITE(rg)                                                             \
  _Pragma("unroll")                                                           \
  for (int ii = 0; ii < 5; ++ii) {                                            \
    const int idx = tid + NT * ii;                                            \
    if (idx < 67 * 32) {                                                      \
      const int r = idx >> 5, cq = (idx & 31) * 4;                            \
      *(float4*)&raw[r][cq] = rg[ii];                                         \
    }                                                                         \
  }

#define CONV_TO(dst, wbase, isq)                                              \
  for (int n = 0; n < 4; ++n) {                                               \
    const int idx = tid + NT * n;                                             \
    const int row = idx >> 5;                                                 \
    const int col = (idx & 31) * 4;                                           \
    float wgt[4][4];                                                          \
    _Pragma("unroll")                                                         \
    for (int x = 0; x < 4; ++x) {                                             \
      const float4 a = *(const float4*)&conv_w[((wbase) + hk * 128 + col + x) * 4]; \
      wgt[x][0] = a.x; wgt[x][1] = a.y; wgt[x][2] = a.z; wgt[x][3] = a.w;     \
    }                                                                         \
    float4 ac = {0.f, 0.f, 0.f, 0.f};                                         \
    _Pragma("unroll")                                                         \
    for (int j = 0; j < 4; ++j) {                                             \
      const float4 xr = *(const float4*)&raw[row + j][col];                   \
      ac.x = fmaf(wgt[0][j], xr.x, ac.x); ac.y = fmaf(wgt[1][j], xr.y, ac.y); \
      ac.z = fmaf(wgt[2][j], xr.z, ac.z); ac.w = fmaf(wgt[3][j], xr.w, ac.w); \
    }                                                                         \
    float4 y;                                                                 \
    y.x = ac.x / (1.f + __expf(-ac.x)); y.y = ac.y / (1.f + __expf(-ac.y));   \
    y.z = ac.z / (1.f + __expf(-ac.z)); y.w = ac.w / (1.f + __expf(-ac.w));   \
    float ss = y.x * y.x + y.y * y.y + y.z * y.z + y.w * y.w;                 \
    _Pragma("unroll")                                                         \
    for (int m = 1; m <= 16; m <<= 1) ss += __shfl_xor(ss, m);                \
    float sc = rsqrtf(ss + 1e-6f);                                            \
    if (isq) sc *= 0.08838834764831845f;                                      \
    const int boff = row * 256 + ((col * 2) ^ ((row & 7) << 4));              \
    ushort4 o = {f2bf(y.x * sc), f2bf(y.y * sc), f2bf(y.z * sc), f2bf(y.w * sc)}; \
    *(ushort4*)((char*)(dst) + boff) = o;                                     \
  }

  // pipeline: q load -> raw; (k loads in flight) conv-q; k -> raw;
  // (v loads in flight) conv-k; v -> raw; dots; solve || epilogue.
  ISSUE(qcol0, rq);
  WRITE(rq);
  __syncthreads();
  ISSUE(kcol0, rk);
  CONV_TO(Qb, 0, true);
  __syncthreads();
  WRITE(rk);
  __syncthreads();
  ISSUE(vcol0, rv);
  CONV_TO(Kb, 1024, false);
  __syncthreads();
  WRITE(rv);

  // ---- dots via MFMA: waves 0-3 KK^T, waves 4-7 QK^T (16 MFMA each)
  const bool isK = (w < 4);
  const int w4 = w & 3;
  f32x4 dacc[4];
#pragma unroll
  for (int ct = 0; ct < 4; ++ct) dacc[ct] = (f32x4){0.f, 0.f, 0.f, 0.f};
  {
    const int rowA = 16 * w4 + lr;
    const int swA  = (rowA & 7) << 4;
    const char* Ab = isK ? (const char*)Kb : (const char*)Qb;
#pragma unroll
    for (int ks = 0; ks < 4; ++ks) {
      const int kb = ks * 64 + lk * 16;
      const short8 a = *(const short8*)(Ab + rowA * 256 + (kb ^ swA));
#pragma unroll
      for (int ct = 0; ct < 4; ++ct) {
        const int rowB = ct * 16 + lr;
        const short8 bK = *(const short8*)((char*)Kb + rowB * 256 + (kb ^ ((rowB & 7) << 4)));
        dacc[ct] = __builtin_amdgcn_mfma_f32_16x16x32_bf16(a, bK, dacc[ct], 0, 0, 0);
      }
    }
  }
#pragma unroll
  for (int ct = 0; ct < 4; ++ct) {
#pragma unroll
    for (int r = 0; r < 4; ++r) {
      const int i = 16 * w4 + lk * 4 + r;
      const int j = ct * 16 + lr;
      const float e = __expf(cg[i] - cg[j]);
      if (isK) Bm[i][j] = f2bf((j < i) ? btl[i] * e * dacc[ct][r] : 0.f);
      else     Gg[(size_t)blockIdx.x * 4096 + i * 64 + j] =
                   f2bf((j <= i) ? e * dacc[ct][r] : 0.f);
    }
  }
  __syncthreads();  // Bm/G done; raw-v visible

  // ---- wave 0: register triangular solve; waves 1-7: operand outputs
  const float cglast = cg[63];
  if (w == 0) {
    const int l = lane;
    float Tc[64];
#pragma unroll
    for (int i = 0; i < 64; ++i) {
      float v = (i == l) ? 1.f : 0.f;
#pragma unroll
      for (int j = 0; j < i; ++j) v -= bf2f(Bm[i][j]) * Tc[j];
      Tc[i] = v;
    }
#pragma unroll
    for (int i = 0; i < 64; ++i)
      Tg[(size_t)blockIdx.x * 4096 + i * 64 + l] = f2bf(Tc[i]);
    if (lane == 0) esg[blockIdx.x] = __expf(cglast);
  } else {
    const int t2 = tid - 64;  // 0..447
    for (int idx = t2; idx < 2048; idx += 448) {
      const int i = idx >> 5;
      const int dk = (idx & 31) * 4;
      const int boff = i * 256 + ((dk * 2) ^ ((i & 7) << 4));
      const ushort4 kq = *(const ushort4*)((char*)Kb + boff);
      const ushort4 qq = *(const ushort4*)((char*)Qb + boff);
      const float ei = __expf(cg[i]);
      const float wi = btl[i] * ei;
      ushort4 wo = {f2bf(wi * bf2f(kq.x)), f2bf(wi * bf2f(kq.y)),
                    f2bf(wi * bf2f(kq.z)), f2bf(wi * bf2f(kq.w))};
      ushort4 qo = {f2bf(ei * bf2f(qq.x)), f2bf(ei * bf2f(qq.y)),
                    f2bf(ei * bf2f(qq.z)), f2bf(ei * bf2f(qq.w))};
      *(ushort4*)&Wtg[(size_t)blockIdx.x * 8192 + i * 128 + dk] = wo;
      *(ushort4*)&Qtg[(size_t)blockIdx.x * 8192 + i * 128 + dk] = qo;

      float wv[4][4];
#pragma unroll
      for (int x = 0; x < 4; ++x) {
        const float4 a = *(const float4*)&conv_w[(2048 + h * 128 + dk + x) * 4];
        wv[x][0] = a.x; wv[x][1] = a.y; wv[x][2] = a.z; wv[x][3] = a.w;
      }
      float4 va = {0.f, 0.f, 0.f, 0.f};
#pragma unroll
      for (int j = 0; j < 4; ++j) {
        const float4 xv = *(const float4*)&raw[i + j][dk];
        va.x = fmaf(wv[0][j], xv.x, va.x); va.y = fmaf(wv[1][j], xv.y, va.y);
        va.z = fmaf(wv[2][j], xv.z, va.z); va.w = fmaf(wv[3][j], xv.w, va.w);
      }
      float4 bv4;
      bv4.x = btl[i] * va.x / (1.f + __expf(-va.x));
      bv4.y = btl[i] * va.y / (1.f + __expf(-va.y));
      bv4.z = btl[i] * va.z / (1.f + __expf(-va.z));
      bv4.w = btl[i] * va.w / (1.f + __expf(-va.w));
      *(float4*)&bvg[(size_t)blockIdx.x * 8192 + i * 128 + dk] = bv4;
    }
    for (int lin = t2; lin < 8192; lin += 448) {  // layout [dk][i]
      const int dk = lin >> 6, i = lin & 63;
      const unsigned short kraw =
          *(const unsigned short*)((char*)Kb + i * 256 + ((dk * 2) ^ ((i & 7) << 4)));
      Khg[(size_t)blockIdx.x * 8192 + lin] = f2bf(__expf(cglast - cg[i]) * bf2f(kraw));
    }
  }
#undef ISSUE
#undef WRITE
#undef CONV_TO
}
#undef NT

// ---------------------------------------------------------------------------
// scan_rec (unchanged): serial over 16 chunks, (h, dv-block) parallel,
// h = bid&15 -> same-head blocks share one XCD's L2; reg-prefetch 2 sets.
// ---------------------------------------------------------------------------
struct SFrags {
  short8 wf[4];
  short8 tf[2];
  short8 qf[4];
  short8 gf[2];
  short8 kh[2][2];
  float  bv[4];
  float  es;
};

__device__ __forceinline__ void sload(SFrags& F,
    const unsigned short* __restrict__ Tg, const unsigned short* __restrict__ Gg,
    const unsigned short* __restrict__ Wtg, const unsigned short* __restrict__ Qtg,
    const unsigned short* __restrict__ Khg, const float* __restrict__ bvg,
    const float* __restrict__ esg,
    size_t base, int w, int lr, int lk, int dv0) {
  const unsigned short* T_  = Tg  + base * 4096;
  const unsigned short* G_  = Gg  + base * 4096;
  const unsigned short* W_  = Wtg + base * 8192;
  const unsigned short* Q_  = Qtg + base * 8192;
  const unsigned short* Kh_ = Khg + base * 8192;
  const float* bv_ = bvg + base * 8192;
#pragma unroll
  for (int ks = 0; ks < 4; ++ks) {
    F.wf[ks] = *(const short8*)(W_ + (16 * w + lr) * 128 + ks * 32 + lk * 8);
    F.qf[ks] = *(const short8*)(Q_ + (16 * w + lr) * 128 + ks * 32 + lk * 8);
  }
#pragma unroll
  for (int ks = 0; ks < 2; ++ks) {
    F.tf[ks]    = *(const short8*)(T_ + (16 * w + lr) * 64 + ks * 32 + lk * 8);
    F.gf[ks]    = *(const short8*)(G_ + (16 * w + lr) * 64 + ks * 32 + lk * 8);
    F.kh[0][ks] = *(const short8*)(Kh_ + (32 * w + lr) * 64 + ks * 32 + lk * 8);
    F.kh[1][ks] = *(const short8*)(Kh_ + (32 * w + 16 + lr) * 64 + ks * 32 + lk * 8);
  }
#pragma unroll
  for (int r = 0; r < 4; ++r)
    F.bv[r] = bv_[(16 * w + lk * 4 + r) * 128 + dv0 + lr];
  F.es = esg[base];
}

__global__ __launch_bounds__(256) void scan_rec(
    const unsigned short* __restrict__ Tg, const unsigned short* __restrict__ Gg,
    const unsigned short* __restrict__ Wtg, const unsigned short* __restrict__ Qtg,
    const unsigned short* __restrict__ Khg, const float* __restrict__ bvg,
    const float* __restrict__ esg, float* __restrict__ obuf) {
  const int h   = blockIdx.x & 15;   // same-head blocks -> same XCD
  const int dvb = blockIdx.x >> 4;
  const int dv0 = dvb * 16;
  const int tid = threadIdx.x;
  const int lane = tid & 63;
  const int w   = tid >> 6;
  const int lr  = lane & 15;
  const int lk  = lane >> 4;

  __shared__ unsigned short Sb[16][136];
  __shared__ unsigned short Ub[16][72];
  __shared__ unsigned short Db[16][72];

  for (int n = tid; n < 16 * 136 / 2; n += 256) ((unsigned int*)Sb)[n] = 0u;

  f32x4 sacc0 = {0.f, 0.f, 0.f, 0.f};
  f32x4 sacc1 = {0.f, 0.f, 0.f, 0.f};

  SFrags fA, fB;
  sload(fA, Tg, Gg, Wtg, Qtg, Khg, bvg, esg, (size_t)h * 16, w, lr, lk, dv0);
  __syncthreads();

#define SCAN_CHUNK(F, c)                                                      \
  {                                                                           \
    short8 sb[4];                                                             \
    _Pragma("unroll")                                                         \
    for (int ks = 0; ks < 4; ++ks)                                            \
      sb[ks] = *(const short8*)(&Sb[lr][ks * 32 + lk * 8]);                   \
    f32x4 au = {0.f, 0.f, 0.f, 0.f};                                          \
    _Pragma("unroll")                                                         \
    for (int ks = 0; ks < 4; ++ks)                                            \
      au = __builtin_amdgcn_mfma_f32_16x16x32_bf16(F.wf[ks], sb[ks], au, 0, 0, 0); \
    {                                                                         \
      ushort4 pk;                                                             \
      _Pragma("unroll")                                                       \
      for (int r = 0; r < 4; ++r)                                             \
        ((unsigned short*)&pk)[r] = f2bf(F.bv[r] - au[r]);                    \
      *(ushort4*)&Ub[lr][16 * w + lk * 4] = pk;                               \
    }                                                                         \
    __syncthreads();                                                          \
    f32x4 ad = {0.f, 0.f, 0.f, 0.f};                                          \
    _Pragma("unroll")                                                         \
    for (int ks = 0; ks < 2; ++ks) {                                          \
      const short8 ub = *(const short8*)(&Ub[lr][ks * 32 + lk * 8]);          \
      ad = __builtin_amdgcn_mfma_f32_16x16x32_bf16(F.tf[ks], ub, ad, 0, 0, 0); \
    }                                                                         \
    {                                                                         \
      ushort4 pk;                                                             \
      _Pragma("unroll")                                                       \
      for (int r = 0; r < 4; ++r) ((unsigned short*)&pk)[r] = f2bf(ad[r]);    \
      *(ushort4*)&Db[lr][16 * w + lk * 4] = pk;                               \
    }                                                                         \
    __syncthreads();                                                          \
    short8 dbf[2];                                                            \
    _Pragma("unroll")                                                         \
    for (int ks = 0; ks < 2; ++ks)                                            \
      dbf[ks] = *(const short8*)(&Db[lr][ks * 32 + lk * 8]);                  \
    f32x4 ao = {0.f, 0.f, 0.f, 0.f};                                          \
    _Pragma("unroll")                                                         \
    for (int ks = 0; ks < 4; ++ks)                                            \
      ao = __builtin_amdgcn_mfma_f32_16x16x32_bf16(F.qf[ks], sb[ks], ao, 0, 0, 0); \
    _Pragma("unroll")                                                         \
    for (int ks = 0; ks < 2; ++ks)                                            \
      ao = __builtin_amdgcn_mfma_f32_16x16x32_bf16(F.gf[ks], dbf[ks], ao, 0, 0, 0); \
    _Pragma("unroll")                                                         \
    for (int r = 0; r < 4; ++r) {                                             \
      const int i = 16 * w + lk * 4 + r;                                      \
      obuf[((size_t)((c) * 64 + i) * 16 + h) * 128 + dv0 + lr] = ao[r];       \
    }                                                                         \
    sacc0 *= F.es;                                                            \
    sacc1 *= F.es;                                                            \
    _Pragma("unroll")                                                         \
    for (int ks = 0; ks < 2; ++ks) {                                          \
      sacc0 = __builtin_amdgcn_mfma_f32_16x16x32_bf16(F.kh[0][ks], dbf[ks], sacc0, 0, 0, 0); \
      sacc1 = __builtin_amdgcn_mfma_f32_16x16x32_bf16(F.kh[1][ks], dbf[ks], sacc1, 0, 0, 0); \
    }                                                                         \
    {                                                                         \
      ushort4 p0, p1;                                                         \
      _Pragma("unroll")                                                       \
      for (int r = 0; r < 4; ++r) {                                           \
        ((unsigned short*)&p0)[r] = f2bf(sacc0[r]);                           \
        ((unsigned short*)&p1)[r] = f2bf(sacc1[r]);                           \
      }                                                                       \
      *(ushort4*)&Sb[lr][32 * w + lk * 4] = p0;                               \
      *(ushort4*)&Sb[lr][32 * w + 16 + lk * 4] = p1;                          \
    }                                                                         \
    __syncthreads();                                                          \
  }

  for (int c = 0; c < 16; c += 2) {
    const int c1 = (c + 1 < 15) ? c + 1 : 15;
    const int c2 = (c + 2 < 15) ? c + 2 : 15;
    sload(fB, Tg, Gg, Wtg, Qtg, Khg, bvg, esg, (size_t)h * 16 + c1, w, lr, lk, dv0);
    SCAN_CHUNK(fA, c);
    sload(fA, Tg, Gg, Wtg, Qtg, Khg, bvg, esg, (size_t)h * 16 + c2, w, lr, lk, dv0);
    SCAN_CHUNK(fB, c + 1);
  }
#undef SCAN_CHUNK
}

// ---------------------------------------------------------------------------
// gated RMSNorm -> bf16
// ---------------------------------------------------------------------------
__global__ __launch_bounds__(128) void rmsnorm_kernel(const float* __restrict__ obuf,
                                                      const float* __restrict__ qkvz,
                                                      const float* __restrict__ nw,
                                                      unsigned short* __restrict__ on) {
  const int vh = blockIdx.x;
  const int s  = blockIdx.y;
  const int d  = threadIdx.x;

  const float x = obuf[((size_t)s * 16 + vh) * 128 + d];
  float ss = x * x;
#pragma unroll
  for (int m = 1; m < 64; m <<= 1) ss += __shfl_xor(ss, m);
  __shared__ float red[2];
  if ((threadIdx.x & 63) == 0) red[threadIdx.x >> 6] = ss;
  __syncthreads();
  const float tot = red[0] + red[1];

  const float z = qkvz[(size_t)s * NQKVZ + (vh >> 1) * 768 + 512 + (vh & 1) * 128 + d];
  const float y = x * rsqrtf(tot * (1.f / 128.f) + 1e-6f) * nw[d] *
                  (z / (1.f + expf(-z)));
  on[(size_t)s * 2048 + vh * 128 + d] = f2bf(y);
}

// ---------------------------------------------------------------------------
extern "C" void kernel_launch(void* const* d_in, const int* in_sizes, int n_in,
                              void* d_out, int out_size, void* d_ws, size_t ws_size,
                              hipStream_t stream) {
  const float* hid     = (const float*)d_in[0];
  const float* W_qkvz  = (const float*)d_in[1];
  const float* W_ba    = (const float*)d_in[2];
  const float* conv_w  = (const float*)d_in[3];
  const float* dt_bias = (const float*)d_in[4];
  const float* A_log   = (const float*)d_in[5];
  const float* norm_w  = (const float*)d_in[6];
  const float* W_out   = (const float*)d_in[7];
  float* out = (float*)d_out;

  char* ws = (char*)d_ws;
  float* qkvz = (float*)ws;                 ws += (size_t)SEQ * NQKVZ * 4;   // 24 MB
  char* region2 = ws;                       ws += (size_t)HID * NQKVZ * 2;   // 24 MB
  unsigned short* W1t = (unsigned short*)region2;
  float* obuf = (float*)(region2 + 16777216);
  unsigned short* Xb = (unsigned short*)ws; ws += (size_t)SEQ * HID * 2;     // 4 MB
  unsigned short* on_bf = Xb;
  unsigned short* W2t = (unsigned short*)ws; ws += (size_t)HID * HID * 2;    // 8 MB
  float* gbuf = (float*)ws;                  ws += (size_t)SEQ * 16 * 4;
  float* bet  = (float*)ws;                  ws += (size_t)SEQ * 16 * 4;
  unsigned short* Tg  = (unsigned short*)ws; ws += (size_t)256 * 4096 * 2;
  unsigned short* Gg  = (unsigned short*)ws; ws += (size_t)256 * 4096 * 2;
  unsigned short* Wtg = (unsigned short*)ws; ws += (size_t)256 * 8192 * 2;
  unsigned short* Qtg = (unsigned short*)ws; ws += (size_t)256 * 8192 * 2;
  unsigned short* Khg = (unsigned short*)ws; ws += (size_t)256 * 8192 * 2;
  float* bvg          = (float*)ws;          ws += (size_t)256 * 8192 * 4;
  float* esg          = (float*)ws;          ws += 256 * 4;
  float* Wbt          = (float*)ws;          ws += (size_t)32 * HID * 4;     // 256 KB

  cast_bf16<<<dim3(SEQ * HID / 1024), 256, 0, stream>>>(hid, Xb, SEQ * HID);
  transpose_cast2<<<dim3(256, 64), 256, 0, stream>>>(W_qkvz, W1t, W_out, W2t);
  transpose_f32<<<dim3(1, HID / 32), 256, 0, stream>>>(W_ba, Wbt, HID, 32);
  ba_kernel<<<dim3(SEQ / 4), 256, 0, stream>>>(hid, Wbt, A_log, dt_bias, gbuf, bet);
  // qkvz = X @ W_qkvz  (64x128 tile, BK=64 -> 768 blocks = 3/CU)
  gemm_bf16<2, 4, 2><<<dim3(NQKVZ / 128, SEQ / 64), 256, 0, stream>>>(Xb, W1t, qkvz,
                                                                      SEQ, NQKVZ, HID);
  // conv fused into chunk_prep (512 thr, reg-prefetch pipeline)
  chunk_prep<<<dim3(256), 512, 0, stream>>>(qkvz, conv_w, gbuf, bet,
                                            Tg, Gg, Wtg, Qtg, Khg, bvg, esg);
  scan_rec<<<dim3(128), 256, 0, stream>>>(Tg, Gg, Wtg, Qtg, Khg, bvg, esg, obuf);
  rmsnorm_kernel<<<dim3(16, SEQ), 128, 0, stream>>>(obuf, qkvz, norm_w, on_bf);
  // out = on @ W_out  (64x64 tile, BK=32 -> 512 blocks = 2/CU)
  gemm_bf16<2, 2, 1><<<dim3(HID / 64, SEQ / 64), 256, 0, stream>>>(on_bf, W2t, out,
                                                                   SEQ, HID, HID);
}